// Round 16
// baseline (595.526 us; speedup 1.0000x reference)
//
#include <hip/hip_runtime.h>
#include <hip/hip_bf16.h>

// Sizes (fixed for this problem)
#define B_  4
#define S_  1024
#define DM_ 1024
#define H_  16
#define HD_ 64
#define I_  4096

typedef __attribute__((ext_vector_type(8))) short bf16x8;
typedef __attribute__((ext_vector_type(4))) float f32x4;

__device__ __forceinline__ float gelu_f(float x) {
  float x3 = x * x * x;
  return 0.5f * x * (1.0f + tanhf(0.7978845608028654f * (x + 0.044715f * x3)));
}

__device__ __forceinline__ unsigned short f32_to_bf16(float f) {
  unsigned int u = __float_as_uint(f);
  unsigned int rounding = 0x7FFFu + ((u >> 16) & 1u);
  u += rounding;
  return (unsigned short)(u >> 16);
}

__device__ __forceinline__ float bf16_to_f32(unsigned short u) {
  return __uint_as_float(((unsigned int)u) << 16);
}

__device__ __forceinline__ void split_bf16(float v, unsigned short& h, unsigned short& l) {
  h = f32_to_bf16(v);
  l = f32_to_bf16(v - bf16_to_f32(h));
}

// Direct global->LDS DMA, 16 B per lane.
__device__ __forceinline__ void gload16(const void* g, void* l) {
  __builtin_amdgcn_global_load_lds(
      (const __attribute__((address_space(1))) void*)g,
      (__attribute__((address_space(3))) void*)l, 16, 0, 0);
}

// ---------------------------------------------------------------------------
// f32 -> (hi, lo) bf16 split, elementwise (for x)
// ---------------------------------------------------------------------------
__global__ __launch_bounds__(256) void cvt_split_kernel(
    const float* __restrict__ in, unsigned short* __restrict__ hi,
    unsigned short* __restrict__ lo, int n4)
{
  int i = blockIdx.x * 256 + threadIdx.x;
  if (i < n4) {
    float4 v = *reinterpret_cast<const float4*>(&in[(size_t)i * 4]);
    ushort4 h4, l4;
    split_bf16(v.x, h4.x, l4.x); split_bf16(v.y, h4.y, l4.y);
    split_bf16(v.z, h4.z, l4.z); split_bf16(v.w, h4.w, l4.w);
    *reinterpret_cast<ushort4*>(&hi[(size_t)i * 4]) = h4;
    *reinterpret_cast<ushort4*>(&lo[(size_t)i * 4]) = l4;
  }
}

// ---------------------------------------------------------------------------
// Transpose + convert: W [K,N] f32 -> WT [N,K] bf16. 64x64 tiles, 256 thr.
// ---------------------------------------------------------------------------
__global__ __launch_bounds__(256) void tcvt_kernel(
    const float* __restrict__ W, unsigned short* __restrict__ WT, int K, int N)
{
  __shared__ float tile[64][65];
  const int tid = threadIdx.x;
  const int k0 = blockIdx.y * 64, n0 = blockIdx.x * 64;
#pragma unroll
  for (int i = 0; i < 4; ++i) {
    int u = tid + i * 256;
    int kr = u >> 4, nc = (u & 15) * 4;
    float4 v = *reinterpret_cast<const float4*>(&W[(size_t)(k0 + kr) * N + n0 + nc]);
    tile[kr][nc + 0] = v.x; tile[kr][nc + 1] = v.y;
    tile[kr][nc + 2] = v.z; tile[kr][nc + 3] = v.w;
  }
  __syncthreads();
  int n = tid >> 2, ks = (tid & 3) * 16;
  unsigned short* dst = &WT[(size_t)(n0 + n) * K + k0 + ks];
#pragma unroll
  for (int j = 0; j < 4; ++j) {
    ushort4 o;
    o.x = f32_to_bf16(tile[ks + j * 4 + 0][n]);
    o.y = f32_to_bf16(tile[ks + j * 4 + 1][n]);
    o.z = f32_to_bf16(tile[ks + j * 4 + 2][n]);
    o.w = f32_to_bf16(tile[ks + j * 4 + 3][n]);
    *reinterpret_cast<ushort4*>(&dst[j * 4]) = o;
  }
}

// ---------------------------------------------------------------------------
// Transpose + SPLIT convert: W [K,N] f32 -> WTh/WTl [N,K] bf16 pair.
// ---------------------------------------------------------------------------
__global__ __launch_bounds__(256) void tcvt2_kernel(
    const float* __restrict__ W, unsigned short* __restrict__ WTh,
    unsigned short* __restrict__ WTl, int K, int N)
{
  __shared__ float tile[64][65];
  const int tid = threadIdx.x;
  const int k0 = blockIdx.y * 64, n0 = blockIdx.x * 64;
#pragma unroll
  for (int i = 0; i < 4; ++i) {
    int u = tid + i * 256;
    int kr = u >> 4, nc = (u & 15) * 4;
    float4 v = *reinterpret_cast<const float4*>(&W[(size_t)(k0 + kr) * N + n0 + nc]);
    tile[kr][nc + 0] = v.x; tile[kr][nc + 1] = v.y;
    tile[kr][nc + 2] = v.z; tile[kr][nc + 3] = v.w;
  }
  __syncthreads();
  int n = tid >> 2, ks = (tid & 3) * 16;
#pragma unroll
  for (int j = 0; j < 4; ++j) {
    ushort4 h4, l4;
    split_bf16(tile[ks + j * 4 + 0][n], h4.x, l4.x);
    split_bf16(tile[ks + j * 4 + 1][n], h4.y, l4.y);
    split_bf16(tile[ks + j * 4 + 2][n], h4.z, l4.z);
    split_bf16(tile[ks + j * 4 + 3][n], h4.w, l4.w);
    *reinterpret_cast<ushort4*>(&WTh[(size_t)(n0 + n) * K + k0 + ks + j * 4]) = h4;
    *reinterpret_cast<ushort4*>(&WTl[(size_t)(n0 + n) * K + k0 + ks + j * 4]) = l4;
  }
}

// ---------------------------------------------------------------------------
// V transpose: vin [BH][S][HD] bf16 -> vout [BH][HD][S] bf16. 64x64 tiles.
// ---------------------------------------------------------------------------
__global__ __launch_bounds__(256) void vtrans_kernel(
    const unsigned short* __restrict__ vin, unsigned short* __restrict__ vout)
{
  __shared__ unsigned short tile[64][76];
  const int tid = threadIdx.x;
  const int st = blockIdx.x;
  const int bh = blockIdx.y;
  const unsigned short* src = vin + ((size_t)bh * S_ + st * 64) * HD_;
  unsigned short* dst = vout + (size_t)bh * HD_ * S_ + st * 64;
#pragma unroll
  for (int i = 0; i < 2; ++i) {
    int u = tid + i * 256;
    int row = u >> 3, unit = u & 7;
    *reinterpret_cast<int4*>(&tile[row][unit * 8]) =
        *reinterpret_cast<const int4*>(&src[(size_t)row * HD_ + unit * 8]);
  }
  __syncthreads();
#pragma unroll
  for (int i = 0; i < 2; ++i) {
    int u = tid + i * 256;
    int d = u >> 3, unit = u & 7;
    unsigned short tmp[8];
#pragma unroll
    for (int j = 0; j < 8; ++j) tmp[j] = tile[unit * 8 + j][d];
    *reinterpret_cast<int4*>(&dst[(size_t)d * S_ + unit * 8]) =
        *reinterpret_cast<const int4*>(tmp);
  }
}

// ---------------------------------------------------------------------------
// bf16 MFMA GEMM, 64x128 tile, BK=64 (half the barriers of BK=32), 4 waves.
// gload16 staging: each covers 8 rows x 64 cols. LDS = 24 KB.
// ---------------------------------------------------------------------------
template<bool GELU, bool RES, bool RESBF16, bool BHSD, bool OBF16>
__global__ __launch_bounds__(256) void gemm_mfma_kernel(
    const unsigned short* __restrict__ A, const unsigned short* __restrict__ BT,
    const float* __restrict__ bias, const void* __restrict__ res,
    void* __restrict__ C, int M, int N, int K)
{
  __shared__ unsigned short As[64][64];
  __shared__ unsigned short Bs[128][64];
  const int tid = threadIdx.x;
  const int wid = tid >> 6;
  const int lane = tid & 63;
  const int bm = blockIdx.y * 64;
  const int bn = blockIdx.x * 128;
  const int l15 = lane & 15;
  const int hi4 = lane >> 4;
  const int kb = hi4 * 8;
  const int srow8 = lane >> 3;         // 0..7 row within 8-row strip
  const int scol8 = (lane & 7) * 8;    // bf16 col offset (16B units)

  f32x4 acc[8];
#pragma unroll
  for (int ni = 0; ni < 8; ++ni) acc[ni] = (f32x4){0.f, 0.f, 0.f, 0.f};

  for (int k0 = 0; k0 < K; k0 += 64) {
#pragma unroll
    for (int i = 0; i < 2; ++i) {      // A: 64 rows = 8 strips, 2/wave
      int br = wid * 16 + i * 8;
      gload16(&A[(size_t)(bm + br + srow8) * K + k0 + scol8], &As[br][0]);
    }
#pragma unroll
    for (int i = 0; i < 4; ++i) {      // B: 128 rows = 16 strips, 4/wave
      int br = wid * 32 + i * 8;
      gload16(&BT[(size_t)(bn + br + srow8) * K + k0 + scol8], &Bs[br][0]);
    }
    __syncthreads();

    bf16x8 af0 = *reinterpret_cast<const bf16x8*>(&As[wid * 16 + l15][kb]);
    bf16x8 af1 = *reinterpret_cast<const bf16x8*>(&As[wid * 16 + l15][32 + kb]);
#pragma unroll
    for (int ni = 0; ni < 8; ++ni) {
      bf16x8 b0 = *reinterpret_cast<const bf16x8*>(&Bs[ni * 16 + l15][kb]);
      bf16x8 b1 = *reinterpret_cast<const bf16x8*>(&Bs[ni * 16 + l15][32 + kb]);
      acc[ni] = __builtin_amdgcn_mfma_f32_16x16x32_bf16(af0, b0, acc[ni], 0, 0, 0);
      acc[ni] = __builtin_amdgcn_mfma_f32_16x16x32_bf16(af1, b1, acc[ni], 0, 0, 0);
    }
    __syncthreads();
  }

#pragma unroll
  for (int ni = 0; ni < 8; ++ni) {
    int gcol = bn + ni * 16 + l15;
    float bsv = bias[gcol];
#pragma unroll
    for (int r = 0; r < 4; ++r) {
      int grow = bm + wid * 16 + hi4 * 4 + r;
      float val = acc[ni][r] + bsv;
      if (GELU) val = gelu_f(val);
      if (RES) {
        if (RESBF16) val += bf16_to_f32(((const unsigned short*)res)[(size_t)grow * N + gcol]);
        else         val += ((const float*)res)[(size_t)grow * N + gcol];
      }
      if (BHSD) {
        int bb = grow >> 10, ss = grow & 1023, hh = gcol >> 6, dd = gcol & 63;
        size_t adr = ((size_t)(bb * H_ + hh) * S_ + ss) * HD_ + dd;
        if (OBF16) ((unsigned short*)C)[adr] = f32_to_bf16(val);
        else       ((float*)C)[adr] = val;
      } else if (OBF16) {
        ((unsigned short*)C)[(size_t)grow * N + gcol] = f32_to_bf16(val);
      } else {
        ((float*)C)[(size_t)grow * N + gcol] = val;
      }
    }
  }
}

// ---------------------------------------------------------------------------
// Split-f32 MFMA GEMM, pre-split inputs, 64x128 tile, BK=64. LDS 48 KB.
// ---------------------------------------------------------------------------
__global__ __launch_bounds__(256) void gemm_mfma3_kernel(
    const unsigned short* __restrict__ Ah_g, const unsigned short* __restrict__ Al_g,
    const unsigned short* __restrict__ Bh_g, const unsigned short* __restrict__ Bl_g,
    const float* __restrict__ bias, unsigned short* __restrict__ Ch,
    unsigned short* __restrict__ Cl, int M, int N, int K)
{
  __shared__ unsigned short Ah[64][64], Al[64][64];
  __shared__ unsigned short Bh[128][64], Bl[128][64];
  const int tid = threadIdx.x;
  const int wid = tid >> 6;
  const int lane = tid & 63;
  const int bm = blockIdx.y * 64;
  const int bn = blockIdx.x * 128;
  const int l15 = lane & 15;
  const int hi4 = lane >> 4;
  const int kb = hi4 * 8;
  const int srow8 = lane >> 3;
  const int scol8 = (lane & 7) * 8;

  f32x4 acc[8];
#pragma unroll
  for (int ni = 0; ni < 8; ++ni) acc[ni] = (f32x4){0.f, 0.f, 0.f, 0.f};

  for (int k0 = 0; k0 < K; k0 += 64) {
#pragma unroll
    for (int i = 0; i < 2; ++i) {
      int br = wid * 16 + i * 8;
      size_t ga = (size_t)(bm + br + srow8) * K + k0 + scol8;
      gload16(&Ah_g[ga], &Ah[br][0]);
      gload16(&Al_g[ga], &Al[br][0]);
    }
#pragma unroll
    for (int i = 0; i < 4; ++i) {
      int br = wid * 32 + i * 8;
      size_t gb = (size_t)(bn + br + srow8) * K + k0 + scol8;
      gload16(&Bh_g[gb], &Bh[br][0]);
      gload16(&Bl_g[gb], &Bl[br][0]);
    }
    __syncthreads();

    bf16x8 ah0 = *reinterpret_cast<const bf16x8*>(&Ah[wid * 16 + l15][kb]);
    bf16x8 ah1 = *reinterpret_cast<const bf16x8*>(&Ah[wid * 16 + l15][32 + kb]);
    bf16x8 al0 = *reinterpret_cast<const bf16x8*>(&Al[wid * 16 + l15][kb]);
    bf16x8 al1 = *reinterpret_cast<const bf16x8*>(&Al[wid * 16 + l15][32 + kb]);
#pragma unroll
    for (int ni = 0; ni < 8; ++ni) {
      bf16x8 bh0 = *reinterpret_cast<const bf16x8*>(&Bh[ni * 16 + l15][kb]);
      bf16x8 bh1 = *reinterpret_cast<const bf16x8*>(&Bh[ni * 16 + l15][32 + kb]);
      bf16x8 bl0 = *reinterpret_cast<const bf16x8*>(&Bl[ni * 16 + l15][kb]);
      bf16x8 bl1 = *reinterpret_cast<const bf16x8*>(&Bl[ni * 16 + l15][32 + kb]);
      acc[ni] = __builtin_amdgcn_mfma_f32_16x16x32_bf16(ah0, bh0, acc[ni], 0, 0, 0);
      acc[ni] = __builtin_amdgcn_mfma_f32_16x16x32_bf16(al0, bh0, acc[ni], 0, 0, 0);
      acc[ni] = __builtin_amdgcn_mfma_f32_16x16x32_bf16(ah0, bl0, acc[ni], 0, 0, 0);
      acc[ni] = __builtin_amdgcn_mfma_f32_16x16x32_bf16(ah1, bh1, acc[ni], 0, 0, 0);
      acc[ni] = __builtin_amdgcn_mfma_f32_16x16x32_bf16(al1, bh1, acc[ni], 0, 0, 0);
      acc[ni] = __builtin_amdgcn_mfma_f32_16x16x32_bf16(ah1, bl1, acc[ni], 0, 0, 0);
    }
    __syncthreads();
  }

#pragma unroll
  for (int ni = 0; ni < 8; ++ni) {
    int gcol = bn + ni * 16 + l15;
    float bsv = bias[gcol];
#pragma unroll
    for (int r = 0; r < 4; ++r) {
      int grow = bm + wid * 16 + hi4 * 4 + r;
      float val = acc[ni][r] + bsv;
      int bb = grow >> 10, ss = grow & 1023, hh = gcol >> 6, dd = gcol & 63;
      size_t adr = ((size_t)(bb * H_ + hh) * S_ + ss) * HD_ + dd;
      unsigned short hh2, ll2;
      split_bf16(val, hh2, ll2);
      Ch[adr] = hh2;
      Cl[adr] = ll2;
    }
  }
}

// ---------------------------------------------------------------------------
// Attention scores + rel + mask + softmax -> probs f32.
// 512 threads = 8 waves: 2 q-groups (16 rows each) x 4 k-strip waves.
// K tiles shared in LDS across both q-groups. LDS ~54 KB.
// ---------------------------------------------------------------------------
__global__ __launch_bounds__(512) void attn_kernel(
    const unsigned short* __restrict__ qkh, const unsigned short* __restrict__ qkl,
    const int* __restrict__ mask, const float* __restrict__ rel_emb,
    float* __restrict__ probs)
{
  __shared__ unsigned short Qh[32][72], Ql[32][72];
  __shared__ unsigned short Kh[128][72], Kl[128][72];
  __shared__ float relp[32][24];
  __shared__ float red1[8][16], red2[8][16];
  __shared__ int msk[1024];

  const int tid = threadIdx.x;
  const int b = blockIdx.z, h = blockIdx.y, qt = blockIdx.x;
  const size_t bhoff = (size_t)(b * H_ + h) * S_ * HD_;
  const unsigned short* qh = qkh + bhoff;
  const unsigned short* ql = qkl + bhoff;
  const int q0 = qt * 32;

  for (int i = tid; i < 1024; i += 512) msk[i] = mask[b * S_ + i];

  if (tid < 256) {
    int row = tid >> 3, seg = (tid & 7) * 8;
    *reinterpret_cast<int4*>(&Qh[row][seg]) =
        *reinterpret_cast<const int4*>(&qh[(size_t)(q0 + row) * HD_ + seg]);
    *reinterpret_cast<int4*>(&Ql[row][seg]) =
        *reinterpret_cast<const int4*>(&ql[(size_t)(q0 + row) * HD_ + seg]);
  }
  __syncthreads();

  for (int idx = tid; idx < 32 * 21; idx += 512) {
    int q = idx / 21, r = idx - q * 21;
    float s = 0.f;
#pragma unroll 8
    for (int d = 0; d < 64; ++d) {
      float qf = bf16_to_f32(Qh[q][d]) + bf16_to_f32(Ql[q][d]);
      s += qf * rel_emb[r * 64 + d];
    }
    relp[q][r] = s;
  }

  const int qg = tid >> 8;
  const int wv = (tid >> 6) & 3;
  const int lane = tid & 63;
  const int l15 = lane & 15;
  const int hi4 = lane >> 4;
  const int kb = hi4 * 8;

  bf16x8 ah[2], al[2];
#pragma unroll
  for (int ks = 0; ks < 2; ++ks) {
    ah[ks] = *reinterpret_cast<const bf16x8*>(&Qh[qg * 16 + l15][ks * 32 + kb]);
    al[ks] = *reinterpret_cast<const bf16x8*>(&Ql[qg * 16 + l15][ks * 32 + kb]);
  }

  f32x4 acc[8][2];
#pragma unroll
  for (int t = 0; t < 8; ++t)
#pragma unroll
    for (int f = 0; f < 2; ++f) acc[t][f] = (f32x4){0.f, 0.f, 0.f, 0.f};

#pragma unroll
  for (int kt = 0; kt < 8; ++kt) {
    __syncthreads();
#pragma unroll
    for (int i = 0; i < 2; ++i) {
      int u = tid + i * 512;
      int row = u >> 3, seg = (u & 7) * 8;
      *reinterpret_cast<int4*>(&Kh[row][seg]) =
          *reinterpret_cast<const int4*>(&qh[(size_t)(kt * 128 + row) * HD_ + seg]);
      *reinterpret_cast<int4*>(&Kl[row][seg]) =
          *reinterpret_cast<const int4*>(&ql[(size_t)(kt * 128 + row) * HD_ + seg]);
    }
    __syncthreads();

#pragma unroll
    for (int f = 0; f < 2; ++f) {
      int cb = wv * 32 + f * 16;
#pragma unroll
      for (int ks = 0; ks < 2; ++ks) {
        bf16x8 bh = *reinterpret_cast<const bf16x8*>(&Kh[cb + l15][ks * 32 + kb]);
        bf16x8 bl = *reinterpret_cast<const bf16x8*>(&Kl[cb + l15][ks * 32 + kb]);
        acc[kt][f] = __builtin_amdgcn_mfma_f32_16x16x32_bf16(ah[ks], bh, acc[kt][f], 0, 0, 0);
        acc[kt][f] = __builtin_amdgcn_mfma_f32_16x16x32_bf16(al[ks], bh, acc[kt][f], 0, 0, 0);
        acc[kt][f] = __builtin_amdgcn_mfma_f32_16x16x32_bf16(ah[ks], bl, acc[kt][f], 0, 0, 0);
      }
    }
  }
  __syncthreads();

  float mx[4] = {-3.0e38f, -3.0e38f, -3.0e38f, -3.0e38f};
#pragma unroll
  for (int t = 0; t < 8; ++t)
#pragma unroll
    for (int f = 0; f < 2; ++f)
#pragma unroll
      for (int r = 0; r < 4; ++r) {
        int qlc = qg * 16 + hi4 * 4 + r;
        int q = q0 + qlc;
        int k = t * 128 + wv * 32 + f * 16 + l15;
        int d = k - q;
        int ridx = (d < -10 ? -10 : (d > 10 ? 10 : d)) + 10;
        float s = acc[t][f][r] + relp[qlc][ridx];
        if (k == q || msk[k] == 0) s -= 10000.0f;
        acc[t][f][r] = s;
        mx[r] = fmaxf(mx[r], s);
      }
#pragma unroll
  for (int r = 0; r < 4; ++r) {
    mx[r] = fmaxf(mx[r], __shfl_xor(mx[r], 1));
    mx[r] = fmaxf(mx[r], __shfl_xor(mx[r], 2));
    mx[r] = fmaxf(mx[r], __shfl_xor(mx[r], 4));
    mx[r] = fmaxf(mx[r], __shfl_xor(mx[r], 8));
  }
  {
    int wrow = qg * 4 + wv;
    if (l15 == 0) {
#pragma unroll
      for (int r = 0; r < 4; ++r) red1[wrow][hi4 * 4 + r] = mx[r];
    }
  }
  __syncthreads();
  float mxq[4];
#pragma unroll
  for (int r = 0; r < 4; ++r) {
    int ql16 = hi4 * 4 + r;
    mxq[r] = fmaxf(fmaxf(red1[qg * 4 + 0][ql16], red1[qg * 4 + 1][ql16]),
                   fmaxf(red1[qg * 4 + 2][ql16], red1[qg * 4 + 3][ql16]));
  }

  float sm[4] = {0.f, 0.f, 0.f, 0.f};
#pragma unroll
  for (int t = 0; t < 8; ++t)
#pragma unroll
    for (int f = 0; f < 2; ++f)
#pragma unroll
      for (int r = 0; r < 4; ++r) {
        float e = __expf(acc[t][f][r] - mxq[r]);
        acc[t][f][r] = e;
        sm[r] += e;
      }
#pragma unroll
  for (int r = 0; r < 4; ++r) {
    sm[r] += __shfl_xor(sm[r], 1);
    sm[r] += __shfl_xor(sm[r], 2);
    sm[r] += __shfl_xor(sm[r], 4);
    sm[r] += __shfl_xor(sm[r], 8);
  }
  {
    int wrow = qg * 4 + wv;
    if (l15 == 0) {
#pragma unroll
      for (int r = 0; r < 4; ++r) red2[wrow][hi4 * 4 + r] = sm[r];
    }
  }
  __syncthreads();
  float rinv[4];
#pragma unroll
  for (int r = 0; r < 4; ++r) {
    int ql16 = hi4 * 4 + r;
    rinv[r] = 1.0f / (red2[qg * 4 + 0][ql16] + red2[qg * 4 + 1][ql16] +
                      red2[qg * 4 + 2][ql16] + red2[qg * 4 + 3][ql16]);
  }

  float* pb = probs + (size_t)(b * H_ + h) * S_ * S_;
#pragma unroll
  for (int t = 0; t < 8; ++t)
#pragma unroll
    for (int f = 0; f < 2; ++f)
#pragma unroll
      for (int r = 0; r < 4; ++r) {
        int qlc = qg * 16 + hi4 * 4 + r;
        int kg = wv * 32 + f * 16 + l15;
        pb[(size_t)(q0 + qlc) * S_ + t * 128 + kg] = acc[t][f][r] * rinv[r];
      }
}

// ---------------------------------------------------------------------------
// PV, zero-LDS: ctx = P @ V. A-fragments direct from probs f32, B-fragments
// direct from pre-transposed vbt [BH][HD][S]. No barriers, no LDS.
// ---------------------------------------------------------------------------
__global__ __launch_bounds__(256) void pv_direct_kernel(
    const float* __restrict__ probs, const unsigned short* __restrict__ vbt,
    unsigned short* __restrict__ ctxb)
{
  const int tid = threadIdx.x;
  const int wv = tid >> 6;
  const int lane = tid & 63;
  const int l15 = lane & 15;
  const int hi4 = lane >> 4;
  const int b = blockIdx.z, h = blockIdx.y, qt = blockIdx.x;
  const float* pr = probs + (size_t)(b * H_ + h) * S_ * S_
                          + (size_t)(qt * 128 + wv * 32) * S_;
  const unsigned short* vtb = vbt + (size_t)(b * H_ + h) * HD_ * S_;

  f32x4 acc[2][4];
#pragma unroll
  for (int mi = 0; mi < 2; ++mi)
#pragma unroll
    for (int ni = 0; ni < 4; ++ni) acc[mi][ni] = (f32x4){0.f, 0.f, 0.f, 0.f};

  for (int k0 = 0; k0 < S_; k0 += 32) {
    bf16x8 af[2];
#pragma unroll
    for (int mi = 0; mi < 2; ++mi) {
      const float* prow = pr + (size_t)(mi * 16 + l15) * S_ + k0 + hi4 * 8;
      float4 p0 = *reinterpret_cast<const float4*>(prow);
      float4 p1 = *reinterpret_cast<const float4*>(prow + 4);
      bf16x8 a;
      a[0] = (short)f32_to_bf16(p0.x); a[1] = (short)f32_to_bf16(p0.y);
      a[2] = (short)f32_to_bf16(p0.z); a[3] = (short)f32_to_bf16(p0.w);
      a[4] = (short)f32_to_bf16(p1.x); a[5] = (short)f32_to_bf16(p1.y);
      a[6] = (short)f32_to_bf16(p1.z); a[7] = (short)f32_to_bf16(p1.w);
      af[mi] = a;
    }
#pragma unroll
    for (int ni = 0; ni < 4; ++ni) {
      bf16x8 vf = *reinterpret_cast<const bf16x8*>(
          &vtb[(size_t)(ni * 16 + l15) * S_ + k0 + hi4 * 8]);
      acc[0][ni] = __builtin_amdgcn_mfma_f32_16x16x32_bf16(af[0], vf, acc[0][ni], 0, 0, 0);
      acc[1][ni] = __builtin_amdgcn_mfma_f32_16x16x32_bf16(af[1], vf, acc[1][ni], 0, 0, 0);
    }
  }

#pragma unroll
  for (int mi = 0; mi < 2; ++mi)
#pragma unroll
    for (int ni = 0; ni < 4; ++ni) {
      int dd = ni * 16 + l15;
#pragma unroll
      for (int r = 0; r < 4; ++r) {
        int q = qt * 128 + wv * 32 + mi * 16 + hi4 * 4 + r;
        ctxb[((size_t)b * S_ + q) * DM_ + h * HD_ + dd] = f32_to_bf16(acc[mi][ni][r]);
      }
    }
}

// ---------------------------------------------------------------------------
// Row LayerNorm (1024 cols), f32 in, f32 or bf16 out (safe in-place for f32)
// ---------------------------------------------------------------------------
template<bool OUTB16>
__global__ __launch_bounds__(256) void ln_kernel(
    const float* __restrict__ in, const float* __restrict__ g,
    const float* __restrict__ be, void* __restrict__ out)
{
  __shared__ float red[4];
  const int row = blockIdx.x, tid = threadIdx.x;
  const float* r = in + (size_t)row * DM_;
  float4 x = *reinterpret_cast<const float4*>(&r[tid * 4]);

  float s = x.x + x.y + x.z + x.w;
#pragma unroll
  for (int m = 1; m < 64; m <<= 1) s += __shfl_xor(s, m);
  if ((tid & 63) == 0) red[tid >> 6] = s;
  __syncthreads();
  float mean = (red[0] + red[1] + red[2] + red[3]) * (1.0f / 1024.0f);
  __syncthreads();

  float d0 = x.x - mean, d1 = x.y - mean, d2 = x.z - mean, d3 = x.w - mean;
  float sq = d0 * d0 + d1 * d1 + d2 * d2 + d3 * d3;
#pragma unroll
  for (int m = 1; m < 64; m <<= 1) sq += __shfl_xor(sq, m);
  if ((tid & 63) == 0) red[tid >> 6] = sq;
  __syncthreads();
  float var = (red[0] + red[1] + red[2] + red[3]) * (1.0f / 1024.0f);
  float rstd = rsqrtf(var + 1e-3f);

  int c = tid * 4;
  float4 gv = *reinterpret_cast<const float4*>(&g[c]);
  float4 bv = *reinterpret_cast<const float4*>(&be[c]);
  float y0 = d0 * rstd * gv.x + bv.x;
  float y1 = d1 * rstd * gv.y + bv.y;
  float y2 = d2 * rstd * gv.z + bv.z;
  float y3 = d3 * rstd * gv.w + bv.w;
  if (OUTB16) {
    ushort4 o;
    o.x = f32_to_bf16(y0); o.y = f32_to_bf16(y1);
    o.z = f32_to_bf16(y2); o.w = f32_to_bf16(y3);
    *reinterpret_cast<ushort4*>(&((unsigned short*)out)[(size_t)row * DM_ + c]) = o;
  } else {
    *reinterpret_cast<float4*>(&((float*)out)[(size_t)row * DM_ + c]) =
        make_float4(y0, y1, y2, y3);
  }
}

// ---------------------------------------------------------------------------
// Workspace plan (64 MB, offsets in MB; overlays lifetime-checked):
//   0-8   WoT bf16       (prep -> Wo)
//   8-16  WiT bf16       (prep -> Wi)
//   16-18 WvT bf16       (prep -> Wv)
//   18-20 WapT bf16      (prep -> Wap)
//   20-22 WqkTh, 22-24 WqkTl  (prep -> qkproj)
//   24-32 xh bf16        (prep -> Wv proj & qkproj), then vbt (vtrans -> pv)
//   32-40 xl bf16        (prep -> qkproj), then ctxb bf16 (pv -> Wap)
//   40-48 qk_hi bf16     (qkproj -> attn)
//   48-56 qk_lo bf16     (qkproj -> attn)
//   40-56 y f32          (Wap -> ln1)   [qk_hi/lo dead]
//   56-64 vb bf16        (Wv -> vtrans)
//   20-28 attnb bf16     (ln1 -> Wo)    [WqkT + vbt dead]
//   32-64 interb bf16    (Wi -> Wo)     [ctxb/y/vb dead]
//   t = outf (d_out); ln2 in place.
// ---------------------------------------------------------------------------
extern "C" void kernel_launch(void* const* d_in, const int* in_sizes, int n_in,
                              void* d_out, int out_size, void* d_ws, size_t ws_size,
                              hipStream_t stream) {
  const float* x    = (const float*)d_in[0];
  const int*   mask = (const int*)d_in[1];
  const float* Wqk  = (const float*)d_in[2];
  const float* bqk  = (const float*)d_in[3];
  const float* Wv   = (const float*)d_in[4];
  const float* bv   = (const float*)d_in[5];
  const float* rel  = (const float*)d_in[6];
  const float* Wap  = (const float*)d_in[7];
  const float* bap  = (const float*)d_in[8];
  const float* g1   = (const float*)d_in[9];
  const float* b1   = (const float*)d_in[10];
  const float* Wi   = (const float*)d_in[11];
  const float* bi   = (const float*)d_in[12];
  const float* Wo   = (const float*)d_in[13];
  const float* bo   = (const float*)d_in[14];
  const float* g2   = (const float*)d_in[15];
  const float* b2   = (const float*)d_in[16];

  char* wsb = (char*)d_ws;
  const size_t MB = 1048576;
  unsigned short* WoT    = (unsigned short*)(wsb + 0 * MB);
  unsigned short* WiT    = (unsigned short*)(wsb + 8 * MB);
  unsigned short* WvT    = (unsigned short*)(wsb + 16 * MB);
  unsigned short* WapT   = (unsigned short*)(wsb + 18 * MB);
  unsigned short* WqkTh  = (unsigned short*)(wsb + 20 * MB);
  unsigned short* WqkTl  = (unsigned short*)(wsb + 22 * MB);
  unsigned short* xh     = (unsigned short*)(wsb + 24 * MB);
  unsigned short* vbt    = (unsigned short*)(wsb + 24 * MB);
  unsigned short* xl     = (unsigned short*)(wsb + 32 * MB);
  unsigned short* ctxb   = (unsigned short*)(wsb + 32 * MB);
  unsigned short* qk_hi  = (unsigned short*)(wsb + 40 * MB);
  unsigned short* qk_lo  = (unsigned short*)(wsb + 48 * MB);
  float*          y      = (float*)(wsb + 40 * MB);
  unsigned short* vb     = (unsigned short*)(wsb + 56 * MB);
  unsigned short* attnb  = (unsigned short*)(wsb + 20 * MB);
  unsigned short* interb = (unsigned short*)(wsb + 32 * MB);

  float* outf  = (float*)d_out;        // out   [B,S,DM]  f32 (also t buffer)
  float* probs = outf + 4194304;       // probs [B,H,S,S] f32

  dim3 blk(256);
  // Preps
  cvt_split_kernel<<<4096, blk, 0, stream>>>(x, xh, xl, 1048576);
  tcvt_kernel<<<dim3(16, 16), blk, 0, stream>>>(Wv,  WvT,  1024, 1024);
  tcvt_kernel<<<dim3(16, 16), blk, 0, stream>>>(Wap, WapT, 1024, 1024);
  tcvt_kernel<<<dim3(64, 16), blk, 0, stream>>>(Wi,  WiT,  1024, 4096);
  tcvt_kernel<<<dim3(16, 64), blk, 0, stream>>>(Wo,  WoT,  4096, 1024);
  tcvt2_kernel<<<dim3(16, 16), blk, 0, stream>>>(Wqk, WqkTh, WqkTl, 1024, 1024);

  // q/k shared projection (pre-split 3-MFMA) -> qk hi/lo bf16 [B,H,S,HD]
  gemm_mfma3_kernel<<<dim3(8, 64), blk, 0, stream>>>(
      xh, xl, WqkTh, WqkTl, bqk, qk_hi, qk_lo, 4096, 1024, 1024);
  // v projection (bf16 MFMA) -> [B,H,S,HD] bf16
  gemm_mfma_kernel<false, false, false, true, true><<<dim3(8, 64), blk, 0, stream>>>(
      xh, WvT, bv, nullptr, vb, 4096, 1024, 1024);
  // V transpose -> [B,H,HD,S]  (xh dead now)
  vtrans_kernel<<<dim3(16, 64), blk, 0, stream>>>(vb, vbt);
  // scores + rel + mask + softmax -> probs f32 (32 q-rows/block, 8 waves)
  attn_kernel<<<dim3(32, 16, 4), dim3(512), 0, stream>>>(
      qk_hi, qk_lo, mask, rel, probs);
  // ctx = probs @ v (zero-LDS direct fragments) -> bf16 [B,S,DM]
  pv_direct_kernel<<<dim3(8, 16, 4), blk, 0, stream>>>(probs, vbt, ctxb);
  // y = gelu(ctx @ Wap + bap) + x
  gemm_mfma_kernel<true, true, false, false, false><<<dim3(8, 64), blk, 0, stream>>>(
      ctxb, WapT, bap, x, y, 4096, 1024, 1024);
  // attnb = LN(y)*g1+b1 (bf16)
  ln_kernel<true><<<4096, blk, 0, stream>>>(y, g1, b1, attnb);
  // inter = gelu(attn @ Wi + bi) (bf16)
  gemm_mfma_kernel<true, false, false, false, true><<<dim3(32, 64), blk, 0, stream>>>(
      attnb, WiT, bi, nullptr, interb, 4096, 4096, 1024);
  // outf = gelu(inter @ Wo + bo) + attn   (t lives in d_out)
  gemm_mfma_kernel<true, true, true, false, false><<<dim3(8, 64), blk, 0, stream>>>(
      interb, WoT, bo, attnb, outf, 4096, 1024, 4096);
  // out = LN(t)*g2+b2 (f32, in place)
  ln_kernel<false><<<4096, blk, 0, stream>>>(outf, g2, b2, outf);
}

// Round 17
// 547.709 us; speedup vs baseline: 1.0873x; 1.0873x over previous
//
#include <hip/hip_runtime.h>
#include <hip/hip_bf16.h>

// Sizes (fixed for this problem)
#define B_  4
#define S_  1024
#define DM_ 1024
#define H_  16
#define HD_ 64
#define I_  4096

typedef __attribute__((ext_vector_type(8))) short bf16x8;
typedef __attribute__((ext_vector_type(4))) float f32x4;

__device__ __forceinline__ float gelu_f(float x) {
  float x3 = x * x * x;
  return 0.5f * x * (1.0f + tanhf(0.7978845608028654f * (x + 0.044715f * x3)));
}

__device__ __forceinline__ unsigned short f32_to_bf16(float f) {
  unsigned int u = __float_as_uint(f);
  unsigned int rounding = 0x7FFFu + ((u >> 16) & 1u);
  u += rounding;
  return (unsigned short)(u >> 16);
}

__device__ __forceinline__ float bf16_to_f32(unsigned short u) {
  return __uint_as_float(((unsigned int)u) << 16);
}

__device__ __forceinline__ void split_bf16(float v, unsigned short& h, unsigned short& l) {
  h = f32_to_bf16(v);
  l = f32_to_bf16(v - bf16_to_f32(h));
}

// Direct global->LDS DMA, 16 B per lane.
__device__ __forceinline__ void gload16(const void* g, void* l) {
  __builtin_amdgcn_global_load_lds(
      (const __attribute__((address_space(1))) void*)g,
      (__attribute__((address_space(3))) void*)l, 16, 0, 0);
}

// ---------------------------------------------------------------------------
// f32 -> (hi, lo) bf16 split, elementwise (for x)
// ---------------------------------------------------------------------------
__global__ __launch_bounds__(256) void cvt_split_kernel(
    const float* __restrict__ in, unsigned short* __restrict__ hi,
    unsigned short* __restrict__ lo, int n4)
{
  int i = blockIdx.x * 256 + threadIdx.x;
  if (i < n4) {
    float4 v = *reinterpret_cast<const float4*>(&in[(size_t)i * 4]);
    ushort4 h4, l4;
    split_bf16(v.x, h4.x, l4.x); split_bf16(v.y, h4.y, l4.y);
    split_bf16(v.z, h4.z, l4.z); split_bf16(v.w, h4.w, l4.w);
    *reinterpret_cast<ushort4*>(&hi[(size_t)i * 4]) = h4;
    *reinterpret_cast<ushort4*>(&lo[(size_t)i * 4]) = l4;
  }
}

// ---------------------------------------------------------------------------
// Transpose + convert: W [K,N] f32 -> WT [N,K] bf16. 64x64 tiles, 256 thr.
// ---------------------------------------------------------------------------
__global__ __launch_bounds__(256) void tcvt_kernel(
    const float* __restrict__ W, unsigned short* __restrict__ WT, int K, int N)
{
  __shared__ float tile[64][65];
  const int tid = threadIdx.x;
  const int k0 = blockIdx.y * 64, n0 = blockIdx.x * 64;
#pragma unroll
  for (int i = 0; i < 4; ++i) {
    int u = tid + i * 256;
    int kr = u >> 4, nc = (u & 15) * 4;
    float4 v = *reinterpret_cast<const float4*>(&W[(size_t)(k0 + kr) * N + n0 + nc]);
    tile[kr][nc + 0] = v.x; tile[kr][nc + 1] = v.y;
    tile[kr][nc + 2] = v.z; tile[kr][nc + 3] = v.w;
  }
  __syncthreads();
  int n = tid >> 2, ks = (tid & 3) * 16;
  unsigned short* dst = &WT[(size_t)(n0 + n) * K + k0 + ks];
#pragma unroll
  for (int j = 0; j < 4; ++j) {
    ushort4 o;
    o.x = f32_to_bf16(tile[ks + j * 4 + 0][n]);
    o.y = f32_to_bf16(tile[ks + j * 4 + 1][n]);
    o.z = f32_to_bf16(tile[ks + j * 4 + 2][n]);
    o.w = f32_to_bf16(tile[ks + j * 4 + 3][n]);
    *reinterpret_cast<ushort4*>(&dst[j * 4]) = o;
  }
}

// ---------------------------------------------------------------------------
// Transpose + SPLIT convert: W [K,N] f32 -> WTh/WTl [N,K] bf16 pair.
// ---------------------------------------------------------------------------
__global__ __launch_bounds__(256) void tcvt2_kernel(
    const float* __restrict__ W, unsigned short* __restrict__ WTh,
    unsigned short* __restrict__ WTl, int K, int N)
{
  __shared__ float tile[64][65];
  const int tid = threadIdx.x;
  const int k0 = blockIdx.y * 64, n0 = blockIdx.x * 64;
#pragma unroll
  for (int i = 0; i < 4; ++i) {
    int u = tid + i * 256;
    int kr = u >> 4, nc = (u & 15) * 4;
    float4 v = *reinterpret_cast<const float4*>(&W[(size_t)(k0 + kr) * N + n0 + nc]);
    tile[kr][nc + 0] = v.x; tile[kr][nc + 1] = v.y;
    tile[kr][nc + 2] = v.z; tile[kr][nc + 3] = v.w;
  }
  __syncthreads();
  int n = tid >> 2, ks = (tid & 3) * 16;
#pragma unroll
  for (int j = 0; j < 4; ++j) {
    ushort4 h4, l4;
    split_bf16(tile[ks + j * 4 + 0][n], h4.x, l4.x);
    split_bf16(tile[ks + j * 4 + 1][n], h4.y, l4.y);
    split_bf16(tile[ks + j * 4 + 2][n], h4.z, l4.z);
    split_bf16(tile[ks + j * 4 + 3][n], h4.w, l4.w);
    *reinterpret_cast<ushort4*>(&WTh[(size_t)(n0 + n) * K + k0 + ks + j * 4]) = h4;
    *reinterpret_cast<ushort4*>(&WTl[(size_t)(n0 + n) * K + k0 + ks + j * 4]) = l4;
  }
}

// ---------------------------------------------------------------------------
// V transpose: vin [BH][S][HD] bf16 -> vout [BH][HD][S] bf16. 64x64 tiles.
// ---------------------------------------------------------------------------
__global__ __launch_bounds__(256) void vtrans_kernel(
    const unsigned short* __restrict__ vin, unsigned short* __restrict__ vout)
{
  __shared__ unsigned short tile[64][76];
  const int tid = threadIdx.x;
  const int st = blockIdx.x;
  const int bh = blockIdx.y;
  const unsigned short* src = vin + ((size_t)bh * S_ + st * 64) * HD_;
  unsigned short* dst = vout + (size_t)bh * HD_ * S_ + st * 64;
#pragma unroll
  for (int i = 0; i < 2; ++i) {
    int u = tid + i * 256;
    int row = u >> 3, unit = u & 7;
    *reinterpret_cast<int4*>(&tile[row][unit * 8]) =
        *reinterpret_cast<const int4*>(&src[(size_t)row * HD_ + unit * 8]);
  }
  __syncthreads();
#pragma unroll
  for (int i = 0; i < 2; ++i) {
    int u = tid + i * 256;
    int d = u >> 3, unit = u & 7;
    unsigned short tmp[8];
#pragma unroll
    for (int j = 0; j < 8; ++j) tmp[j] = tile[unit * 8 + j][d];
    *reinterpret_cast<int4*>(&dst[(size_t)d * S_ + unit * 8]) =
        *reinterpret_cast<const int4*>(tmp);
  }
}

// ---------------------------------------------------------------------------
// bf16 MFMA GEMM, 64x128 tile, BK=32, 4 waves. gload16 staging. LDS 12 KB.
// ---------------------------------------------------------------------------
template<bool GELU, bool RES, bool RESBF16, bool BHSD, bool OBF16>
__global__ __launch_bounds__(256) void gemm_mfma_kernel(
    const unsigned short* __restrict__ A, const unsigned short* __restrict__ BT,
    const float* __restrict__ bias, const void* __restrict__ res,
    void* __restrict__ C, int M, int N, int K)
{
  __shared__ unsigned short As[64][32];
  __shared__ unsigned short Bs[128][32];
  const int tid = threadIdx.x;
  const int wid = tid >> 6;
  const int lane = tid & 63;
  const int bm = blockIdx.y * 64;
  const int bn = blockIdx.x * 128;
  const int l15 = lane & 15;
  const int hi4 = lane >> 4;
  const int kb = hi4 * 8;
  const int srow = lane >> 2;
  const int sseg = (lane & 3) * 8;

  f32x4 acc[8];
#pragma unroll
  for (int ni = 0; ni < 8; ++ni) acc[ni] = (f32x4){0.f, 0.f, 0.f, 0.f};

  for (int k0 = 0; k0 < K; k0 += 32) {
    gload16(&A[(size_t)(bm + wid * 16 + srow) * K + k0 + sseg], &As[wid * 16][0]);
#pragma unroll
    for (int i = 0; i < 2; ++i) {
      int base_row = i * 64 + wid * 16;
      gload16(&BT[(size_t)(bn + base_row + srow) * K + k0 + sseg], &Bs[base_row][0]);
    }
    __syncthreads();

    bf16x8 af = *reinterpret_cast<const bf16x8*>(&As[wid * 16 + l15][kb]);
#pragma unroll
    for (int ni = 0; ni < 8; ++ni) {
      bf16x8 bfr = *reinterpret_cast<const bf16x8*>(&Bs[ni * 16 + l15][kb]);
      acc[ni] = __builtin_amdgcn_mfma_f32_16x16x32_bf16(af, bfr, acc[ni], 0, 0, 0);
    }
    __syncthreads();
  }

#pragma unroll
  for (int ni = 0; ni < 8; ++ni) {
    int gcol = bn + ni * 16 + l15;
    float bsv = bias[gcol];
#pragma unroll
    for (int r = 0; r < 4; ++r) {
      int grow = bm + wid * 16 + hi4 * 4 + r;
      float val = acc[ni][r] + bsv;
      if (GELU) val = gelu_f(val);
      if (RES) {
        if (RESBF16) val += bf16_to_f32(((const unsigned short*)res)[(size_t)grow * N + gcol]);
        else         val += ((const float*)res)[(size_t)grow * N + gcol];
      }
      if (BHSD) {
        int bb = grow >> 10, ss = grow & 1023, hh = gcol >> 6, dd = gcol & 63;
        size_t adr = ((size_t)(bb * H_ + hh) * S_ + ss) * HD_ + dd;
        if (OBF16) ((unsigned short*)C)[adr] = f32_to_bf16(val);
        else       ((float*)C)[adr] = val;
      } else if (OBF16) {
        ((unsigned short*)C)[(size_t)grow * N + gcol] = f32_to_bf16(val);
      } else {
        ((float*)C)[(size_t)grow * N + gcol] = val;
      }
    }
  }
}

// ---------------------------------------------------------------------------
// Split-f32 MFMA GEMM, pre-split inputs, 64x128 tile, BK=32. LDS 24 KB.
// ---------------------------------------------------------------------------
__global__ __launch_bounds__(256) void gemm_mfma3_kernel(
    const unsigned short* __restrict__ Ah_g, const unsigned short* __restrict__ Al_g,
    const unsigned short* __restrict__ Bh_g, const unsigned short* __restrict__ Bl_g,
    const float* __restrict__ bias, unsigned short* __restrict__ Ch,
    unsigned short* __restrict__ Cl, int M, int N, int K)
{
  __shared__ unsigned short Ah[64][32], Al[64][32];
  __shared__ unsigned short Bh[128][32], Bl[128][32];
  const int tid = threadIdx.x;
  const int wid = tid >> 6;
  const int lane = tid & 63;
  const int bm = blockIdx.y * 64;
  const int bn = blockIdx.x * 128;
  const int l15 = lane & 15;
  const int hi4 = lane >> 4;
  const int kb = hi4 * 8;
  const int srow = lane >> 2;
  const int sseg = (lane & 3) * 8;

  f32x4 acc[8];
#pragma unroll
  for (int ni = 0; ni < 8; ++ni) acc[ni] = (f32x4){0.f, 0.f, 0.f, 0.f};

  for (int k0 = 0; k0 < K; k0 += 32) {
    {
      size_t ga = (size_t)(bm + wid * 16 + srow) * K + k0 + sseg;
      gload16(&Ah_g[ga], &Ah[wid * 16][0]);
      gload16(&Al_g[ga], &Al[wid * 16][0]);
    }
#pragma unroll
    for (int i = 0; i < 2; ++i) {
      int base_row = i * 64 + wid * 16;
      size_t gb = (size_t)(bn + base_row + srow) * K + k0 + sseg;
      gload16(&Bh_g[gb], &Bh[base_row][0]);
      gload16(&Bl_g[gb], &Bl[base_row][0]);
    }
    __syncthreads();

    bf16x8 ahf = *reinterpret_cast<const bf16x8*>(&Ah[wid * 16 + l15][kb]);
    bf16x8 alf = *reinterpret_cast<const bf16x8*>(&Al[wid * 16 + l15][kb]);
#pragma unroll
    for (int ni = 0; ni < 8; ++ni) {
      bf16x8 bh = *reinterpret_cast<const bf16x8*>(&Bh[ni * 16 + l15][kb]);
      bf16x8 bl = *reinterpret_cast<const bf16x8*>(&Bl[ni * 16 + l15][kb]);
      acc[ni] = __builtin_amdgcn_mfma_f32_16x16x32_bf16(ahf, bh, acc[ni], 0, 0, 0);
      acc[ni] = __builtin_amdgcn_mfma_f32_16x16x32_bf16(alf, bh, acc[ni], 0, 0, 0);
      acc[ni] = __builtin_amdgcn_mfma_f32_16x16x32_bf16(ahf, bl, acc[ni], 0, 0, 0);
    }
    __syncthreads();
  }

#pragma unroll
  for (int ni = 0; ni < 8; ++ni) {
    int gcol = bn + ni * 16 + l15;
    float bsv = bias[gcol];
#pragma unroll
    for (int r = 0; r < 4; ++r) {
      int grow = bm + wid * 16 + hi4 * 4 + r;
      float val = acc[ni][r] + bsv;
      int bb = grow >> 10, ss = grow & 1023, hh = gcol >> 6, dd = gcol & 63;
      size_t adr = ((size_t)(bb * H_ + hh) * S_ + ss) * HD_ + dd;
      unsigned short hh2, ll2;
      split_bf16(val, hh2, ll2);
      Ch[adr] = hh2;
      Cl[adr] = ll2;
    }
  }
}

// ---------------------------------------------------------------------------
// Attention scores + rel + mask + softmax -> probs f32.
// 512 threads = 8 waves: 2 q-groups (16 rows each) x 4 k-strip waves.
// K tiles shared in LDS across both q-groups. LDS ~54 KB.
// ---------------------------------------------------------------------------
__global__ __launch_bounds__(512) void attn_kernel(
    const unsigned short* __restrict__ qkh, const unsigned short* __restrict__ qkl,
    const int* __restrict__ mask, const float* __restrict__ rel_emb,
    float* __restrict__ probs)
{
  __shared__ unsigned short Qh[32][72], Ql[32][72];
  __shared__ unsigned short Kh[128][72], Kl[128][72];
  __shared__ float relp[32][24];
  __shared__ float red1[8][16], red2[8][16];
  __shared__ int msk[1024];

  const int tid = threadIdx.x;
  const int b = blockIdx.z, h = blockIdx.y, qt = blockIdx.x;
  const size_t bhoff = (size_t)(b * H_ + h) * S_ * HD_;
  const unsigned short* qh = qkh + bhoff;
  const unsigned short* ql = qkl + bhoff;
  const int q0 = qt * 32;

  for (int i = tid; i < 1024; i += 512) msk[i] = mask[b * S_ + i];

  if (tid < 256) {
    int row = tid >> 3, seg = (tid & 7) * 8;
    *reinterpret_cast<int4*>(&Qh[row][seg]) =
        *reinterpret_cast<const int4*>(&qh[(size_t)(q0 + row) * HD_ + seg]);
    *reinterpret_cast<int4*>(&Ql[row][seg]) =
        *reinterpret_cast<const int4*>(&ql[(size_t)(q0 + row) * HD_ + seg]);
  }
  __syncthreads();

  for (int idx = tid; idx < 32 * 21; idx += 512) {
    int q = idx / 21, r = idx - q * 21;
    float s = 0.f;
#pragma unroll 8
    for (int d = 0; d < 64; ++d) {
      float qf = bf16_to_f32(Qh[q][d]) + bf16_to_f32(Ql[q][d]);
      s += qf * rel_emb[r * 64 + d];
    }
    relp[q][r] = s;
  }

  const int qg = tid >> 8;
  const int wv = (tid >> 6) & 3;
  const int lane = tid & 63;
  const int l15 = lane & 15;
  const int hi4 = lane >> 4;
  const int kb = hi4 * 8;

  bf16x8 ah[2], al[2];
#pragma unroll
  for (int ks = 0; ks < 2; ++ks) {
    ah[ks] = *reinterpret_cast<const bf16x8*>(&Qh[qg * 16 + l15][ks * 32 + kb]);
    al[ks] = *reinterpret_cast<const bf16x8*>(&Ql[qg * 16 + l15][ks * 32 + kb]);
  }

  f32x4 acc[8][2];
#pragma unroll
  for (int t = 0; t < 8; ++t)
#pragma unroll
    for (int f = 0; f < 2; ++f) acc[t][f] = (f32x4){0.f, 0.f, 0.f, 0.f};

#pragma unroll
  for (int kt = 0; kt < 8; ++kt) {
    __syncthreads();
#pragma unroll
    for (int i = 0; i < 2; ++i) {
      int u = tid + i * 512;
      int row = u >> 3, seg = (u & 7) * 8;
      *reinterpret_cast<int4*>(&Kh[row][seg]) =
          *reinterpret_cast<const int4*>(&qh[(size_t)(kt * 128 + row) * HD_ + seg]);
      *reinterpret_cast<int4*>(&Kl[row][seg]) =
          *reinterpret_cast<const int4*>(&ql[(size_t)(kt * 128 + row) * HD_ + seg]);
    }
    __syncthreads();

#pragma unroll
    for (int f = 0; f < 2; ++f) {
      int cb = wv * 32 + f * 16;
#pragma unroll
      for (int ks = 0; ks < 2; ++ks) {
        bf16x8 bh = *reinterpret_cast<const bf16x8*>(&Kh[cb + l15][ks * 32 + kb]);
        bf16x8 bl = *reinterpret_cast<const bf16x8*>(&Kl[cb + l15][ks * 32 + kb]);
        acc[kt][f] = __builtin_amdgcn_mfma_f32_16x16x32_bf16(ah[ks], bh, acc[kt][f], 0, 0, 0);
        acc[kt][f] = __builtin_amdgcn_mfma_f32_16x16x32_bf16(al[ks], bh, acc[kt][f], 0, 0, 0);
        acc[kt][f] = __builtin_amdgcn_mfma_f32_16x16x32_bf16(ah[ks], bl, acc[kt][f], 0, 0, 0);
      }
    }
  }
  __syncthreads();

  float mx[4] = {-3.0e38f, -3.0e38f, -3.0e38f, -3.0e38f};
#pragma unroll
  for (int t = 0; t < 8; ++t)
#pragma unroll
    for (int f = 0; f < 2; ++f)
#pragma unroll
      for (int r = 0; r < 4; ++r) {
        int qlc = qg * 16 + hi4 * 4 + r;
        int q = q0 + qlc;
        int k = t * 128 + wv * 32 + f * 16 + l15;
        int d = k - q;
        int ridx = (d < -10 ? -10 : (d > 10 ? 10 : d)) + 10;
        float s = acc[t][f][r] + relp[qlc][ridx];
        if (k == q || msk[k] == 0) s -= 10000.0f;
        acc[t][f][r] = s;
        mx[r] = fmaxf(mx[r], s);
      }
#pragma unroll
  for (int r = 0; r < 4; ++r) {
    mx[r] = fmaxf(mx[r], __shfl_xor(mx[r], 1));
    mx[r] = fmaxf(mx[r], __shfl_xor(mx[r], 2));
    mx[r] = fmaxf(mx[r], __shfl_xor(mx[r], 4));
    mx[r] = fmaxf(mx[r], __shfl_xor(mx[r], 8));
  }
  {
    int wrow = qg * 4 + wv;
    if (l15 == 0) {
#pragma unroll
      for (int r = 0; r < 4; ++r) red1[wrow][hi4 * 4 + r] = mx[r];
    }
  }
  __syncthreads();
  float mxq[4];
#pragma unroll
  for (int r = 0; r < 4; ++r) {
    int ql16 = hi4 * 4 + r;
    mxq[r] = fmaxf(fmaxf(red1[qg * 4 + 0][ql16], red1[qg * 4 + 1][ql16]),
                   fmaxf(red1[qg * 4 + 2][ql16], red1[qg * 4 + 3][ql16]));
  }

  float sm[4] = {0.f, 0.f, 0.f, 0.f};
#pragma unroll
  for (int t = 0; t < 8; ++t)
#pragma unroll
    for (int f = 0; f < 2; ++f)
#pragma unroll
      for (int r = 0; r < 4; ++r) {
        float e = __expf(acc[t][f][r] - mxq[r]);
        acc[t][f][r] = e;
        sm[r] += e;
      }
#pragma unroll
  for (int r = 0; r < 4; ++r) {
    sm[r] += __shfl_xor(sm[r], 1);
    sm[r] += __shfl_xor(sm[r], 2);
    sm[r] += __shfl_xor(sm[r], 4);
    sm[r] += __shfl_xor(sm[r], 8);
  }
  {
    int wrow = qg * 4 + wv;
    if (l15 == 0) {
#pragma unroll
      for (int r = 0; r < 4; ++r) red2[wrow][hi4 * 4 + r] = sm[r];
    }
  }
  __syncthreads();
  float rinv[4];
#pragma unroll
  for (int r = 0; r < 4; ++r) {
    int ql16 = hi4 * 4 + r;
    rinv[r] = 1.0f / (red2[qg * 4 + 0][ql16] + red2[qg * 4 + 1][ql16] +
                      red2[qg * 4 + 2][ql16] + red2[qg * 4 + 3][ql16]);
  }

  float* pb = probs + (size_t)(b * H_ + h) * S_ * S_;
#pragma unroll
  for (int t = 0; t < 8; ++t)
#pragma unroll
    for (int f = 0; f < 2; ++f)
#pragma unroll
      for (int r = 0; r < 4; ++r) {
        int qlc = qg * 16 + hi4 * 4 + r;
        int kg = wv * 32 + f * 16 + l15;
        pb[(size_t)(q0 + qlc) * S_ + t * 128 + kg] = acc[t][f][r] * rinv[r];
      }
}

// ---------------------------------------------------------------------------
// PV, zero-LDS: ctx = P @ V. A-fragments direct from probs f32, B-fragments
// direct from pre-transposed vbt [BH][HD][S]. No barriers, no LDS.
// ---------------------------------------------------------------------------
__global__ __launch_bounds__(256) void pv_direct_kernel(
    const float* __restrict__ probs, const unsigned short* __restrict__ vbt,
    unsigned short* __restrict__ ctxb)
{
  const int tid = threadIdx.x;
  const int wv = tid >> 6;
  const int lane = tid & 63;
  const int l15 = lane & 15;
  const int hi4 = lane >> 4;
  const int b = blockIdx.z, h = blockIdx.y, qt = blockIdx.x;
  const float* pr = probs + (size_t)(b * H_ + h) * S_ * S_
                          + (size_t)(qt * 128 + wv * 32) * S_;
  const unsigned short* vtb = vbt + (size_t)(b * H_ + h) * HD_ * S_;

  f32x4 acc[2][4];
#pragma unroll
  for (int mi = 0; mi < 2; ++mi)
#pragma unroll
    for (int ni = 0; ni < 4; ++ni) acc[mi][ni] = (f32x4){0.f, 0.f, 0.f, 0.f};

  for (int k0 = 0; k0 < S_; k0 += 32) {
    bf16x8 af[2];
#pragma unroll
    for (int mi = 0; mi < 2; ++mi) {
      const float* prow = pr + (size_t)(mi * 16 + l15) * S_ + k0 + hi4 * 8;
      float4 p0 = *reinterpret_cast<const float4*>(prow);
      float4 p1 = *reinterpret_cast<const float4*>(prow + 4);
      bf16x8 a;
      a[0] = (short)f32_to_bf16(p0.x); a[1] = (short)f32_to_bf16(p0.y);
      a[2] = (short)f32_to_bf16(p0.z); a[3] = (short)f32_to_bf16(p0.w);
      a[4] = (short)f32_to_bf16(p1.x); a[5] = (short)f32_to_bf16(p1.y);
      a[6] = (short)f32_to_bf16(p1.z); a[7] = (short)f32_to_bf16(p1.w);
      af[mi] = a;
    }
#pragma unroll
    for (int ni = 0; ni < 4; ++ni) {
      bf16x8 vf = *reinterpret_cast<const bf16x8*>(
          &vtb[(size_t)(ni * 16 + l15) * S_ + k0 + hi4 * 8]);
      acc[0][ni] = __builtin_amdgcn_mfma_f32_16x16x32_bf16(af[0], vf, acc[0][ni], 0, 0, 0);
      acc[1][ni] = __builtin_amdgcn_mfma_f32_16x16x32_bf16(af[1], vf, acc[1][ni], 0, 0, 0);
    }
  }

#pragma unroll
  for (int mi = 0; mi < 2; ++mi)
#pragma unroll
    for (int ni = 0; ni < 4; ++ni) {
      int dd = ni * 16 + l15;
#pragma unroll
      for (int r = 0; r < 4; ++r) {
        int q = qt * 128 + wv * 32 + mi * 16 + hi4 * 4 + r;
        ctxb[((size_t)b * S_ + q) * DM_ + h * HD_ + dd] = f32_to_bf16(acc[mi][ni][r]);
      }
    }
}

// ---------------------------------------------------------------------------
// Row LayerNorm (1024 cols), f32 in, f32 or bf16 out (safe in-place for f32)
// ---------------------------------------------------------------------------
template<bool OUTB16>
__global__ __launch_bounds__(256) void ln_kernel(
    const float* __restrict__ in, const float* __restrict__ g,
    const float* __restrict__ be, void* __restrict__ out)
{
  __shared__ float red[4];
  const int row = blockIdx.x, tid = threadIdx.x;
  const float* r = in + (size_t)row * DM_;
  float4 x = *reinterpret_cast<const float4*>(&r[tid * 4]);

  float s = x.x + x.y + x.z + x.w;
#pragma unroll
  for (int m = 1; m < 64; m <<= 1) s += __shfl_xor(s, m);
  if ((tid & 63) == 0) red[tid >> 6] = s;
  __syncthreads();
  float mean = (red[0] + red[1] + red[2] + red[3]) * (1.0f / 1024.0f);
  __syncthreads();

  float d0 = x.x - mean, d1 = x.y - mean, d2 = x.z - mean, d3 = x.w - mean;
  float sq = d0 * d0 + d1 * d1 + d2 * d2 + d3 * d3;
#pragma unroll
  for (int m = 1; m < 64; m <<= 1) sq += __shfl_xor(sq, m);
  if ((tid & 63) == 0) red[tid >> 6] = sq;
  __syncthreads();
  float var = (red[0] + red[1] + red[2] + red[3]) * (1.0f / 1024.0f);
  float rstd = rsqrtf(var + 1e-3f);

  int c = tid * 4;
  float4 gv = *reinterpret_cast<const float4*>(&g[c]);
  float4 bv = *reinterpret_cast<const float4*>(&be[c]);
  float y0 = d0 * rstd * gv.x + bv.x;
  float y1 = d1 * rstd * gv.y + bv.y;
  float y2 = d2 * rstd * gv.z + bv.z;
  float y3 = d3 * rstd * gv.w + bv.w;
  if (OUTB16) {
    ushort4 o;
    o.x = f32_to_bf16(y0); o.y = f32_to_bf16(y1);
    o.z = f32_to_bf16(y2); o.w = f32_to_bf16(y3);
    *reinterpret_cast<ushort4*>(&((unsigned short*)out)[(size_t)row * DM_ + c]) = o;
  } else {
    *reinterpret_cast<float4*>(&((float*)out)[(size_t)row * DM_ + c]) =
        make_float4(y0, y1, y2, y3);
  }
}

// ---------------------------------------------------------------------------
// Workspace plan (64 MB, offsets in MB; overlays lifetime-checked):
//   0-8   WoT bf16       (prep -> Wo)
//   8-16  WiT bf16       (prep -> Wi)
//   16-18 WvT bf16       (prep -> Wv)
//   18-20 WapT bf16      (prep -> Wap)
//   20-22 WqkTh, 22-24 WqkTl  (prep -> qkproj)
//   24-32 xh bf16        (prep -> Wv proj & qkproj), then vbt (vtrans -> pv)
//   32-40 xl bf16        (prep -> qkproj), then ctxb bf16 (pv -> Wap)
//   40-48 qk_hi bf16     (qkproj -> attn)
//   48-56 qk_lo bf16     (qkproj -> attn)
//   40-56 y f32          (Wap -> ln1)   [qk_hi/lo dead]
//   56-64 vb bf16        (Wv -> vtrans)
//   20-28 attnb bf16     (ln1 -> Wo)    [WqkT + vbt dead]
//   32-64 interb bf16    (Wi -> Wo)     [ctxb/y/vb dead]
//   t = outf (d_out); ln2 in place.
// ---------------------------------------------------------------------------
extern "C" void kernel_launch(void* const* d_in, const int* in_sizes, int n_in,
                              void* d_out, int out_size, void* d_ws, size_t ws_size,
                              hipStream_t stream) {
  const float* x    = (const float*)d_in[0];
  const int*   mask = (const int*)d_in[1];
  const float* Wqk  = (const float*)d_in[2];
  const float* bqk  = (const float*)d_in[3];
  const float* Wv   = (const float*)d_in[4];
  const float* bv   = (const float*)d_in[5];
  const float* rel  = (const float*)d_in[6];
  const float* Wap  = (const float*)d_in[7];
  const float* bap  = (const float*)d_in[8];
  const float* g1   = (const float*)d_in[9];
  const float* b1   = (const float*)d_in[10];
  const float* Wi   = (const float*)d_in[11];
  const float* bi   = (const float*)d_in[12];
  const float* Wo   = (const float*)d_in[13];
  const float* bo   = (const float*)d_in[14];
  const float* g2   = (const float*)d_in[15];
  const float* b2   = (const float*)d_in[16];

  char* wsb = (char*)d_ws;
  const size_t MB = 1048576;
  unsigned short* WoT    = (unsigned short*)(wsb + 0 * MB);
  unsigned short* WiT    = (unsigned short*)(wsb + 8 * MB);
  unsigned short* WvT    = (unsigned short*)(wsb + 16 * MB);
  unsigned short* WapT   = (unsigned short*)(wsb + 18 * MB);
  unsigned short* WqkTh  = (unsigned short*)(wsb + 20 * MB);
  unsigned short* WqkTl  = (unsigned short*)(wsb + 22 * MB);
  unsigned short* xh     = (unsigned short*)(wsb + 24 * MB);
  unsigned short* vbt    = (unsigned short*)(wsb + 24 * MB);
  unsigned short* xl     = (unsigned short*)(wsb + 32 * MB);
  unsigned short* ctxb   = (unsigned short*)(wsb + 32 * MB);
  unsigned short* qk_hi  = (unsigned short*)(wsb + 40 * MB);
  unsigned short* qk_lo  = (unsigned short*)(wsb + 48 * MB);
  float*          y      = (float*)(wsb + 40 * MB);
  unsigned short* vb     = (unsigned short*)(wsb + 56 * MB);
  unsigned short* attnb  = (unsigned short*)(wsb + 20 * MB);
  unsigned short* interb = (unsigned short*)(wsb + 32 * MB);

  float* outf  = (float*)d_out;        // out   [B,S,DM]  f32 (also t buffer)
  float* probs = outf + 4194304;       // probs [B,H,S,S] f32

  dim3 blk(256);
  // Preps
  cvt_split_kernel<<<4096, blk, 0, stream>>>(x, xh, xl, 1048576);
  tcvt_kernel<<<dim3(16, 16), blk, 0, stream>>>(Wv,  WvT,  1024, 1024);
  tcvt_kernel<<<dim3(16, 16), blk, 0, stream>>>(Wap, WapT, 1024, 1024);
  tcvt_kernel<<<dim3(64, 16), blk, 0, stream>>>(Wi,  WiT,  1024, 4096);
  tcvt_kernel<<<dim3(16, 64), blk, 0, stream>>>(Wo,  WoT,  4096, 1024);
  tcvt2_kernel<<<dim3(16, 16), blk, 0, stream>>>(Wqk, WqkTh, WqkTl, 1024, 1024);

  // q/k shared projection (pre-split 3-MFMA) -> qk hi/lo bf16 [B,H,S,HD]
  gemm_mfma3_kernel<<<dim3(8, 64), blk, 0, stream>>>(
      xh, xl, WqkTh, WqkTl, bqk, qk_hi, qk_lo, 4096, 1024, 1024);
  // v projection (bf16 MFMA) -> [B,H,S,HD] bf16
  gemm_mfma_kernel<false, false, false, true, true><<<dim3(8, 64), blk, 0, stream>>>(
      xh, WvT, bv, nullptr, vb, 4096, 1024, 1024);
  // V transpose -> [B,H,HD,S]  (xh dead now)
  vtrans_kernel<<<dim3(16, 64), blk, 0, stream>>>(vb, vbt);
  // scores + rel + mask + softmax -> probs f32 (32 q-rows/block, 8 waves)
  attn_kernel<<<dim3(32, 16, 4), dim3(512), 0, stream>>>(
      qk_hi, qk_lo, mask, rel, probs);
  // ctx = probs @ v (zero-LDS direct fragments) -> bf16 [B,S,DM]
  pv_direct_kernel<<<dim3(8, 16, 4), blk, 0, stream>>>(probs, vbt, ctxb);
  // y = gelu(ctx @ Wap + bap) + x
  gemm_mfma_kernel<true, true, false, false, false><<<dim3(8, 64), blk, 0, stream>>>(
      ctxb, WapT, bap, x, y, 4096, 1024, 1024);
  // attnb = LN(y)*g1+b1 (bf16)
  ln_kernel<true><<<4096, blk, 0, stream>>>(y, g1, b1, attnb);
  // inter = gelu(attn @ Wi + bi) (bf16)
  gemm_mfma_kernel<true, false, false, false, true><<<dim3(32, 64), blk, 0, stream>>>(
      attnb, WiT, bi, nullptr, interb, 4096, 4096, 1024);
  // outf = gelu(inter @ Wo + bo) + attn   (t lives in d_out)
  gemm_mfma_kernel<true, true, true, false, false><<<dim3(8, 64), blk, 0, stream>>>(
      interb, WoT, bo, attnb, outf, 4096, 1024, 4096);
  // out = LN(t)*g2+b2 (f32, in place)
  ln_kernel<false><<<4096, blk, 0, stream>>>(outf, g2, b2, outf);
}

// Round 18
// 538.717 us; speedup vs baseline: 1.1055x; 1.0167x over previous
//
#include <hip/hip_runtime.h>
#include <hip/hip_bf16.h>

// Sizes (fixed for this problem)
#define B_  4
#define S_  1024
#define DM_ 1024
#define H_  16
#define HD_ 64
#define I_  4096

typedef __attribute__((ext_vector_type(8))) short bf16x8;
typedef __attribute__((ext_vector_type(4))) float f32x4;

__device__ __forceinline__ float gelu_f(float x) {
  float x3 = x * x * x;
  return 0.5f * x * (1.0f + tanhf(0.7978845608028654f * (x + 0.044715f * x3)));
}

__device__ __forceinline__ unsigned short f32_to_bf16(float f) {
  unsigned int u = __float_as_uint(f);
  unsigned int rounding = 0x7FFFu + ((u >> 16) & 1u);
  u += rounding;
  return (unsigned short)(u >> 16);
}

__device__ __forceinline__ float bf16_to_f32(unsigned short u) {
  return __uint_as_float(((unsigned int)u) << 16);
}

__device__ __forceinline__ void split_bf16(float v, unsigned short& h, unsigned short& l) {
  h = f32_to_bf16(v);
  l = f32_to_bf16(v - bf16_to_f32(h));
}

// Direct global->LDS DMA, 16 B per lane.
__device__ __forceinline__ void gload16(const void* g, void* l) {
  __builtin_amdgcn_global_load_lds(
      (const __attribute__((address_space(1))) void*)g,
      (__attribute__((address_space(3))) void*)l, 16, 0, 0);
}

// ---------------------------------------------------------------------------
// Merged prep kernel: one launch replaces cvt_split + 4x tcvt + tcvt2.
// Sections by blockIdx.x:
//   [0,4096)      cvt_split (x -> xh,xl)
//   [4096,4352)   tcvt Wv   (16x16)
//   [4352,4608)   tcvt Wap  (16x16)
//   [4608,5632)   tcvt Wi   (64x16)
//   [5632,6656)   tcvt Wo   (16x64)
//   [6656,6912)   tcvt2 Wqk (16x16)
// ---------------------------------------------------------------------------
__device__ __forceinline__ void tcvt_body(
    const float* __restrict__ W, unsigned short* __restrict__ WT,
    int K, int N, int bx, int by, float (*tile)[65], int tid)
{
  const int k0 = by * 64, n0 = bx * 64;
#pragma unroll
  for (int i = 0; i < 4; ++i) {
    int u = tid + i * 256;
    int kr = u >> 4, nc = (u & 15) * 4;
    float4 v = *reinterpret_cast<const float4*>(&W[(size_t)(k0 + kr) * N + n0 + nc]);
    tile[kr][nc + 0] = v.x; tile[kr][nc + 1] = v.y;
    tile[kr][nc + 2] = v.z; tile[kr][nc + 3] = v.w;
  }
  __syncthreads();
  int n = tid >> 2, ks = (tid & 3) * 16;
  unsigned short* dst = &WT[(size_t)(n0 + n) * K + k0 + ks];
#pragma unroll
  for (int j = 0; j < 4; ++j) {
    ushort4 o;
    o.x = f32_to_bf16(tile[ks + j * 4 + 0][n]);
    o.y = f32_to_bf16(tile[ks + j * 4 + 1][n]);
    o.z = f32_to_bf16(tile[ks + j * 4 + 2][n]);
    o.w = f32_to_bf16(tile[ks + j * 4 + 3][n]);
    *reinterpret_cast<ushort4*>(&dst[j * 4]) = o;
  }
}

__device__ __forceinline__ void tcvt2_body(
    const float* __restrict__ W, unsigned short* __restrict__ WTh,
    unsigned short* __restrict__ WTl, int K, int N, int bx, int by,
    float (*tile)[65], int tid)
{
  const int k0 = by * 64, n0 = bx * 64;
#pragma unroll
  for (int i = 0; i < 4; ++i) {
    int u = tid + i * 256;
    int kr = u >> 4, nc = (u & 15) * 4;
    float4 v = *reinterpret_cast<const float4*>(&W[(size_t)(k0 + kr) * N + n0 + nc]);
    tile[kr][nc + 0] = v.x; tile[kr][nc + 1] = v.y;
    tile[kr][nc + 2] = v.z; tile[kr][nc + 3] = v.w;
  }
  __syncthreads();
  int n = tid >> 2, ks = (tid & 3) * 16;
#pragma unroll
  for (int j = 0; j < 4; ++j) {
    ushort4 h4, l4;
    split_bf16(tile[ks + j * 4 + 0][n], h4.x, l4.x);
    split_bf16(tile[ks + j * 4 + 1][n], h4.y, l4.y);
    split_bf16(tile[ks + j * 4 + 2][n], h4.z, l4.z);
    split_bf16(tile[ks + j * 4 + 3][n], h4.w, l4.w);
    *reinterpret_cast<ushort4*>(&WTh[(size_t)(n0 + n) * K + k0 + ks + j * 4]) = h4;
    *reinterpret_cast<ushort4*>(&WTl[(size_t)(n0 + n) * K + k0 + ks + j * 4]) = l4;
  }
}

__global__ __launch_bounds__(256) void prep_kernel(
    const float* __restrict__ x, unsigned short* __restrict__ xh,
    unsigned short* __restrict__ xl,
    const float* __restrict__ Wv,  unsigned short* __restrict__ WvT,
    const float* __restrict__ Wap, unsigned short* __restrict__ WapT,
    const float* __restrict__ Wi,  unsigned short* __restrict__ WiT,
    const float* __restrict__ Wo,  unsigned short* __restrict__ WoT,
    const float* __restrict__ Wqk, unsigned short* __restrict__ WqkTh,
    unsigned short* __restrict__ WqkTl)
{
  __shared__ float tile[64][65];
  const int blk = blockIdx.x;
  const int tid = threadIdx.x;

  if (blk < 4096) {
    int i = blk * 256 + tid;   // n4 = 1048576 = 4096*256, always in range
    float4 v = *reinterpret_cast<const float4*>(&x[(size_t)i * 4]);
    ushort4 h4, l4;
    split_bf16(v.x, h4.x, l4.x); split_bf16(v.y, h4.y, l4.y);
    split_bf16(v.z, h4.z, l4.z); split_bf16(v.w, h4.w, l4.w);
    *reinterpret_cast<ushort4*>(&xh[(size_t)i * 4]) = h4;
    *reinterpret_cast<ushort4*>(&xl[(size_t)i * 4]) = l4;
  } else if (blk < 4352) {
    int b = blk - 4096;   // grid was (16,16)
    tcvt_body(Wv, WvT, 1024, 1024, b & 15, b >> 4, tile, tid);
  } else if (blk < 4608) {
    int b = blk - 4352;
    tcvt_body(Wap, WapT, 1024, 1024, b & 15, b >> 4, tile, tid);
  } else if (blk < 5632) {
    int b = blk - 4608;   // grid was (64,16)
    tcvt_body(Wi, WiT, 1024, 4096, b & 63, b >> 6, tile, tid);
  } else if (blk < 6656) {
    int b = blk - 5632;   // grid was (16,64)
    tcvt_body(Wo, WoT, 4096, 1024, b & 15, b >> 4, tile, tid);
  } else {
    int b = blk - 6656;
    tcvt2_body(Wqk, WqkTh, WqkTl, 1024, 1024, b & 15, b >> 4, tile, tid);
  }
}

// ---------------------------------------------------------------------------
// V transpose: vin [BH][S][HD] bf16 -> vout [BH][HD][S] bf16. 64x64 tiles.
// ---------------------------------------------------------------------------
__global__ __launch_bounds__(256) void vtrans_kernel(
    const unsigned short* __restrict__ vin, unsigned short* __restrict__ vout)
{
  __shared__ unsigned short tile[64][76];
  const int tid = threadIdx.x;
  const int st = blockIdx.x;
  const int bh = blockIdx.y;
  const unsigned short* src = vin + ((size_t)bh * S_ + st * 64) * HD_;
  unsigned short* dst = vout + (size_t)bh * HD_ * S_ + st * 64;
#pragma unroll
  for (int i = 0; i < 2; ++i) {
    int u = tid + i * 256;
    int row = u >> 3, unit = u & 7;
    *reinterpret_cast<int4*>(&tile[row][unit * 8]) =
        *reinterpret_cast<const int4*>(&src[(size_t)row * HD_ + unit * 8]);
  }
  __syncthreads();
#pragma unroll
  for (int i = 0; i < 2; ++i) {
    int u = tid + i * 256;
    int d = u >> 3, unit = u & 7;
    unsigned short tmp[8];
#pragma unroll
    for (int j = 0; j < 8; ++j) tmp[j] = tile[unit * 8 + j][d];
    *reinterpret_cast<int4*>(&dst[(size_t)d * S_ + unit * 8]) =
        *reinterpret_cast<const int4*>(tmp);
  }
}

// ---------------------------------------------------------------------------
// bf16 MFMA GEMM, 64x128 tile, BK=32, 4 waves. gload16 staging. LDS 12 KB.
// ---------------------------------------------------------------------------
template<bool GELU, bool RES, bool RESBF16, bool BHSD, bool OBF16>
__global__ __launch_bounds__(256) void gemm_mfma_kernel(
    const unsigned short* __restrict__ A, const unsigned short* __restrict__ BT,
    const float* __restrict__ bias, const void* __restrict__ res,
    void* __restrict__ C, int M, int N, int K)
{
  __shared__ unsigned short As[64][32];
  __shared__ unsigned short Bs[128][32];
  const int tid = threadIdx.x;
  const int wid = tid >> 6;
  const int lane = tid & 63;
  const int bm = blockIdx.y * 64;
  const int bn = blockIdx.x * 128;
  const int l15 = lane & 15;
  const int hi4 = lane >> 4;
  const int kb = hi4 * 8;
  const int srow = lane >> 2;
  const int sseg = (lane & 3) * 8;

  f32x4 acc[8];
#pragma unroll
  for (int ni = 0; ni < 8; ++ni) acc[ni] = (f32x4){0.f, 0.f, 0.f, 0.f};

  for (int k0 = 0; k0 < K; k0 += 32) {
    gload16(&A[(size_t)(bm + wid * 16 + srow) * K + k0 + sseg], &As[wid * 16][0]);
#pragma unroll
    for (int i = 0; i < 2; ++i) {
      int base_row = i * 64 + wid * 16;
      gload16(&BT[(size_t)(bn + base_row + srow) * K + k0 + sseg], &Bs[base_row][0]);
    }
    __syncthreads();

    bf16x8 af = *reinterpret_cast<const bf16x8*>(&As[wid * 16 + l15][kb]);
#pragma unroll
    for (int ni = 0; ni < 8; ++ni) {
      bf16x8 bfr = *reinterpret_cast<const bf16x8*>(&Bs[ni * 16 + l15][kb]);
      acc[ni] = __builtin_amdgcn_mfma_f32_16x16x32_bf16(af, bfr, acc[ni], 0, 0, 0);
    }
    __syncthreads();
  }

#pragma unroll
  for (int ni = 0; ni < 8; ++ni) {
    int gcol = bn + ni * 16 + l15;
    float bsv = bias[gcol];
#pragma unroll
    for (int r = 0; r < 4; ++r) {
      int grow = bm + wid * 16 + hi4 * 4 + r;
      float val = acc[ni][r] + bsv;
      if (GELU) val = gelu_f(val);
      if (RES) {
        if (RESBF16) val += bf16_to_f32(((const unsigned short*)res)[(size_t)grow * N + gcol]);
        else         val += ((const float*)res)[(size_t)grow * N + gcol];
      }
      if (BHSD) {
        int bb = grow >> 10, ss = grow & 1023, hh = gcol >> 6, dd = gcol & 63;
        size_t adr = ((size_t)(bb * H_ + hh) * S_ + ss) * HD_ + dd;
        if (OBF16) ((unsigned short*)C)[adr] = f32_to_bf16(val);
        else       ((float*)C)[adr] = val;
      } else if (OBF16) {
        ((unsigned short*)C)[(size_t)grow * N + gcol] = f32_to_bf16(val);
      } else {
        ((float*)C)[(size_t)grow * N + gcol] = val;
      }
    }
  }
}

// ---------------------------------------------------------------------------
// Split-f32 MFMA GEMM, pre-split inputs, 64x128 tile, BK=32. LDS 24 KB.
// ---------------------------------------------------------------------------
__global__ __launch_bounds__(256) void gemm_mfma3_kernel(
    const unsigned short* __restrict__ Ah_g, const unsigned short* __restrict__ Al_g,
    const unsigned short* __restrict__ Bh_g, const unsigned short* __restrict__ Bl_g,
    const float* __restrict__ bias, unsigned short* __restrict__ Ch,
    unsigned short* __restrict__ Cl, int M, int N, int K)
{
  __shared__ unsigned short Ah[64][32], Al[64][32];
  __shared__ unsigned short Bh[128][32], Bl[128][32];
  const int tid = threadIdx.x;
  const int wid = tid >> 6;
  const int lane = tid & 63;
  const int bm = blockIdx.y * 64;
  const int bn = blockIdx.x * 128;
  const int l15 = lane & 15;
  const int hi4 = lane >> 4;
  const int kb = hi4 * 8;
  const int srow = lane >> 2;
  const int sseg = (lane & 3) * 8;

  f32x4 acc[8];
#pragma unroll
  for (int ni = 0; ni < 8; ++ni) acc[ni] = (f32x4){0.f, 0.f, 0.f, 0.f};

  for (int k0 = 0; k0 < K; k0 += 32) {
    {
      size_t ga = (size_t)(bm + wid * 16 + srow) * K + k0 + sseg;
      gload16(&Ah_g[ga], &Ah[wid * 16][0]);
      gload16(&Al_g[ga], &Al[wid * 16][0]);
    }
#pragma unroll
    for (int i = 0; i < 2; ++i) {
      int base_row = i * 64 + wid * 16;
      size_t gb = (size_t)(bn + base_row + srow) * K + k0 + sseg;
      gload16(&Bh_g[gb], &Bh[base_row][0]);
      gload16(&Bl_g[gb], &Bl[base_row][0]);
    }
    __syncthreads();

    bf16x8 ahf = *reinterpret_cast<const bf16x8*>(&Ah[wid * 16 + l15][kb]);
    bf16x8 alf = *reinterpret_cast<const bf16x8*>(&Al[wid * 16 + l15][kb]);
#pragma unroll
    for (int ni = 0; ni < 8; ++ni) {
      bf16x8 bh = *reinterpret_cast<const bf16x8*>(&Bh[ni * 16 + l15][kb]);
      bf16x8 bl = *reinterpret_cast<const bf16x8*>(&Bl[ni * 16 + l15][kb]);
      acc[ni] = __builtin_amdgcn_mfma_f32_16x16x32_bf16(ahf, bh, acc[ni], 0, 0, 0);
      acc[ni] = __builtin_amdgcn_mfma_f32_16x16x32_bf16(alf, bh, acc[ni], 0, 0, 0);
      acc[ni] = __builtin_amdgcn_mfma_f32_16x16x32_bf16(ahf, bl, acc[ni], 0, 0, 0);
    }
    __syncthreads();
  }

#pragma unroll
  for (int ni = 0; ni < 8; ++ni) {
    int gcol = bn + ni * 16 + l15;
    float bsv = bias[gcol];
#pragma unroll
    for (int r = 0; r < 4; ++r) {
      int grow = bm + wid * 16 + hi4 * 4 + r;
      float val = acc[ni][r] + bsv;
      int bb = grow >> 10, ss = grow & 1023, hh = gcol >> 6, dd = gcol & 63;
      size_t adr = ((size_t)(bb * H_ + hh) * S_ + ss) * HD_ + dd;
      unsigned short hh2, ll2;
      split_bf16(val, hh2, ll2);
      Ch[adr] = hh2;
      Cl[adr] = ll2;
    }
  }
}

// ---------------------------------------------------------------------------
// Attention scores + rel + mask + softmax -> probs f32.
// 512 threads = 8 waves: 2 q-groups (16 rows each) x 4 k-strip waves.
// K tiles shared in LDS across both q-groups. LDS ~54 KB.
// ---------------------------------------------------------------------------
__global__ __launch_bounds__(512) void attn_kernel(
    const unsigned short* __restrict__ qkh, const unsigned short* __restrict__ qkl,
    const int* __restrict__ mask, const float* __restrict__ rel_emb,
    float* __restrict__ probs)
{
  __shared__ unsigned short Qh[32][72], Ql[32][72];
  __shared__ unsigned short Kh[128][72], Kl[128][72];
  __shared__ float relp[32][24];
  __shared__ float red1[8][16], red2[8][16];
  __shared__ int msk[1024];

  const int tid = threadIdx.x;
  const int b = blockIdx.z, h = blockIdx.y, qt = blockIdx.x;
  const size_t bhoff = (size_t)(b * H_ + h) * S_ * HD_;
  const unsigned short* qh = qkh + bhoff;
  const unsigned short* ql = qkl + bhoff;
  const int q0 = qt * 32;

  for (int i = tid; i < 1024; i += 512) msk[i] = mask[b * S_ + i];

  if (tid < 256) {
    int row = tid >> 3, seg = (tid & 7) * 8;
    *reinterpret_cast<int4*>(&Qh[row][seg]) =
        *reinterpret_cast<const int4*>(&qh[(size_t)(q0 + row) * HD_ + seg]);
    *reinterpret_cast<int4*>(&Ql[row][seg]) =
        *reinterpret_cast<const int4*>(&ql[(size_t)(q0 + row) * HD_ + seg]);
  }
  __syncthreads();

  for (int idx = tid; idx < 32 * 21; idx += 512) {
    int q = idx / 21, r = idx - q * 21;
    float s = 0.f;
#pragma unroll 8
    for (int d = 0; d < 64; ++d) {
      float qf = bf16_to_f32(Qh[q][d]) + bf16_to_f32(Ql[q][d]);
      s += qf * rel_emb[r * 64 + d];
    }
    relp[q][r] = s;
  }

  const int qg = tid >> 8;
  const int wv = (tid >> 6) & 3;
  const int lane = tid & 63;
  const int l15 = lane & 15;
  const int hi4 = lane >> 4;
  const int kb = hi4 * 8;

  bf16x8 ah[2], al[2];
#pragma unroll
  for (int ks = 0; ks < 2; ++ks) {
    ah[ks] = *reinterpret_cast<const bf16x8*>(&Qh[qg * 16 + l15][ks * 32 + kb]);
    al[ks] = *reinterpret_cast<const bf16x8*>(&Ql[qg * 16 + l15][ks * 32 + kb]);
  }

  f32x4 acc[8][2];
#pragma unroll
  for (int t = 0; t < 8; ++t)
#pragma unroll
    for (int f = 0; f < 2; ++f) acc[t][f] = (f32x4){0.f, 0.f, 0.f, 0.f};

#pragma unroll
  for (int kt = 0; kt < 8; ++kt) {
    __syncthreads();
#pragma unroll
    for (int i = 0; i < 2; ++i) {
      int u = tid + i * 512;
      int row = u >> 3, seg = (u & 7) * 8;
      *reinterpret_cast<int4*>(&Kh[row][seg]) =
          *reinterpret_cast<const int4*>(&qh[(size_t)(kt * 128 + row) * HD_ + seg]);
      *reinterpret_cast<int4*>(&Kl[row][seg]) =
          *reinterpret_cast<const int4*>(&ql[(size_t)(kt * 128 + row) * HD_ + seg]);
    }
    __syncthreads();

#pragma unroll
    for (int f = 0; f < 2; ++f) {
      int cb = wv * 32 + f * 16;
#pragma unroll
      for (int ks = 0; ks < 2; ++ks) {
        bf16x8 bh = *reinterpret_cast<const bf16x8*>(&Kh[cb + l15][ks * 32 + kb]);
        bf16x8 bl = *reinterpret_cast<const bf16x8*>(&Kl[cb + l15][ks * 32 + kb]);
        acc[kt][f] = __builtin_amdgcn_mfma_f32_16x16x32_bf16(ah[ks], bh, acc[kt][f], 0, 0, 0);
        acc[kt][f] = __builtin_amdgcn_mfma_f32_16x16x32_bf16(al[ks], bh, acc[kt][f], 0, 0, 0);
        acc[kt][f] = __builtin_amdgcn_mfma_f32_16x16x32_bf16(ah[ks], bl, acc[kt][f], 0, 0, 0);
      }
    }
  }
  __syncthreads();

  float mx[4] = {-3.0e38f, -3.0e38f, -3.0e38f, -3.0e38f};
#pragma unroll
  for (int t = 0; t < 8; ++t)
#pragma unroll
    for (int f = 0; f < 2; ++f)
#pragma unroll
      for (int r = 0; r < 4; ++r) {
        int qlc = qg * 16 + hi4 * 4 + r;
        int q = q0 + qlc;
        int k = t * 128 + wv * 32 + f * 16 + l15;
        int d = k - q;
        int ridx = (d < -10 ? -10 : (d > 10 ? 10 : d)) + 10;
        float s = acc[t][f][r] + relp[qlc][ridx];
        if (k == q || msk[k] == 0) s -= 10000.0f;
        acc[t][f][r] = s;
        mx[r] = fmaxf(mx[r], s);
      }
#pragma unroll
  for (int r = 0; r < 4; ++r) {
    mx[r] = fmaxf(mx[r], __shfl_xor(mx[r], 1));
    mx[r] = fmaxf(mx[r], __shfl_xor(mx[r], 2));
    mx[r] = fmaxf(mx[r], __shfl_xor(mx[r], 4));
    mx[r] = fmaxf(mx[r], __shfl_xor(mx[r], 8));
  }
  {
    int wrow = qg * 4 + wv;
    if (l15 == 0) {
#pragma unroll
      for (int r = 0; r < 4; ++r) red1[wrow][hi4 * 4 + r] = mx[r];
    }
  }
  __syncthreads();
  float mxq[4];
#pragma unroll
  for (int r = 0; r < 4; ++r) {
    int ql16 = hi4 * 4 + r;
    mxq[r] = fmaxf(fmaxf(red1[qg * 4 + 0][ql16], red1[qg * 4 + 1][ql16]),
                   fmaxf(red1[qg * 4 + 2][ql16], red1[qg * 4 + 3][ql16]));
  }

  float sm[4] = {0.f, 0.f, 0.f, 0.f};
#pragma unroll
  for (int t = 0; t < 8; ++t)
#pragma unroll
    for (int f = 0; f < 2; ++f)
#pragma unroll
      for (int r = 0; r < 4; ++r) {
        float e = __expf(acc[t][f][r] - mxq[r]);
        acc[t][f][r] = e;
        sm[r] += e;
      }
#pragma unroll
  for (int r = 0; r < 4; ++r) {
    sm[r] += __shfl_xor(sm[r], 1);
    sm[r] += __shfl_xor(sm[r], 2);
    sm[r] += __shfl_xor(sm[r], 4);
    sm[r] += __shfl_xor(sm[r], 8);
  }
  {
    int wrow = qg * 4 + wv;
    if (l15 == 0) {
#pragma unroll
      for (int r = 0; r < 4; ++r) red2[wrow][hi4 * 4 + r] = sm[r];
    }
  }
  __syncthreads();
  float rinv[4];
#pragma unroll
  for (int r = 0; r < 4; ++r) {
    int ql16 = hi4 * 4 + r;
    rinv[r] = 1.0f / (red2[qg * 4 + 0][ql16] + red2[qg * 4 + 1][ql16] +
                      red2[qg * 4 + 2][ql16] + red2[qg * 4 + 3][ql16]);
  }

  float* pb = probs + (size_t)(b * H_ + h) * S_ * S_;
#pragma unroll
  for (int t = 0; t < 8; ++t)
#pragma unroll
    for (int f = 0; f < 2; ++f)
#pragma unroll
      for (int r = 0; r < 4; ++r) {
        int qlc = qg * 16 + hi4 * 4 + r;
        int kg = wv * 32 + f * 16 + l15;
        pb[(size_t)(q0 + qlc) * S_ + t * 128 + kg] = acc[t][f][r] * rinv[r];
      }
}

// ---------------------------------------------------------------------------
// PV, zero-LDS: ctx = P @ V. A-fragments direct from probs f32, B-fragments
// direct from pre-transposed vbt [BH][HD][S]. No barriers, no LDS.
// ---------------------------------------------------------------------------
__global__ __launch_bounds__(256) void pv_direct_kernel(
    const float* __restrict__ probs, const unsigned short* __restrict__ vbt,
    unsigned short* __restrict__ ctxb)
{
  const int tid = threadIdx.x;
  const int wv = tid >> 6;
  const int lane = tid & 63;
  const int l15 = lane & 15;
  const int hi4 = lane >> 4;
  const int b = blockIdx.z, h = blockIdx.y, qt = blockIdx.x;
  const float* pr = probs + (size_t)(b * H_ + h) * S_ * S_
                          + (size_t)(qt * 128 + wv * 32) * S_;
  const unsigned short* vtb = vbt + (size_t)(b * H_ + h) * HD_ * S_;

  f32x4 acc[2][4];
#pragma unroll
  for (int mi = 0; mi < 2; ++mi)
#pragma unroll
    for (int ni = 0; ni < 4; ++ni) acc[mi][ni] = (f32x4){0.f, 0.f, 0.f, 0.f};

  for (int k0 = 0; k0 < S_; k0 += 32) {
    bf16x8 af[2];
#pragma unroll
    for (int mi = 0; mi < 2; ++mi) {
      const float* prow = pr + (size_t)(mi * 16 + l15) * S_ + k0 + hi4 * 8;
      float4 p0 = *reinterpret_cast<const float4*>(prow);
      float4 p1 = *reinterpret_cast<const float4*>(prow + 4);
      bf16x8 a;
      a[0] = (short)f32_to_bf16(p0.x); a[1] = (short)f32_to_bf16(p0.y);
      a[2] = (short)f32_to_bf16(p0.z); a[3] = (short)f32_to_bf16(p0.w);
      a[4] = (short)f32_to_bf16(p1.x); a[5] = (short)f32_to_bf16(p1.y);
      a[6] = (short)f32_to_bf16(p1.z); a[7] = (short)f32_to_bf16(p1.w);
      af[mi] = a;
    }
#pragma unroll
    for (int ni = 0; ni < 4; ++ni) {
      bf16x8 vf = *reinterpret_cast<const bf16x8*>(
          &vtb[(size_t)(ni * 16 + l15) * S_ + k0 + hi4 * 8]);
      acc[0][ni] = __builtin_amdgcn_mfma_f32_16x16x32_bf16(af[0], vf, acc[0][ni], 0, 0, 0);
      acc[1][ni] = __builtin_amdgcn_mfma_f32_16x16x32_bf16(af[1], vf, acc[1][ni], 0, 0, 0);
    }
  }

#pragma unroll
  for (int mi = 0; mi < 2; ++mi)
#pragma unroll
    for (int ni = 0; ni < 4; ++ni) {
      int dd = ni * 16 + l15;
#pragma unroll
      for (int r = 0; r < 4; ++r) {
        int q = qt * 128 + wv * 32 + mi * 16 + hi4 * 4 + r;
        ctxb[((size_t)b * S_ + q) * DM_ + h * HD_ + dd] = f32_to_bf16(acc[mi][ni][r]);
      }
    }
}

// ---------------------------------------------------------------------------
// Row LayerNorm (1024 cols), f32 in, f32 or bf16 out (safe in-place for f32)
// ---------------------------------------------------------------------------
template<bool OUTB16>
__global__ __launch_bounds__(256) void ln_kernel(
    const float* __restrict__ in, const float* __restrict__ g,
    const float* __restrict__ be, void* __restrict__ out)
{
  __shared__ float red[4];
  const int row = blockIdx.x, tid = threadIdx.x;
  const float* r = in + (size_t)row * DM_;
  float4 x = *reinterpret_cast<const float4*>(&r[tid * 4]);

  float s = x.x + x.y + x.z + x.w;
#pragma unroll
  for (int m = 1; m < 64; m <<= 1) s += __shfl_xor(s, m);
  if ((tid & 63) == 0) red[tid >> 6] = s;
  __syncthreads();
  float mean = (red[0] + red[1] + red[2] + red[3]) * (1.0f / 1024.0f);
  __syncthreads();

  float d0 = x.x - mean, d1 = x.y - mean, d2 = x.z - mean, d3 = x.w - mean;
  float sq = d0 * d0 + d1 * d1 + d2 * d2 + d3 * d3;
#pragma unroll
  for (int m = 1; m < 64; m <<= 1) sq += __shfl_xor(sq, m);
  if ((tid & 63) == 0) red[tid >> 6] = sq;
  __syncthreads();
  float var = (red[0] + red[1] + red[2] + red[3]) * (1.0f / 1024.0f);
  float rstd = rsqrtf(var + 1e-3f);

  int c = tid * 4;
  float4 gv = *reinterpret_cast<const float4*>(&g[c]);
  float4 bv = *reinterpret_cast<const float4*>(&be[c]);
  float y0 = d0 * rstd * gv.x + bv.x;
  float y1 = d1 * rstd * gv.y + bv.y;
  float y2 = d2 * rstd * gv.z + bv.z;
  float y3 = d3 * rstd * gv.w + bv.w;
  if (OUTB16) {
    ushort4 o;
    o.x = f32_to_bf16(y0); o.y = f32_to_bf16(y1);
    o.z = f32_to_bf16(y2); o.w = f32_to_bf16(y3);
    *reinterpret_cast<ushort4*>(&((unsigned short*)out)[(size_t)row * DM_ + c]) = o;
  } else {
    *reinterpret_cast<float4*>(&((float*)out)[(size_t)row * DM_ + c]) =
        make_float4(y0, y1, y2, y3);
  }
}

// ---------------------------------------------------------------------------
// Workspace plan (64 MB, offsets in MB; overlays lifetime-checked):
//   0-8   WoT bf16       (prep -> Wo)
//   8-16  WiT bf16       (prep -> Wi)
//   16-18 WvT bf16       (prep -> Wv)
//   18-20 WapT bf16      (prep -> Wap)
//   20-22 WqkTh, 22-24 WqkTl  (prep -> qkproj)
//   24-32 xh bf16        (prep -> Wv proj & qkproj), then vbt (vtrans -> pv)
//   32-40 xl bf16        (prep -> qkproj), then ctxb bf16 (pv -> Wap)
//   40-48 qk_hi bf16     (qkproj -> attn)
//   48-56 qk_lo bf16     (qkproj -> attn)
//   40-56 y f32          (Wap -> ln1)   [qk_hi/lo dead]
//   56-64 vb bf16        (Wv -> vtrans)
//   20-28 attnb bf16     (ln1 -> Wo)    [WqkT + vbt dead]
//   32-64 interb bf16    (Wi -> Wo)     [ctxb/y/vb dead]
//   t = outf (d_out); ln2 in place.
// ---------------------------------------------------------------------------
extern "C" void kernel_launch(void* const* d_in, const int* in_sizes, int n_in,
                              void* d_out, int out_size, void* d_ws, size_t ws_size,
                              hipStream_t stream) {
  const float* x    = (const float*)d_in[0];
  const int*   mask = (const int*)d_in[1];
  const float* Wqk  = (const float*)d_in[2];
  const float* bqk  = (const float*)d_in[3];
  const float* Wv   = (const float*)d_in[4];
  const float* bv   = (const float*)d_in[5];
  const float* rel  = (const float*)d_in[6];
  const float* Wap  = (const float*)d_in[7];
  const float* bap  = (const float*)d_in[8];
  const float* g1   = (const float*)d_in[9];
  const float* b1   = (const float*)d_in[10];
  const float* Wi   = (const float*)d_in[11];
  const float* bi   = (const float*)d_in[12];
  const float* Wo   = (const float*)d_in[13];
  const float* bo   = (const float*)d_in[14];
  const float* g2   = (const float*)d_in[15];
  const float* b2   = (const float*)d_in[16];

  char* wsb = (char*)d_ws;
  const size_t MB = 1048576;
  unsigned short* WoT    = (unsigned short*)(wsb + 0 * MB);
  unsigned short* WiT    = (unsigned short*)(wsb + 8 * MB);
  unsigned short* WvT    = (unsigned short*)(wsb + 16 * MB);
  unsigned short* WapT   = (unsigned short*)(wsb + 18 * MB);
  unsigned short* WqkTh  = (unsigned short*)(wsb + 20 * MB);
  unsigned short* WqkTl  = (unsigned short*)(wsb + 22 * MB);
  unsigned short* xh     = (unsigned short*)(wsb + 24 * MB);
  unsigned short* vbt    = (unsigned short*)(wsb + 24 * MB);
  unsigned short* xl     = (unsigned short*)(wsb + 32 * MB);
  unsigned short* ctxb   = (unsigned short*)(wsb + 32 * MB);
  unsigned short* qk_hi  = (unsigned short*)(wsb + 40 * MB);
  unsigned short* qk_lo  = (unsigned short*)(wsb + 48 * MB);
  float*          y      = (float*)(wsb + 40 * MB);
  unsigned short* vb     = (unsigned short*)(wsb + 56 * MB);
  unsigned short* attnb  = (unsigned short*)(wsb + 20 * MB);
  unsigned short* interb = (unsigned short*)(wsb + 32 * MB);

  float* outf  = (float*)d_out;        // out   [B,S,DM]  f32 (also t buffer)
  float* probs = outf + 4194304;       // probs [B,H,S,S] f32

  dim3 blk(256);
  // Merged preps: cvt_split + 4x tcvt + tcvt2 in one launch
  prep_kernel<<<6912, blk, 0, stream>>>(
      x, xh, xl, Wv, WvT, Wap, WapT, Wi, WiT, Wo, WoT, Wqk, WqkTh, WqkTl);

  // q/k shared projection (pre-split 3-MFMA) -> qk hi/lo bf16 [B,H,S,HD]
  gemm_mfma3_kernel<<<dim3(8, 64), blk, 0, stream>>>(
      xh, xl, WqkTh, WqkTl, bqk, qk_hi, qk_lo, 4096, 1024, 1024);
  // v projection (bf16 MFMA) -> [B,H,S,HD] bf16
  gemm_mfma_kernel<false, false, false, true, true><<<dim3(8, 64), blk, 0, stream>>>(
      xh, WvT, bv, nullptr, vb, 4096, 1024, 1024);
  // V transpose -> [B,H,HD,S]  (xh dead now)
  vtrans_kernel<<<dim3(16, 64), blk, 0, stream>>>(vb, vbt);
  // scores + rel + mask + softmax -> probs f32 (32 q-rows/block, 8 waves)
  attn_kernel<<<dim3(32, 16, 4), dim3(512), 0, stream>>>(
      qk_hi, qk_lo, mask, rel, probs);
  // ctx = probs @ v (zero-LDS direct fragments) -> bf16 [B,S,DM]
  pv_direct_kernel<<<dim3(8, 16, 4), blk, 0, stream>>>(probs, vbt, ctxb);
  // y = gelu(ctx @ Wap + bap) + x
  gemm_mfma_kernel<true, true, false, false, false><<<dim3(8, 64), blk, 0, stream>>>(
      ctxb, WapT, bap, x, y, 4096, 1024, 1024);
  // attnb = LN(y)*g1+b1 (bf16)
  ln_kernel<true><<<4096, blk, 0, stream>>>(y, g1, b1, attnb);
  // inter = gelu(attn @ Wi + bi) (bf16)
  gemm_mfma_kernel<true, false, false, false, true><<<dim3(32, 64), blk, 0, stream>>>(
      attnb, WiT, bi, nullptr, interb, 4096, 4096, 1024);
  // outf = gelu(inter @ Wo + bo) + attn   (t lives in d_out)
  gemm_mfma_kernel<true, true, true, false, false><<<dim3(8, 64), blk, 0, stream>>>(
      interb, WoT, bo, attnb, outf, 4096, 1024, 4096);
  // out = LN(t)*g2+b2 (f32, in place)
  ln_kernel<false><<<4096, blk, 0, stream>>>(outf, g2, b2, outf);
}

// Round 19
// 517.247 us; speedup vs baseline: 1.1513x; 1.0415x over previous
//
#include <hip/hip_runtime.h>
#include <hip/hip_bf16.h>

// Sizes (fixed for this problem)
#define B_  4
#define S_  1024
#define DM_ 1024
#define H_  16
#define HD_ 64
#define I_  4096

typedef __attribute__((ext_vector_type(8))) short bf16x8;
typedef __attribute__((ext_vector_type(4))) float f32x4;

__device__ __forceinline__ float gelu_f(float x) {
  float x3 = x * x * x;
  return 0.5f * x * (1.0f + tanhf(0.7978845608028654f * (x + 0.044715f * x3)));
}

__device__ __forceinline__ unsigned short f32_to_bf16(float f) {
  unsigned int u = __float_as_uint(f);
  unsigned int rounding = 0x7FFFu + ((u >> 16) & 1u);
  u += rounding;
  return (unsigned short)(u >> 16);
}

__device__ __forceinline__ float bf16_to_f32(unsigned short u) {
  return __uint_as_float(((unsigned int)u) << 16);
}

__device__ __forceinline__ void split_bf16(float v, unsigned short& h, unsigned short& l) {
  h = f32_to_bf16(v);
  l = f32_to_bf16(v - bf16_to_f32(h));
}

// Direct global->LDS DMA, 16 B per lane.
__device__ __forceinline__ void gload16(const void* g, void* l) {
  __builtin_amdgcn_global_load_lds(
      (const __attribute__((address_space(1))) void*)g,
      (__attribute__((address_space(3))) void*)l, 16, 0, 0);
}

// ---------------------------------------------------------------------------
// Merged prep kernel: one launch replaces cvt_split + 4x tcvt + tcvt2.
// ---------------------------------------------------------------------------
__device__ __forceinline__ void tcvt_body(
    const float* __restrict__ W, unsigned short* __restrict__ WT,
    int K, int N, int bx, int by, float (*tile)[65], int tid)
{
  const int k0 = by * 64, n0 = bx * 64;
#pragma unroll
  for (int i = 0; i < 4; ++i) {
    int u = tid + i * 256;
    int kr = u >> 4, nc = (u & 15) * 4;
    float4 v = *reinterpret_cast<const float4*>(&W[(size_t)(k0 + kr) * N + n0 + nc]);
    tile[kr][nc + 0] = v.x; tile[kr][nc + 1] = v.y;
    tile[kr][nc + 2] = v.z; tile[kr][nc + 3] = v.w;
  }
  __syncthreads();
  int n = tid >> 2, ks = (tid & 3) * 16;
  unsigned short* dst = &WT[(size_t)(n0 + n) * K + k0 + ks];
#pragma unroll
  for (int j = 0; j < 4; ++j) {
    ushort4 o;
    o.x = f32_to_bf16(tile[ks + j * 4 + 0][n]);
    o.y = f32_to_bf16(tile[ks + j * 4 + 1][n]);
    o.z = f32_to_bf16(tile[ks + j * 4 + 2][n]);
    o.w = f32_to_bf16(tile[ks + j * 4 + 3][n]);
    *reinterpret_cast<ushort4*>(&dst[j * 4]) = o;
  }
}

__device__ __forceinline__ void tcvt2_body(
    const float* __restrict__ W, unsigned short* __restrict__ WTh,
    unsigned short* __restrict__ WTl, int K, int N, int bx, int by,
    float (*tile)[65], int tid)
{
  const int k0 = by * 64, n0 = bx * 64;
#pragma unroll
  for (int i = 0; i < 4; ++i) {
    int u = tid + i * 256;
    int kr = u >> 4, nc = (u & 15) * 4;
    float4 v = *reinterpret_cast<const float4*>(&W[(size_t)(k0 + kr) * N + n0 + nc]);
    tile[kr][nc + 0] = v.x; tile[kr][nc + 1] = v.y;
    tile[kr][nc + 2] = v.z; tile[kr][nc + 3] = v.w;
  }
  __syncthreads();
  int n = tid >> 2, ks = (tid & 3) * 16;
#pragma unroll
  for (int j = 0; j < 4; ++j) {
    ushort4 h4, l4;
    split_bf16(tile[ks + j * 4 + 0][n], h4.x, l4.x);
    split_bf16(tile[ks + j * 4 + 1][n], h4.y, l4.y);
    split_bf16(tile[ks + j * 4 + 2][n], h4.z, l4.z);
    split_bf16(tile[ks + j * 4 + 3][n], h4.w, l4.w);
    *reinterpret_cast<ushort4*>(&WTh[(size_t)(n0 + n) * K + k0 + ks + j * 4]) = h4;
    *reinterpret_cast<ushort4*>(&WTl[(size_t)(n0 + n) * K + k0 + ks + j * 4]) = l4;
  }
}

__global__ __launch_bounds__(256) void prep_kernel(
    const float* __restrict__ x, unsigned short* __restrict__ xh,
    unsigned short* __restrict__ xl,
    const float* __restrict__ Wv,  unsigned short* __restrict__ WvT,
    const float* __restrict__ Wap, unsigned short* __restrict__ WapT,
    const float* __restrict__ Wi,  unsigned short* __restrict__ WiT,
    const float* __restrict__ Wo,  unsigned short* __restrict__ WoT,
    const float* __restrict__ Wqk, unsigned short* __restrict__ WqkTh,
    unsigned short* __restrict__ WqkTl)
{
  __shared__ float tile[64][65];
  const int blk = blockIdx.x;
  const int tid = threadIdx.x;

  if (blk < 4096) {
    int i = blk * 256 + tid;
    float4 v = *reinterpret_cast<const float4*>(&x[(size_t)i * 4]);
    ushort4 h4, l4;
    split_bf16(v.x, h4.x, l4.x); split_bf16(v.y, h4.y, l4.y);
    split_bf16(v.z, h4.z, l4.z); split_bf16(v.w, h4.w, l4.w);
    *reinterpret_cast<ushort4*>(&xh[(size_t)i * 4]) = h4;
    *reinterpret_cast<ushort4*>(&xl[(size_t)i * 4]) = l4;
  } else if (blk < 4352) {
    int b = blk - 4096;
    tcvt_body(Wv, WvT, 1024, 1024, b & 15, b >> 4, tile, tid);
  } else if (blk < 4608) {
    int b = blk - 4352;
    tcvt_body(Wap, WapT, 1024, 1024, b & 15, b >> 4, tile, tid);
  } else if (blk < 5632) {
    int b = blk - 4608;
    tcvt_body(Wi, WiT, 1024, 4096, b & 63, b >> 6, tile, tid);
  } else if (blk < 6656) {
    int b = blk - 5632;
    tcvt_body(Wo, WoT, 4096, 1024, b & 15, b >> 4, tile, tid);
  } else {
    int b = blk - 6656;
    tcvt2_body(Wqk, WqkTh, WqkTl, 1024, 1024, b & 15, b >> 4, tile, tid);
  }
}

// ---------------------------------------------------------------------------
// V transpose: vin [BH][S][HD] bf16 -> vout [BH][HD][S] bf16. 64x64 tiles.
// ---------------------------------------------------------------------------
__global__ __launch_bounds__(256) void vtrans_kernel(
    const unsigned short* __restrict__ vin, unsigned short* __restrict__ vout)
{
  __shared__ unsigned short tile[64][76];
  const int tid = threadIdx.x;
  const int st = blockIdx.x;
  const int bh = blockIdx.y;
  const unsigned short* src = vin + ((size_t)bh * S_ + st * 64) * HD_;
  unsigned short* dst = vout + (size_t)bh * HD_ * S_ + st * 64;
#pragma unroll
  for (int i = 0; i < 2; ++i) {
    int u = tid + i * 256;
    int row = u >> 3, unit = u & 7;
    *reinterpret_cast<int4*>(&tile[row][unit * 8]) =
        *reinterpret_cast<const int4*>(&src[(size_t)row * HD_ + unit * 8]);
  }
  __syncthreads();
#pragma unroll
  for (int i = 0; i < 2; ++i) {
    int u = tid + i * 256;
    int d = u >> 3, unit = u & 7;
    unsigned short tmp[8];
#pragma unroll
    for (int j = 0; j < 8; ++j) tmp[j] = tile[unit * 8 + j][d];
    *reinterpret_cast<int4*>(&dst[(size_t)d * S_ + unit * 8]) =
        *reinterpret_cast<const int4*>(tmp);
  }
}

// ---------------------------------------------------------------------------
// Merged QK-proj + V-proj kernel. Blocks [0,512): split-f32 3-MFMA qk
// projection; [512,1024): bf16 V projection. Shared 24 KB LDS union.
// Bodies identical to the r18 gemm_mfma3 / gemm_mfma<...,BHSD,OBF16> specials.
// ---------------------------------------------------------------------------
__global__ __launch_bounds__(256) void qkv_kernel(
    const unsigned short* __restrict__ xh_g, const unsigned short* __restrict__ xl_g,
    const unsigned short* __restrict__ Bh_g, const unsigned short* __restrict__ Bl_g,
    const float* __restrict__ bqk, unsigned short* __restrict__ Ch,
    unsigned short* __restrict__ Cl,
    const unsigned short* __restrict__ WvT, const float* __restrict__ bv,
    unsigned short* __restrict__ vb)
{
  __shared__ __align__(16) unsigned short smem[12288];   // 24 KB union
  const int tid = threadIdx.x;
  const int wid = tid >> 6;
  const int lane = tid & 63;
  const int l15 = lane & 15;
  const int hi4 = lane >> 4;
  const int kb = hi4 * 8;
  const int srow = lane >> 2;
  const int sseg = (lane & 3) * 8;
  const int K = 1024, N = 1024;

  if (blockIdx.x < 512) {
    // ---- qk projection (pre-split 3-MFMA) ----
    unsigned short (*Ah)[32] = (unsigned short (*)[32])smem;          // 64x32
    unsigned short (*Al)[32] = (unsigned short (*)[32])(smem + 2048); // 64x32
    unsigned short (*Bh)[32] = (unsigned short (*)[32])(smem + 4096); // 128x32
    unsigned short (*Bl)[32] = (unsigned short (*)[32])(smem + 8192); // 128x32
    const int blk = blockIdx.x;
    const int bm = (blk >> 3) * 64;
    const int bn = (blk & 7) * 128;

    f32x4 acc[8];
#pragma unroll
    for (int ni = 0; ni < 8; ++ni) acc[ni] = (f32x4){0.f, 0.f, 0.f, 0.f};

    for (int k0 = 0; k0 < K; k0 += 32) {
      {
        size_t ga = (size_t)(bm + wid * 16 + srow) * K + k0 + sseg;
        gload16(&xh_g[ga], &Ah[wid * 16][0]);
        gload16(&xl_g[ga], &Al[wid * 16][0]);
      }
#pragma unroll
      for (int i = 0; i < 2; ++i) {
        int base_row = i * 64 + wid * 16;
        size_t gb = (size_t)(bn + base_row + srow) * K + k0 + sseg;
        gload16(&Bh_g[gb], &Bh[base_row][0]);
        gload16(&Bl_g[gb], &Bl[base_row][0]);
      }
      __syncthreads();

      bf16x8 ahf = *reinterpret_cast<const bf16x8*>(&Ah[wid * 16 + l15][kb]);
      bf16x8 alf = *reinterpret_cast<const bf16x8*>(&Al[wid * 16 + l15][kb]);
#pragma unroll
      for (int ni = 0; ni < 8; ++ni) {
        bf16x8 bh = *reinterpret_cast<const bf16x8*>(&Bh[ni * 16 + l15][kb]);
        bf16x8 bl = *reinterpret_cast<const bf16x8*>(&Bl[ni * 16 + l15][kb]);
        acc[ni] = __builtin_amdgcn_mfma_f32_16x16x32_bf16(ahf, bh, acc[ni], 0, 0, 0);
        acc[ni] = __builtin_amdgcn_mfma_f32_16x16x32_bf16(alf, bh, acc[ni], 0, 0, 0);
        acc[ni] = __builtin_amdgcn_mfma_f32_16x16x32_bf16(ahf, bl, acc[ni], 0, 0, 0);
      }
      __syncthreads();
    }

#pragma unroll
    for (int ni = 0; ni < 8; ++ni) {
      int gcol = bn + ni * 16 + l15;
      float bsv = bqk[gcol];
#pragma unroll
      for (int r = 0; r < 4; ++r) {
        int grow = bm + wid * 16 + hi4 * 4 + r;
        float val = acc[ni][r] + bsv;
        int bb = grow >> 10, ss = grow & 1023, hh = gcol >> 6, dd = gcol & 63;
        size_t adr = ((size_t)(bb * H_ + hh) * S_ + ss) * HD_ + dd;
        unsigned short hh2, ll2;
        split_bf16(val, hh2, ll2);
        Ch[adr] = hh2;
        Cl[adr] = ll2;
      }
    }
  } else {
    // ---- V projection (bf16 MFMA, BHSD bf16 out) ----
    unsigned short (*As)[32] = (unsigned short (*)[32])smem;          // 64x32
    unsigned short (*Bs)[32] = (unsigned short (*)[32])(smem + 2048); // 128x32
    const int blk = blockIdx.x - 512;
    const int bm = (blk >> 3) * 64;
    const int bn = (blk & 7) * 128;

    f32x4 acc[8];
#pragma unroll
    for (int ni = 0; ni < 8; ++ni) acc[ni] = (f32x4){0.f, 0.f, 0.f, 0.f};

    for (int k0 = 0; k0 < K; k0 += 32) {
      gload16(&xh_g[(size_t)(bm + wid * 16 + srow) * K + k0 + sseg], &As[wid * 16][0]);
#pragma unroll
      for (int i = 0; i < 2; ++i) {
        int base_row = i * 64 + wid * 16;
        gload16(&WvT[(size_t)(bn + base_row + srow) * K + k0 + sseg], &Bs[base_row][0]);
      }
      __syncthreads();

      bf16x8 af = *reinterpret_cast<const bf16x8*>(&As[wid * 16 + l15][kb]);
#pragma unroll
      for (int ni = 0; ni < 8; ++ni) {
        bf16x8 bfr = *reinterpret_cast<const bf16x8*>(&Bs[ni * 16 + l15][kb]);
        acc[ni] = __builtin_amdgcn_mfma_f32_16x16x32_bf16(af, bfr, acc[ni], 0, 0, 0);
      }
      __syncthreads();
    }

#pragma unroll
    for (int ni = 0; ni < 8; ++ni) {
      int gcol = bn + ni * 16 + l15;
      float bsv = bv[gcol];
#pragma unroll
      for (int r = 0; r < 4; ++r) {
        int grow = bm + wid * 16 + hi4 * 4 + r;
        float val = acc[ni][r] + bsv;
        int bb = grow >> 10, ss = grow & 1023, hh = gcol >> 6, dd = gcol & 63;
        size_t adr = ((size_t)(bb * H_ + hh) * S_ + ss) * HD_ + dd;
        vb[adr] = f32_to_bf16(val);
      }
    }
  }
  (void)N;
}

// ---------------------------------------------------------------------------
// bf16 MFMA GEMM, 64x128 tile, BK=32, 4 waves. gload16 staging. LDS 12 KB.
// ---------------------------------------------------------------------------
template<bool GELU, bool RES, bool RESBF16, bool OBF16>
__global__ __launch_bounds__(256) void gemm_mfma_kernel(
    const unsigned short* __restrict__ A, const unsigned short* __restrict__ BT,
    const float* __restrict__ bias, const void* __restrict__ res,
    void* __restrict__ C, int M, int N, int K)
{
  __shared__ unsigned short As[64][32];
  __shared__ unsigned short Bs[128][32];
  const int tid = threadIdx.x;
  const int wid = tid >> 6;
  const int lane = tid & 63;
  const int bm = blockIdx.y * 64;
  const int bn = blockIdx.x * 128;
  const int l15 = lane & 15;
  const int hi4 = lane >> 4;
  const int kb = hi4 * 8;
  const int srow = lane >> 2;
  const int sseg = (lane & 3) * 8;

  f32x4 acc[8];
#pragma unroll
  for (int ni = 0; ni < 8; ++ni) acc[ni] = (f32x4){0.f, 0.f, 0.f, 0.f};

  for (int k0 = 0; k0 < K; k0 += 32) {
    gload16(&A[(size_t)(bm + wid * 16 + srow) * K + k0 + sseg], &As[wid * 16][0]);
#pragma unroll
    for (int i = 0; i < 2; ++i) {
      int base_row = i * 64 + wid * 16;
      gload16(&BT[(size_t)(bn + base_row + srow) * K + k0 + sseg], &Bs[base_row][0]);
    }
    __syncthreads();

    bf16x8 af = *reinterpret_cast<const bf16x8*>(&As[wid * 16 + l15][kb]);
#pragma unroll
    for (int ni = 0; ni < 8; ++ni) {
      bf16x8 bfr = *reinterpret_cast<const bf16x8*>(&Bs[ni * 16 + l15][kb]);
      acc[ni] = __builtin_amdgcn_mfma_f32_16x16x32_bf16(af, bfr, acc[ni], 0, 0, 0);
    }
    __syncthreads();
  }

#pragma unroll
  for (int ni = 0; ni < 8; ++ni) {
    int gcol = bn + ni * 16 + l15;
    float bsv = bias[gcol];
#pragma unroll
    for (int r = 0; r < 4; ++r) {
      int grow = bm + wid * 16 + hi4 * 4 + r;
      float val = acc[ni][r] + bsv;
      if (GELU) val = gelu_f(val);
      if (RES) {
        if (RESBF16) val += bf16_to_f32(((const unsigned short*)res)[(size_t)grow * N + gcol]);
        else         val += ((const float*)res)[(size_t)grow * N + gcol];
      }
      if (OBF16) {
        ((unsigned short*)C)[(size_t)grow * N + gcol] = f32_to_bf16(val);
      } else {
        ((float*)C)[(size_t)grow * N + gcol] = val;
      }
    }
  }
}

// ---------------------------------------------------------------------------
// Attention scores + rel + mask + softmax -> probs f32.
// 512 threads = 8 waves: 2 q-groups (16 rows each) x 4 k-strip waves.
// ---------------------------------------------------------------------------
__global__ __launch_bounds__(512) void attn_kernel(
    const unsigned short* __restrict__ qkh, const unsigned short* __restrict__ qkl,
    const int* __restrict__ mask, const float* __restrict__ rel_emb,
    float* __restrict__ probs)
{
  __shared__ unsigned short Qh[32][72], Ql[32][72];
  __shared__ unsigned short Kh[128][72], Kl[128][72];
  __shared__ float relp[32][24];
  __shared__ float red1[8][16], red2[8][16];
  __shared__ int msk[1024];

  const int tid = threadIdx.x;
  const int b = blockIdx.z, h = blockIdx.y, qt = blockIdx.x;
  const size_t bhoff = (size_t)(b * H_ + h) * S_ * HD_;
  const unsigned short* qh = qkh + bhoff;
  const unsigned short* ql = qkl + bhoff;
  const int q0 = qt * 32;

  for (int i = tid; i < 1024; i += 512) msk[i] = mask[b * S_ + i];

  if (tid < 256) {
    int row = tid >> 3, seg = (tid & 7) * 8;
    *reinterpret_cast<int4*>(&Qh[row][seg]) =
        *reinterpret_cast<const int4*>(&qh[(size_t)(q0 + row) * HD_ + seg]);
    *reinterpret_cast<int4*>(&Ql[row][seg]) =
        *reinterpret_cast<const int4*>(&ql[(size_t)(q0 + row) * HD_ + seg]);
  }
  __syncthreads();

  for (int idx = tid; idx < 32 * 21; idx += 512) {
    int q = idx / 21, r = idx - q * 21;
    float s = 0.f;
#pragma unroll 8
    for (int d = 0; d < 64; ++d) {
      float qf = bf16_to_f32(Qh[q][d]) + bf16_to_f32(Ql[q][d]);
      s += qf * rel_emb[r * 64 + d];
    }
    relp[q][r] = s;
  }

  const int qg = tid >> 8;
  const int wv = (tid >> 6) & 3;
  const int lane = tid & 63;
  const int l15 = lane & 15;
  const int hi4 = lane >> 4;
  const int kb = hi4 * 8;

  bf16x8 ah[2], al[2];
#pragma unroll
  for (int ks = 0; ks < 2; ++ks) {
    ah[ks] = *reinterpret_cast<const bf16x8*>(&Qh[qg * 16 + l15][ks * 32 + kb]);
    al[ks] = *reinterpret_cast<const bf16x8*>(&Ql[qg * 16 + l15][ks * 32 + kb]);
  }

  f32x4 acc[8][2];
#pragma unroll
  for (int t = 0; t < 8; ++t)
#pragma unroll
    for (int f = 0; f < 2; ++f) acc[t][f] = (f32x4){0.f, 0.f, 0.f, 0.f};

#pragma unroll
  for (int kt = 0; kt < 8; ++kt) {
    __syncthreads();
#pragma unroll
    for (int i = 0; i < 2; ++i) {
      int u = tid + i * 512;
      int row = u >> 3, seg = (u & 7) * 8;
      *reinterpret_cast<int4*>(&Kh[row][seg]) =
          *reinterpret_cast<const int4*>(&qh[(size_t)(kt * 128 + row) * HD_ + seg]);
      *reinterpret_cast<int4*>(&Kl[row][seg]) =
          *reinterpret_cast<const int4*>(&ql[(size_t)(kt * 128 + row) * HD_ + seg]);
    }
    __syncthreads();

#pragma unroll
    for (int f = 0; f < 2; ++f) {
      int cb = wv * 32 + f * 16;
#pragma unroll
      for (int ks = 0; ks < 2; ++ks) {
        bf16x8 bh = *reinterpret_cast<const bf16x8*>(&Kh[cb + l15][ks * 32 + kb]);
        bf16x8 bl = *reinterpret_cast<const bf16x8*>(&Kl[cb + l15][ks * 32 + kb]);
        acc[kt][f] = __builtin_amdgcn_mfma_f32_16x16x32_bf16(ah[ks], bh, acc[kt][f], 0, 0, 0);
        acc[kt][f] = __builtin_amdgcn_mfma_f32_16x16x32_bf16(al[ks], bh, acc[kt][f], 0, 0, 0);
        acc[kt][f] = __builtin_amdgcn_mfma_f32_16x16x32_bf16(ah[ks], bl, acc[kt][f], 0, 0, 0);
      }
    }
  }
  __syncthreads();

  float mx[4] = {-3.0e38f, -3.0e38f, -3.0e38f, -3.0e38f};
#pragma unroll
  for (int t = 0; t < 8; ++t)
#pragma unroll
    for (int f = 0; f < 2; ++f)
#pragma unroll
      for (int r = 0; r < 4; ++r) {
        int qlc = qg * 16 + hi4 * 4 + r;
        int q = q0 + qlc;
        int k = t * 128 + wv * 32 + f * 16 + l15;
        int d = k - q;
        int ridx = (d < -10 ? -10 : (d > 10 ? 10 : d)) + 10;
        float s = acc[t][f][r] + relp[qlc][ridx];
        if (k == q || msk[k] == 0) s -= 10000.0f;
        acc[t][f][r] = s;
        mx[r] = fmaxf(mx[r], s);
      }
#pragma unroll
  for (int r = 0; r < 4; ++r) {
    mx[r] = fmaxf(mx[r], __shfl_xor(mx[r], 1));
    mx[r] = fmaxf(mx[r], __shfl_xor(mx[r], 2));
    mx[r] = fmaxf(mx[r], __shfl_xor(mx[r], 4));
    mx[r] = fmaxf(mx[r], __shfl_xor(mx[r], 8));
  }
  {
    int wrow = qg * 4 + wv;
    if (l15 == 0) {
#pragma unroll
      for (int r = 0; r < 4; ++r) red1[wrow][hi4 * 4 + r] = mx[r];
    }
  }
  __syncthreads();
  float mxq[4];
#pragma unroll
  for (int r = 0; r < 4; ++r) {
    int ql16 = hi4 * 4 + r;
    mxq[r] = fmaxf(fmaxf(red1[qg * 4 + 0][ql16], red1[qg * 4 + 1][ql16]),
                   fmaxf(red1[qg * 4 + 2][ql16], red1[qg * 4 + 3][ql16]));
  }

  float sm[4] = {0.f, 0.f, 0.f, 0.f};
#pragma unroll
  for (int t = 0; t < 8; ++t)
#pragma unroll
    for (int f = 0; f < 2; ++f)
#pragma unroll
      for (int r = 0; r < 4; ++r) {
        float e = __expf(acc[t][f][r] - mxq[r]);
        acc[t][f][r] = e;
        sm[r] += e;
      }
#pragma unroll
  for (int r = 0; r < 4; ++r) {
    sm[r] += __shfl_xor(sm[r], 1);
    sm[r] += __shfl_xor(sm[r], 2);
    sm[r] += __shfl_xor(sm[r], 4);
    sm[r] += __shfl_xor(sm[r], 8);
  }
  {
    int wrow = qg * 4 + wv;
    if (l15 == 0) {
#pragma unroll
      for (int r = 0; r < 4; ++r) red2[wrow][hi4 * 4 + r] = sm[r];
    }
  }
  __syncthreads();
  float rinv[4];
#pragma unroll
  for (int r = 0; r < 4; ++r) {
    int ql16 = hi4 * 4 + r;
    rinv[r] = 1.0f / (red2[qg * 4 + 0][ql16] + red2[qg * 4 + 1][ql16] +
                      red2[qg * 4 + 2][ql16] + red2[qg * 4 + 3][ql16]);
  }

  float* pb = probs + (size_t)(b * H_ + h) * S_ * S_;
#pragma unroll
  for (int t = 0; t < 8; ++t)
#pragma unroll
    for (int f = 0; f < 2; ++f)
#pragma unroll
      for (int r = 0; r < 4; ++r) {
        int qlc = qg * 16 + hi4 * 4 + r;
        int kg = wv * 32 + f * 16 + l15;
        pb[(size_t)(q0 + qlc) * S_ + t * 128 + kg] = acc[t][f][r] * rinv[r];
      }
}

// ---------------------------------------------------------------------------
// PV, zero-LDS. Block (b,h) iteration REVERSED vs attn's write order so the
// first pv blocks read the most-recently-written probs while L3-resident
// (probs = 268 MB vs 256 MB L3: same-order streaming would miss ~all).
// ---------------------------------------------------------------------------
__global__ __launch_bounds__(256) void pv_direct_kernel(
    const float* __restrict__ probs, const unsigned short* __restrict__ vbt,
    unsigned short* __restrict__ ctxb)
{
  const int tid = threadIdx.x;
  const int wv = tid >> 6;
  const int lane = tid & 63;
  const int l15 = lane & 15;
  const int hi4 = lane >> 4;
  const int b = (B_ - 1) - blockIdx.z;
  const int h = (H_ - 1) - blockIdx.y;
  const int qt = blockIdx.x;
  const float* pr = probs + (size_t)(b * H_ + h) * S_ * S_
                          + (size_t)(qt * 128 + wv * 32) * S_;
  const unsigned short* vtb = vbt + (size_t)(b * H_ + h) * HD_ * S_;

  f32x4 acc[2][4];
#pragma unroll
  for (int mi = 0; mi < 2; ++mi)
#pragma unroll
    for (int ni = 0; ni < 4; ++ni) acc[mi][ni] = (f32x4){0.f, 0.f, 0.f, 0.f};

  for (int k0 = 0; k0 < S_; k0 += 32) {
    bf16x8 af[2];
#pragma unroll
    for (int mi = 0; mi < 2; ++mi) {
      const float* prow = pr + (size_t)(mi * 16 + l15) * S_ + k0 + hi4 * 8;
      float4 p0 = *reinterpret_cast<const float4*>(prow);
      float4 p1 = *reinterpret_cast<const float4*>(prow + 4);
      bf16x8 a;
      a[0] = (short)f32_to_bf16(p0.x); a[1] = (short)f32_to_bf16(p0.y);
      a[2] = (short)f32_to_bf16(p0.z); a[3] = (short)f32_to_bf16(p0.w);
      a[4] = (short)f32_to_bf16(p1.x); a[5] = (short)f32_to_bf16(p1.y);
      a[6] = (short)f32_to_bf16(p1.z); a[7] = (short)f32_to_bf16(p1.w);
      af[mi] = a;
    }
#pragma unroll
    for (int ni = 0; ni < 4; ++ni) {
      bf16x8 vf = *reinterpret_cast<const bf16x8*>(
          &vtb[(size_t)(ni * 16 + l15) * S_ + k0 + hi4 * 8]);
      acc[0][ni] = __builtin_amdgcn_mfma_f32_16x16x32_bf16(af[0], vf, acc[0][ni], 0, 0, 0);
      acc[1][ni] = __builtin_amdgcn_mfma_f32_16x16x32_bf16(af[1], vf, acc[1][ni], 0, 0, 0);
    }
  }

#pragma unroll
  for (int mi = 0; mi < 2; ++mi)
#pragma unroll
    for (int ni = 0; ni < 4; ++ni) {
      int dd = ni * 16 + l15;
#pragma unroll
      for (int r = 0; r < 4; ++r) {
        int q = qt * 128 + wv * 32 + mi * 16 + hi4 * 4 + r;
        ctxb[((size_t)b * S_ + q) * DM_ + h * HD_ + dd] = f32_to_bf16(acc[mi][ni][r]);
      }
    }
}

// ---------------------------------------------------------------------------
// Row LayerNorm (1024 cols), f32 in, f32 or bf16 out (safe in-place for f32)
// ---------------------------------------------------------------------------
template<bool OUTB16>
__global__ __launch_bounds__(256) void ln_kernel(
    const float* __restrict__ in, const float* __restrict__ g,
    const float* __restrict__ be, void* __restrict__ out)
{
  __shared__ float red[4];
  const int row = blockIdx.x, tid = threadIdx.x;
  const float* r = in + (size_t)row * DM_;
  float4 x = *reinterpret_cast<const float4*>(&r[tid * 4]);

  float s = x.x + x.y + x.z + x.w;
#pragma unroll
  for (int m = 1; m < 64; m <<= 1) s += __shfl_xor(s, m);
  if ((tid & 63) == 0) red[tid >> 6] = s;
  __syncthreads();
  float mean = (red[0] + red[1] + red[2] + red[3]) * (1.0f / 1024.0f);
  __syncthreads();

  float d0 = x.x - mean, d1 = x.y - mean, d2 = x.z - mean, d3 = x.w - mean;
  float sq = d0 * d0 + d1 * d1 + d2 * d2 + d3 * d3;
#pragma unroll
  for (int m = 1; m < 64; m <<= 1) sq += __shfl_xor(sq, m);
  if ((tid & 63) == 0) red[tid >> 6] = sq;
  __syncthreads();
  float var = (red[0] + red[1] + red[2] + red[3]) * (1.0f / 1024.0f);
  float rstd = rsqrtf(var + 1e-3f);

  int c = tid * 4;
  float4 gv = *reinterpret_cast<const float4*>(&g[c]);
  float4 bv = *reinterpret_cast<const float4*>(&be[c]);
  float y0 = d0 * rstd * gv.x + bv.x;
  float y1 = d1 * rstd * gv.y + bv.y;
  float y2 = d2 * rstd * gv.z + bv.z;
  float y3 = d3 * rstd * gv.w + bv.w;
  if (OUTB16) {
    ushort4 o;
    o.x = f32_to_bf16(y0); o.y = f32_to_bf16(y1);
    o.z = f32_to_bf16(y2); o.w = f32_to_bf16(y3);
    *reinterpret_cast<ushort4*>(&((unsigned short*)out)[(size_t)row * DM_ + c]) = o;
  } else {
    *reinterpret_cast<float4*>(&((float*)out)[(size_t)row * DM_ + c]) =
        make_float4(y0, y1, y2, y3);
  }
}

// ---------------------------------------------------------------------------
// Workspace plan (64 MB, offsets in MB; overlays lifetime-checked):
//   0-8   WoT bf16       (prep -> Wo)
//   8-16  WiT bf16       (prep -> Wi)
//   16-18 WvT bf16       (prep -> Wv)
//   18-20 WapT bf16      (prep -> Wap)
//   20-22 WqkTh, 22-24 WqkTl  (prep -> qkv)
//   24-32 xh bf16        (prep -> qkv), then vbt (vtrans -> pv)
//   32-40 xl bf16        (prep -> qkv), then ctxb bf16 (pv -> Wap)
//   40-48 qk_hi bf16     (qkv -> attn)
//   48-56 qk_lo bf16     (qkv -> attn)
//   40-56 y f32          (Wap -> ln1)   [qk_hi/lo dead]
//   56-64 vb bf16        (qkv -> vtrans)
//   20-28 attnb bf16     (ln1 -> Wo)    [WqkT + vbt dead]
//   32-64 interb bf16    (Wi -> Wo)     [ctxb/y/vb dead]
//   t = outf (d_out); ln2 in place.
// ---------------------------------------------------------------------------
extern "C" void kernel_launch(void* const* d_in, const int* in_sizes, int n_in,
                              void* d_out, int out_size, void* d_ws, size_t ws_size,
                              hipStream_t stream) {
  const float* x    = (const float*)d_in[0];
  const int*   mask = (const int*)d_in[1];
  const float* Wqk  = (const float*)d_in[2];
  const float* bqk  = (const float*)d_in[3];
  const float* Wv   = (const float*)d_in[4];
  const float* bv   = (const float*)d_in[5];
  const float* rel  = (const float*)d_in[6];
  const float* Wap  = (const float*)d_in[7];
  const float* bap  = (const float*)d_in[8];
  const float* g1   = (const float*)d_in[9];
  const float* b1   = (const float*)d_in[10];
  const float* Wi   = (const float*)d_in[11];
  const float* bi   = (const float*)d_in[12];
  const float* Wo   = (const float*)d_in[13];
  const float* bo   = (const float*)d_in[14];
  const float* g2   = (const float*)d_in[15];
  const float* b2   = (const float*)d_in[16];

  char* wsb = (char*)d_ws;
  const size_t MB = 1048576;
  unsigned short* WoT    = (unsigned short*)(wsb + 0 * MB);
  unsigned short* WiT    = (unsigned short*)(wsb + 8 * MB);
  unsigned short* WvT    = (unsigned short*)(wsb + 16 * MB);
  unsigned short* WapT   = (unsigned short*)(wsb + 18 * MB);
  unsigned short* WqkTh  = (unsigned short*)(wsb + 20 * MB);
  unsigned short* WqkTl  = (unsigned short*)(wsb + 22 * MB);
  unsigned short* xh     = (unsigned short*)(wsb + 24 * MB);
  unsigned short* vbt    = (unsigned short*)(wsb + 24 * MB);
  unsigned short* xl     = (unsigned short*)(wsb + 32 * MB);
  unsigned short* ctxb   = (unsigned short*)(wsb + 32 * MB);
  unsigned short* qk_hi  = (unsigned short*)(wsb + 40 * MB);
  unsigned short* qk_lo  = (unsigned short*)(wsb + 48 * MB);
  float*          y      = (float*)(wsb + 40 * MB);
  unsigned short* vb     = (unsigned short*)(wsb + 56 * MB);
  unsigned short* attnb  = (unsigned short*)(wsb + 20 * MB);
  unsigned short* interb = (unsigned short*)(wsb + 32 * MB);

  float* outf  = (float*)d_out;        // out   [B,S,DM]  f32 (also t buffer)
  float* probs = outf + 4194304;       // probs [B,H,S,S] f32

  dim3 blk(256);
  // Merged preps: cvt_split + 4x tcvt + tcvt2 in one launch
  prep_kernel<<<6912, blk, 0, stream>>>(
      x, xh, xl, Wv, WvT, Wap, WapT, Wi, WiT, Wo, WoT, Wqk, WqkTh, WqkTl);

  // Merged qk projection (split 3-MFMA) + v projection (bf16 MFMA)
  qkv_kernel<<<1024, blk, 0, stream>>>(
      xh, xl, WqkTh, WqkTl, bqk, qk_hi, qk_lo, WvT, bv, vb);

  // V transpose -> [B,H,HD,S]  (xh dead now)
  vtrans_kernel<<<dim3(16, 64), blk, 0, stream>>>(vb, vbt);
  // scores + rel + mask + softmax -> probs f32 (32 q-rows/block, 8 waves)
  attn_kernel<<<dim3(32, 16, 4), dim3(512), 0, stream>>>(
      qk_hi, qk_lo, mask, rel, probs);
  // ctx = probs @ v (zero-LDS, reversed (b,h) for L3 reuse) -> bf16 [B,S,DM]
  pv_direct_kernel<<<dim3(8, 16, 4), blk, 0, stream>>>(probs, vbt, ctxb);
  // y = gelu(ctx @ Wap + bap) + x
  gemm_mfma_kernel<true, true, false, false><<<dim3(8, 64), blk, 0, stream>>>(
      ctxb, WapT, bap, x, y, 4096, 1024, 1024);
  // attnb = LN(y)*g1+b1 (bf16)
  ln_kernel<true><<<4096, blk, 0, stream>>>(y, g1, b1, attnb);
  // inter = gelu(attn @ Wi + bi) (bf16)
  gemm_mfma_kernel<true, false, false, true><<<dim3(32, 64), blk, 0, stream>>>(
      attnb, WiT, bi, nullptr, interb, 4096, 4096, 1024);
  // outf = gelu(inter @ Wo + bo) + attn   (t lives in d_out)
  gemm_mfma_kernel<true, true, true, false><<<dim3(8, 64), blk, 0, stream>>>(
      interb, WoT, bo, attnb, outf, 4096, 1024, 4096);
  // out = LN(t)*g2+b2 (f32, in place)
  ln_kernel<false><<<4096, blk, 0, stream>>>(outf, g2, b2, outf);
}

// Round 20
// 508.876 us; speedup vs baseline: 1.1703x; 1.0165x over previous
//
#include <hip/hip_runtime.h>
#include <hip/hip_bf16.h>

// Sizes (fixed for this problem)
#define B_  4
#define S_  1024
#define DM_ 1024
#define H_  16
#define HD_ 64
#define I_  4096

typedef __attribute__((ext_vector_type(8))) short bf16x8;
typedef __attribute__((ext_vector_type(4))) float f32x4;

__device__ __forceinline__ float gelu_f(float x) {
  float x3 = x * x * x;
  return 0.5f * x * (1.0f + tanhf(0.7978845608028654f * (x + 0.044715f * x3)));
}

__device__ __forceinline__ unsigned short f32_to_bf16(float f) {
  unsigned int u = __float_as_uint(f);
  unsigned int rounding = 0x7FFFu + ((u >> 16) & 1u);
  u += rounding;
  return (unsigned short)(u >> 16);
}

__device__ __forceinline__ float bf16_to_f32(unsigned short u) {
  return __uint_as_float(((unsigned int)u) << 16);
}

__device__ __forceinline__ void split_bf16(float v, unsigned short& h, unsigned short& l) {
  h = f32_to_bf16(v);
  l = f32_to_bf16(v - bf16_to_f32(h));
}

// Direct global->LDS DMA, 16 B per lane.
__device__ __forceinline__ void gload16(const void* g, void* l) {
  __builtin_amdgcn_global_load_lds(
      (const __attribute__((address_space(1))) void*)g,
      (__attribute__((address_space(3))) void*)l, 16, 0, 0);
}

// ---------------------------------------------------------------------------
// Merged prep kernel: one launch replaces cvt_split + 4x tcvt + tcvt2.
// ---------------------------------------------------------------------------
__device__ __forceinline__ void tcvt_body(
    const float* __restrict__ W, unsigned short* __restrict__ WT,
    int K, int N, int bx, int by, float (*tile)[65], int tid)
{
  const int k0 = by * 64, n0 = bx * 64;
#pragma unroll
  for (int i = 0; i < 4; ++i) {
    int u = tid + i * 256;
    int kr = u >> 4, nc = (u & 15) * 4;
    float4 v = *reinterpret_cast<const float4*>(&W[(size_t)(k0 + kr) * N + n0 + nc]);
    tile[kr][nc + 0] = v.x; tile[kr][nc + 1] = v.y;
    tile[kr][nc + 2] = v.z; tile[kr][nc + 3] = v.w;
  }
  __syncthreads();
  int n = tid >> 2, ks = (tid & 3) * 16;
  unsigned short* dst = &WT[(size_t)(n0 + n) * K + k0 + ks];
#pragma unroll
  for (int j = 0; j < 4; ++j) {
    ushort4 o;
    o.x = f32_to_bf16(tile[ks + j * 4 + 0][n]);
    o.y = f32_to_bf16(tile[ks + j * 4 + 1][n]);
    o.z = f32_to_bf16(tile[ks + j * 4 + 2][n]);
    o.w = f32_to_bf16(tile[ks + j * 4 + 3][n]);
    *reinterpret_cast<ushort4*>(&dst[j * 4]) = o;
  }
}

__device__ __forceinline__ void tcvt2_body(
    const float* __restrict__ W, unsigned short* __restrict__ WTh,
    unsigned short* __restrict__ WTl, int K, int N, int bx, int by,
    float (*tile)[65], int tid)
{
  const int k0 = by * 64, n0 = bx * 64;
#pragma unroll
  for (int i = 0; i < 4; ++i) {
    int u = tid + i * 256;
    int kr = u >> 4, nc = (u & 15) * 4;
    float4 v = *reinterpret_cast<const float4*>(&W[(size_t)(k0 + kr) * N + n0 + nc]);
    tile[kr][nc + 0] = v.x; tile[kr][nc + 1] = v.y;
    tile[kr][nc + 2] = v.z; tile[kr][nc + 3] = v.w;
  }
  __syncthreads();
  int n = tid >> 2, ks = (tid & 3) * 16;
#pragma unroll
  for (int j = 0; j < 4; ++j) {
    ushort4 h4, l4;
    split_bf16(tile[ks + j * 4 + 0][n], h4.x, l4.x);
    split_bf16(tile[ks + j * 4 + 1][n], h4.y, l4.y);
    split_bf16(tile[ks + j * 4 + 2][n], h4.z, l4.z);
    split_bf16(tile[ks + j * 4 + 3][n], h4.w, l4.w);
    *reinterpret_cast<ushort4*>(&WTh[(size_t)(n0 + n) * K + k0 + ks + j * 4]) = h4;
    *reinterpret_cast<ushort4*>(&WTl[(size_t)(n0 + n) * K + k0 + ks + j * 4]) = l4;
  }
}

__global__ __launch_bounds__(256) void prep_kernel(
    const float* __restrict__ x, unsigned short* __restrict__ xh,
    unsigned short* __restrict__ xl,
    const float* __restrict__ Wv,  unsigned short* __restrict__ WvT,
    const float* __restrict__ Wap, unsigned short* __restrict__ WapT,
    const float* __restrict__ Wi,  unsigned short* __restrict__ WiT,
    const float* __restrict__ Wo,  unsigned short* __restrict__ WoT,
    const float* __restrict__ Wqk, unsigned short* __restrict__ WqkTh,
    unsigned short* __restrict__ WqkTl)
{
  __shared__ float tile[64][65];
  const int blk = blockIdx.x;
  const int tid = threadIdx.x;

  if (blk < 4096) {
    int i = blk * 256 + tid;
    float4 v = *reinterpret_cast<const float4*>(&x[(size_t)i * 4]);
    ushort4 h4, l4;
    split_bf16(v.x, h4.x, l4.x); split_bf16(v.y, h4.y, l4.y);
    split_bf16(v.z, h4.z, l4.z); split_bf16(v.w, h4.w, l4.w);
    *reinterpret_cast<ushort4*>(&xh[(size_t)i * 4]) = h4;
    *reinterpret_cast<ushort4*>(&xl[(size_t)i * 4]) = l4;
  } else if (blk < 4352) {
    int b = blk - 4096;
    tcvt_body(Wv, WvT, 1024, 1024, b & 15, b >> 4, tile, tid);
  } else if (blk < 4608) {
    int b = blk - 4352;
    tcvt_body(Wap, WapT, 1024, 1024, b & 15, b >> 4, tile, tid);
  } else if (blk < 5632) {
    int b = blk - 4608;
    tcvt_body(Wi, WiT, 1024, 4096, b & 63, b >> 6, tile, tid);
  } else if (blk < 6656) {
    int b = blk - 5632;
    tcvt_body(Wo, WoT, 4096, 1024, b & 15, b >> 4, tile, tid);
  } else {
    int b = blk - 6656;
    tcvt2_body(Wqk, WqkTh, WqkTl, 1024, 1024, b & 15, b >> 4, tile, tid);
  }
}

// ---------------------------------------------------------------------------
// V transpose: vin [BH][S][HD] bf16 -> vout [BH][HD][S] bf16. 64x64 tiles.
// ---------------------------------------------------------------------------
__global__ __launch_bounds__(256) void vtrans_kernel(
    const unsigned short* __restrict__ vin, unsigned short* __restrict__ vout)
{
  __shared__ unsigned short tile[64][76];
  const int tid = threadIdx.x;
  const int st = blockIdx.x;
  const int bh = blockIdx.y;
  const unsigned short* src = vin + ((size_t)bh * S_ + st * 64) * HD_;
  unsigned short* dst = vout + (size_t)bh * HD_ * S_ + st * 64;
#pragma unroll
  for (int i = 0; i < 2; ++i) {
    int u = tid + i * 256;
    int row = u >> 3, unit = u & 7;
    *reinterpret_cast<int4*>(&tile[row][unit * 8]) =
        *reinterpret_cast<const int4*>(&src[(size_t)row * HD_ + unit * 8]);
  }
  __syncthreads();
#pragma unroll
  for (int i = 0; i < 2; ++i) {
    int u = tid + i * 256;
    int d = u >> 3, unit = u & 7;
    unsigned short tmp[8];
#pragma unroll
    for (int j = 0; j < 8; ++j) tmp[j] = tile[unit * 8 + j][d];
    *reinterpret_cast<int4*>(&dst[(size_t)d * S_ + unit * 8]) =
        *reinterpret_cast<const int4*>(tmp);
  }
}

// ---------------------------------------------------------------------------
// Merged QK-proj + V-proj kernel with XCD swizzle per 512-block section.
// ---------------------------------------------------------------------------
__global__ __launch_bounds__(256) void qkv_kernel(
    const unsigned short* __restrict__ xh_g, const unsigned short* __restrict__ xl_g,
    const unsigned short* __restrict__ Bh_g, const unsigned short* __restrict__ Bl_g,
    const float* __restrict__ bqk, unsigned short* __restrict__ Ch,
    unsigned short* __restrict__ Cl,
    const unsigned short* __restrict__ WvT, const float* __restrict__ bv,
    unsigned short* __restrict__ vb)
{
  __shared__ __align__(16) unsigned short smem[12288];   // 24 KB union
  const int tid = threadIdx.x;
  const int wid = tid >> 6;
  const int lane = tid & 63;
  const int l15 = lane & 15;
  const int hi4 = lane >> 4;
  const int kb = hi4 * 8;
  const int srow = lane >> 2;
  const int sseg = (lane & 3) * 8;
  const int K = 1024;

  if (blockIdx.x < 512) {
    // ---- qk projection (pre-split 3-MFMA) ----
    unsigned short (*Ah)[32] = (unsigned short (*)[32])smem;
    unsigned short (*Al)[32] = (unsigned short (*)[32])(smem + 2048);
    unsigned short (*Bh)[32] = (unsigned short (*)[32])(smem + 4096);
    unsigned short (*Bl)[32] = (unsigned short (*)[32])(smem + 8192);
    const int local = blockIdx.x;
    const int swz = (local & 7) * 64 + (local >> 3);   // XCD chunk swizzle
    const int bm = (swz >> 3) * 64;
    const int bn = (swz & 7) * 128;

    f32x4 acc[8];
#pragma unroll
    for (int ni = 0; ni < 8; ++ni) acc[ni] = (f32x4){0.f, 0.f, 0.f, 0.f};

    for (int k0 = 0; k0 < K; k0 += 32) {
      {
        size_t ga = (size_t)(bm + wid * 16 + srow) * K + k0 + sseg;
        gload16(&xh_g[ga], &Ah[wid * 16][0]);
        gload16(&xl_g[ga], &Al[wid * 16][0]);
      }
#pragma unroll
      for (int i = 0; i < 2; ++i) {
        int base_row = i * 64 + wid * 16;
        size_t gb = (size_t)(bn + base_row + srow) * K + k0 + sseg;
        gload16(&Bh_g[gb], &Bh[base_row][0]);
        gload16(&Bl_g[gb], &Bl[base_row][0]);
      }
      __syncthreads();

      bf16x8 ahf = *reinterpret_cast<const bf16x8*>(&Ah[wid * 16 + l15][kb]);
      bf16x8 alf = *reinterpret_cast<const bf16x8*>(&Al[wid * 16 + l15][kb]);
#pragma unroll
      for (int ni = 0; ni < 8; ++ni) {
        bf16x8 bh = *reinterpret_cast<const bf16x8*>(&Bh[ni * 16 + l15][kb]);
        bf16x8 bl = *reinterpret_cast<const bf16x8*>(&Bl[ni * 16 + l15][kb]);
        acc[ni] = __builtin_amdgcn_mfma_f32_16x16x32_bf16(ahf, bh, acc[ni], 0, 0, 0);
        acc[ni] = __builtin_amdgcn_mfma_f32_16x16x32_bf16(alf, bh, acc[ni], 0, 0, 0);
        acc[ni] = __builtin_amdgcn_mfma_f32_16x16x32_bf16(ahf, bl, acc[ni], 0, 0, 0);
      }
      __syncthreads();
    }

#pragma unroll
    for (int ni = 0; ni < 8; ++ni) {
      int gcol = bn + ni * 16 + l15;
      float bsv = bqk[gcol];
#pragma unroll
      for (int r = 0; r < 4; ++r) {
        int grow = bm + wid * 16 + hi4 * 4 + r;
        float val = acc[ni][r] + bsv;
        int bb = grow >> 10, ss = grow & 1023, hh = gcol >> 6, dd = gcol & 63;
        size_t adr = ((size_t)(bb * H_ + hh) * S_ + ss) * HD_ + dd;
        unsigned short hh2, ll2;
        split_bf16(val, hh2, ll2);
        Ch[adr] = hh2;
        Cl[adr] = ll2;
      }
    }
  } else {
    // ---- V projection (bf16 MFMA, BHSD bf16 out) ----
    unsigned short (*As)[32] = (unsigned short (*)[32])smem;
    unsigned short (*Bs)[32] = (unsigned short (*)[32])(smem + 2048);
    const int local = blockIdx.x - 512;
    const int swz = (local & 7) * 64 + (local >> 3);
    const int bm = (swz >> 3) * 64;
    const int bn = (swz & 7) * 128;

    f32x4 acc[8];
#pragma unroll
    for (int ni = 0; ni < 8; ++ni) acc[ni] = (f32x4){0.f, 0.f, 0.f, 0.f};

    for (int k0 = 0; k0 < K; k0 += 32) {
      gload16(&xh_g[(size_t)(bm + wid * 16 + srow) * K + k0 + sseg], &As[wid * 16][0]);
#pragma unroll
      for (int i = 0; i < 2; ++i) {
        int base_row = i * 64 + wid * 16;
        gload16(&WvT[(size_t)(bn + base_row + srow) * K + k0 + sseg], &Bs[base_row][0]);
      }
      __syncthreads();

      bf16x8 af = *reinterpret_cast<const bf16x8*>(&As[wid * 16 + l15][kb]);
#pragma unroll
      for (int ni = 0; ni < 8; ++ni) {
        bf16x8 bfr = *reinterpret_cast<const bf16x8*>(&Bs[ni * 16 + l15][kb]);
        acc[ni] = __builtin_amdgcn_mfma_f32_16x16x32_bf16(af, bfr, acc[ni], 0, 0, 0);
      }
      __syncthreads();
    }

#pragma unroll
    for (int ni = 0; ni < 8; ++ni) {
      int gcol = bn + ni * 16 + l15;
      float bsv = bv[gcol];
#pragma unroll
      for (int r = 0; r < 4; ++r) {
        int grow = bm + wid * 16 + hi4 * 4 + r;
        float val = acc[ni][r] + bsv;
        int bb = grow >> 10, ss = grow & 1023, hh = gcol >> 6, dd = gcol & 63;
        size_t adr = ((size_t)(bb * H_ + hh) * S_ + ss) * HD_ + dd;
        vb[adr] = f32_to_bf16(val);
      }
    }
  }
}

// ---------------------------------------------------------------------------
// bf16 MFMA GEMM, 64x128 tile, BK=32, 4 waves, gload16 staging, XCD swizzle.
// ---------------------------------------------------------------------------
template<bool GELU, bool RES, bool RESBF16, bool OBF16>
__global__ __launch_bounds__(256) void gemm_mfma_kernel(
    const unsigned short* __restrict__ A, const unsigned short* __restrict__ BT,
    const float* __restrict__ bias, const void* __restrict__ res,
    void* __restrict__ C, int M, int N, int K)
{
  __shared__ unsigned short As[64][32];
  __shared__ unsigned short Bs[128][32];
  const int tid = threadIdx.x;
  const int wid = tid >> 6;
  const int lane = tid & 63;
  // XCD chunk swizzle (nwg divisible by 8 for all launches here)
  const int flat = blockIdx.y * gridDim.x + blockIdx.x;
  const int cpx = (gridDim.x * gridDim.y) >> 3;
  const int swz = (flat & 7) * cpx + (flat >> 3);
  const int bm = (swz / gridDim.x) * 64;
  const int bn = (swz % gridDim.x) * 128;
  const int l15 = lane & 15;
  const int hi4 = lane >> 4;
  const int kb = hi4 * 8;
  const int srow = lane >> 2;
  const int sseg = (lane & 3) * 8;

  f32x4 acc[8];
#pragma unroll
  for (int ni = 0; ni < 8; ++ni) acc[ni] = (f32x4){0.f, 0.f, 0.f, 0.f};

  for (int k0 = 0; k0 < K; k0 += 32) {
    gload16(&A[(size_t)(bm + wid * 16 + srow) * K + k0 + sseg], &As[wid * 16][0]);
#pragma unroll
    for (int i = 0; i < 2; ++i) {
      int base_row = i * 64 + wid * 16;
      gload16(&BT[(size_t)(bn + base_row + srow) * K + k0 + sseg], &Bs[base_row][0]);
    }
    __syncthreads();

    bf16x8 af = *reinterpret_cast<const bf16x8*>(&As[wid * 16 + l15][kb]);
#pragma unroll
    for (int ni = 0; ni < 8; ++ni) {
      bf16x8 bfr = *reinterpret_cast<const bf16x8*>(&Bs[ni * 16 + l15][kb]);
      acc[ni] = __builtin_amdgcn_mfma_f32_16x16x32_bf16(af, bfr, acc[ni], 0, 0, 0);
    }
    __syncthreads();
  }

#pragma unroll
  for (int ni = 0; ni < 8; ++ni) {
    int gcol = bn + ni * 16 + l15;
    float bsv = bias[gcol];
#pragma unroll
    for (int r = 0; r < 4; ++r) {
      int grow = bm + wid * 16 + hi4 * 4 + r;
      float val = acc[ni][r] + bsv;
      if (GELU) val = gelu_f(val);
      if (RES) {
        if (RESBF16) val += bf16_to_f32(((const unsigned short*)res)[(size_t)grow * N + gcol]);
        else         val += ((const float*)res)[(size_t)grow * N + gcol];
      }
      if (OBF16) {
        ((unsigned short*)C)[(size_t)grow * N + gcol] = f32_to_bf16(val);
      } else {
        ((float*)C)[(size_t)grow * N + gcol] = val;
      }
    }
  }
}

// ---------------------------------------------------------------------------
// Attention scores + rel + mask + softmax -> probs f32.
// 512 threads = 8 waves: 2 q-groups x 4 k-strip waves. XCD swizzle clusters
// each (b,h)'s 32 qt-blocks onto one XCD so the K-panel is fetched into one
// L2 instead of all eight.
// ---------------------------------------------------------------------------
__global__ __launch_bounds__(512) void attn_kernel(
    const unsigned short* __restrict__ qkh, const unsigned short* __restrict__ qkl,
    const int* __restrict__ mask, const float* __restrict__ rel_emb,
    float* __restrict__ probs)
{
  __shared__ unsigned short Qh[32][72], Ql[32][72];
  __shared__ unsigned short Kh[128][72], Kl[128][72];
  __shared__ float relp[32][24];
  __shared__ float red1[8][16], red2[8][16];
  __shared__ int msk[1024];

  const int tid = threadIdx.x;
  // XCD chunk swizzle over flattened (qt,h,b) grid: nwg = 2048, cpx = 256
  const int flat = (blockIdx.z * gridDim.y + blockIdx.y) * gridDim.x + blockIdx.x;
  const int swz = (flat & 7) * 256 + (flat >> 3);
  const int qt = swz & 31;
  const int h = (swz >> 5) & 15;
  const int b = swz >> 9;
  const size_t bhoff = (size_t)(b * H_ + h) * S_ * HD_;
  const unsigned short* qh = qkh + bhoff;
  const unsigned short* ql = qkl + bhoff;
  const int q0 = qt * 32;

  for (int i = tid; i < 1024; i += 512) msk[i] = mask[b * S_ + i];

  if (tid < 256) {
    int row = tid >> 3, seg = (tid & 7) * 8;
    *reinterpret_cast<int4*>(&Qh[row][seg]) =
        *reinterpret_cast<const int4*>(&qh[(size_t)(q0 + row) * HD_ + seg]);
    *reinterpret_cast<int4*>(&Ql[row][seg]) =
        *reinterpret_cast<const int4*>(&ql[(size_t)(q0 + row) * HD_ + seg]);
  }
  __syncthreads();

  for (int idx = tid; idx < 32 * 21; idx += 512) {
    int q = idx / 21, r = idx - q * 21;
    float s = 0.f;
#pragma unroll 8
    for (int d = 0; d < 64; ++d) {
      float qf = bf16_to_f32(Qh[q][d]) + bf16_to_f32(Ql[q][d]);
      s += qf * rel_emb[r * 64 + d];
    }
    relp[q][r] = s;
  }

  const int qg = tid >> 8;
  const int wv = (tid >> 6) & 3;
  const int lane = tid & 63;
  const int l15 = lane & 15;
  const int hi4 = lane >> 4;
  const int kb = hi4 * 8;

  bf16x8 ah[2], al[2];
#pragma unroll
  for (int ks = 0; ks < 2; ++ks) {
    ah[ks] = *reinterpret_cast<const bf16x8*>(&Qh[qg * 16 + l15][ks * 32 + kb]);
    al[ks] = *reinterpret_cast<const bf16x8*>(&Ql[qg * 16 + l15][ks * 32 + kb]);
  }

  f32x4 acc[8][2];
#pragma unroll
  for (int t = 0; t < 8; ++t)
#pragma unroll
    for (int f = 0; f < 2; ++f) acc[t][f] = (f32x4){0.f, 0.f, 0.f, 0.f};

#pragma unroll
  for (int kt = 0; kt < 8; ++kt) {
    __syncthreads();
#pragma unroll
    for (int i = 0; i < 2; ++i) {
      int u = tid + i * 512;
      int row = u >> 3, seg = (u & 7) * 8;
      *reinterpret_cast<int4*>(&Kh[row][seg]) =
          *reinterpret_cast<const int4*>(&qh[(size_t)(kt * 128 + row) * HD_ + seg]);
      *reinterpret_cast<int4*>(&Kl[row][seg]) =
          *reinterpret_cast<const int4*>(&ql[(size_t)(kt * 128 + row) * HD_ + seg]);
    }
    __syncthreads();

#pragma unroll
    for (int f = 0; f < 2; ++f) {
      int cb = wv * 32 + f * 16;
#pragma unroll
      for (int ks = 0; ks < 2; ++ks) {
        bf16x8 bh = *reinterpret_cast<const bf16x8*>(&Kh[cb + l15][ks * 32 + kb]);
        bf16x8 bl = *reinterpret_cast<const bf16x8*>(&Kl[cb + l15][ks * 32 + kb]);
        acc[kt][f] = __builtin_amdgcn_mfma_f32_16x16x32_bf16(ah[ks], bh, acc[kt][f], 0, 0, 0);
        acc[kt][f] = __builtin_amdgcn_mfma_f32_16x16x32_bf16(al[ks], bh, acc[kt][f], 0, 0, 0);
        acc[kt][f] = __builtin_amdgcn_mfma_f32_16x16x32_bf16(ah[ks], bl, acc[kt][f], 0, 0, 0);
      }
    }
  }
  __syncthreads();

  float mx[4] = {-3.0e38f, -3.0e38f, -3.0e38f, -3.0e38f};
#pragma unroll
  for (int t = 0; t < 8; ++t)
#pragma unroll
    for (int f = 0; f < 2; ++f)
#pragma unroll
      for (int r = 0; r < 4; ++r) {
        int qlc = qg * 16 + hi4 * 4 + r;
        int q = q0 + qlc;
        int k = t * 128 + wv * 32 + f * 16 + l15;
        int d = k - q;
        int ridx = (d < -10 ? -10 : (d > 10 ? 10 : d)) + 10;
        float s = acc[t][f][r] + relp[qlc][ridx];
        if (k == q || msk[k] == 0) s -= 10000.0f;
        acc[t][f][r] = s;
        mx[r] = fmaxf(mx[r], s);
      }
#pragma unroll
  for (int r = 0; r < 4; ++r) {
    mx[r] = fmaxf(mx[r], __shfl_xor(mx[r], 1));
    mx[r] = fmaxf(mx[r], __shfl_xor(mx[r], 2));
    mx[r] = fmaxf(mx[r], __shfl_xor(mx[r], 4));
    mx[r] = fmaxf(mx[r], __shfl_xor(mx[r], 8));
  }
  {
    int wrow = qg * 4 + wv;
    if (l15 == 0) {
#pragma unroll
      for (int r = 0; r < 4; ++r) red1[wrow][hi4 * 4 + r] = mx[r];
    }
  }
  __syncthreads();
  float mxq[4];
#pragma unroll
  for (int r = 0; r < 4; ++r) {
    int ql16 = hi4 * 4 + r;
    mxq[r] = fmaxf(fmaxf(red1[qg * 4 + 0][ql16], red1[qg * 4 + 1][ql16]),
                   fmaxf(red1[qg * 4 + 2][ql16], red1[qg * 4 + 3][ql16]));
  }

  float sm[4] = {0.f, 0.f, 0.f, 0.f};
#pragma unroll
  for (int t = 0; t < 8; ++t)
#pragma unroll
    for (int f = 0; f < 2; ++f)
#pragma unroll
      for (int r = 0; r < 4; ++r) {
        float e = __expf(acc[t][f][r] - mxq[r]);
        acc[t][f][r] = e;
        sm[r] += e;
      }
#pragma unroll
  for (int r = 0; r < 4; ++r) {
    sm[r] += __shfl_xor(sm[r], 1);
    sm[r] += __shfl_xor(sm[r], 2);
    sm[r] += __shfl_xor(sm[r], 4);
    sm[r] += __shfl_xor(sm[r], 8);
  }
  {
    int wrow = qg * 4 + wv;
    if (l15 == 0) {
#pragma unroll
      for (int r = 0; r < 4; ++r) red2[wrow][hi4 * 4 + r] = sm[r];
    }
  }
  __syncthreads();
  float rinv[4];
#pragma unroll
  for (int r = 0; r < 4; ++r) {
    int ql16 = hi4 * 4 + r;
    rinv[r] = 1.0f / (red2[qg * 4 + 0][ql16] + red2[qg * 4 + 1][ql16] +
                      red2[qg * 4 + 2][ql16] + red2[qg * 4 + 3][ql16]);
  }

  float* pb = probs + (size_t)(b * H_ + h) * S_ * S_;
#pragma unroll
  for (int t = 0; t < 8; ++t)
#pragma unroll
    for (int f = 0; f < 2; ++f)
#pragma unroll
      for (int r = 0; r < 4; ++r) {
        int qlc = qg * 16 + hi4 * 4 + r;
        int kg = wv * 32 + f * 16 + l15;
        pb[(size_t)(q0 + qlc) * S_ + t * 128 + kg] = acc[t][f][r] * rinv[r];
      }
}

// ---------------------------------------------------------------------------
// PV, zero-LDS, reversed (b,h) for L3 recency (unchanged from r19).
// ---------------------------------------------------------------------------
__global__ __launch_bounds__(256) void pv_direct_kernel(
    const float* __restrict__ probs, const unsigned short* __restrict__ vbt,
    unsigned short* __restrict__ ctxb)
{
  const int tid = threadIdx.x;
  const int wv = tid >> 6;
  const int lane = tid & 63;
  const int l15 = lane & 15;
  const int hi4 = lane >> 4;
  const int b = (B_ - 1) - blockIdx.z;
  const int h = (H_ - 1) - blockIdx.y;
  const int qt = blockIdx.x;
  const float* pr = probs + (size_t)(b * H_ + h) * S_ * S_
                          + (size_t)(qt * 128 + wv * 32) * S_;
  const unsigned short* vtb = vbt + (size_t)(b * H_ + h) * HD_ * S_;

  f32x4 acc[2][4];
#pragma unroll
  for (int mi = 0; mi < 2; ++mi)
#pragma unroll
    for (int ni = 0; ni < 4; ++ni) acc[mi][ni] = (f32x4){0.f, 0.f, 0.f, 0.f};

  for (int k0 = 0; k0 < S_; k0 += 32) {
    bf16x8 af[2];
#pragma unroll
    for (int mi = 0; mi < 2; ++mi) {
      const float* prow = pr + (size_t)(mi * 16 + l15) * S_ + k0 + hi4 * 8;
      float4 p0 = *reinterpret_cast<const float4*>(prow);
      float4 p1 = *reinterpret_cast<const float4*>(prow + 4);
      bf16x8 a;
      a[0] = (short)f32_to_bf16(p0.x); a[1] = (short)f32_to_bf16(p0.y);
      a[2] = (short)f32_to_bf16(p0.z); a[3] = (short)f32_to_bf16(p0.w);
      a[4] = (short)f32_to_bf16(p1.x); a[5] = (short)f32_to_bf16(p1.y);
      a[6] = (short)f32_to_bf16(p1.z); a[7] = (short)f32_to_bf16(p1.w);
      af[mi] = a;
    }
#pragma unroll
    for (int ni = 0; ni < 4; ++ni) {
      bf16x8 vf = *reinterpret_cast<const bf16x8*>(
          &vtb[(size_t)(ni * 16 + l15) * S_ + k0 + hi4 * 8]);
      acc[0][ni] = __builtin_amdgcn_mfma_f32_16x16x32_bf16(af[0], vf, acc[0][ni], 0, 0, 0);
      acc[1][ni] = __builtin_amdgcn_mfma_f32_16x16x32_bf16(af[1], vf, acc[1][ni], 0, 0, 0);
    }
  }

#pragma unroll
  for (int mi = 0; mi < 2; ++mi)
#pragma unroll
    for (int ni = 0; ni < 4; ++ni) {
      int dd = ni * 16 + l15;
#pragma unroll
      for (int r = 0; r < 4; ++r) {
        int q = qt * 128 + wv * 32 + mi * 16 + hi4 * 4 + r;
        ctxb[((size_t)b * S_ + q) * DM_ + h * HD_ + dd] = f32_to_bf16(acc[mi][ni][r]);
      }
    }
}

// ---------------------------------------------------------------------------
// Row LayerNorm (1024 cols), f32 in, f32 or bf16 out (safe in-place for f32)
// ---------------------------------------------------------------------------
template<bool OUTB16>
__global__ __launch_bounds__(256) void ln_kernel(
    const float* __restrict__ in, const float* __restrict__ g,
    const float* __restrict__ be, void* __restrict__ out)
{
  __shared__ float red[4];
  const int row = blockIdx.x, tid = threadIdx.x;
  const float* r = in + (size_t)row * DM_;
  float4 x = *reinterpret_cast<const float4*>(&r[tid * 4]);

  float s = x.x + x.y + x.z + x.w;
#pragma unroll
  for (int m = 1; m < 64; m <<= 1) s += __shfl_xor(s, m);
  if ((tid & 63) == 0) red[tid >> 6] = s;
  __syncthreads();
  float mean = (red[0] + red[1] + red[2] + red[3]) * (1.0f / 1024.0f);
  __syncthreads();

  float d0 = x.x - mean, d1 = x.y - mean, d2 = x.z - mean, d3 = x.w - mean;
  float sq = d0 * d0 + d1 * d1 + d2 * d2 + d3 * d3;
#pragma unroll
  for (int m = 1; m < 64; m <<= 1) sq += __shfl_xor(sq, m);
  if ((tid & 63) == 0) red[tid >> 6] = sq;
  __syncthreads();
  float var = (red[0] + red[1] + red[2] + red[3]) * (1.0f / 1024.0f);
  float rstd = rsqrtf(var + 1e-3f);

  int c = tid * 4;
  float4 gv = *reinterpret_cast<const float4*>(&g[c]);
  float4 bv = *reinterpret_cast<const float4*>(&be[c]);
  float y0 = d0 * rstd * gv.x + bv.x;
  float y1 = d1 * rstd * gv.y + bv.y;
  float y2 = d2 * rstd * gv.z + bv.z;
  float y3 = d3 * rstd * gv.w + bv.w;
  if (OUTB16) {
    ushort4 o;
    o.x = f32_to_bf16(y0); o.y = f32_to_bf16(y1);
    o.z = f32_to_bf16(y2); o.w = f32_to_bf16(y3);
    *reinterpret_cast<ushort4*>(&((unsigned short*)out)[(size_t)row * DM_ + c]) = o;
  } else {
    *reinterpret_cast<float4*>(&((float*)out)[(size_t)row * DM_ + c]) =
        make_float4(y0, y1, y2, y3);
  }
}

// ---------------------------------------------------------------------------
// Workspace plan (64 MB, offsets in MB; overlays lifetime-checked):
//   0-8   WoT bf16       (prep -> Wo)
//   8-16  WiT bf16       (prep -> Wi)
//   16-18 WvT bf16       (prep -> Wv)
//   18-20 WapT bf16      (prep -> Wap)
//   20-22 WqkTh, 22-24 WqkTl  (prep -> qkv)
//   24-32 xh bf16        (prep -> qkv), then vbt (vtrans -> pv)
//   32-40 xl bf16        (prep -> qkv), then ctxb bf16 (pv -> Wap)
//   40-48 qk_hi bf16     (qkv -> attn)
//   48-56 qk_lo bf16     (qkv -> attn)
//   40-56 y f32          (Wap -> ln1)   [qk_hi/lo dead]
//   56-64 vb bf16        (qkv -> vtrans)
//   20-28 attnb bf16     (ln1 -> Wo)    [WqkT + vbt dead]
//   32-64 interb bf16    (Wi -> Wo)     [ctxb/y/vb dead]
//   t = outf (d_out); ln2 in place.
// ---------------------------------------------------------------------------
extern "C" void kernel_launch(void* const* d_in, const int* in_sizes, int n_in,
                              void* d_out, int out_size, void* d_ws, size_t ws_size,
                              hipStream_t stream) {
  const float* x    = (const float*)d_in[0];
  const int*   mask = (const int*)d_in[1];
  const float* Wqk  = (const float*)d_in[2];
  const float* bqk  = (const float*)d_in[3];
  const float* Wv   = (const float*)d_in[4];
  const float* bv   = (const float*)d_in[5];
  const float* rel  = (const float*)d_in[6];
  const float* Wap  = (const float*)d_in[7];
  const float* bap  = (const float*)d_in[8];
  const float* g1   = (const float*)d_in[9];
  const float* b1   = (const float*)d_in[10];
  const float* Wi   = (const float*)d_in[11];
  const float* bi   = (const float*)d_in[12];
  const float* Wo   = (const float*)d_in[13];
  const float* bo   = (const float*)d_in[14];
  const float* g2   = (const float*)d_in[15];
  const float* b2   = (const float*)d_in[16];

  char* wsb = (char*)d_ws;
  const size_t MB = 1048576;
  unsigned short* WoT    = (unsigned short*)(wsb + 0 * MB);
  unsigned short* WiT    = (unsigned short*)(wsb + 8 * MB);
  unsigned short* WvT    = (unsigned short*)(wsb + 16 * MB);
  unsigned short* WapT   = (unsigned short*)(wsb + 18 * MB);
  unsigned short* WqkTh  = (unsigned short*)(wsb + 20 * MB);
  unsigned short* WqkTl  = (unsigned short*)(wsb + 22 * MB);
  unsigned short* xh     = (unsigned short*)(wsb + 24 * MB);
  unsigned short* vbt    = (unsigned short*)(wsb + 24 * MB);
  unsigned short* xl     = (unsigned short*)(wsb + 32 * MB);
  unsigned short* ctxb   = (unsigned short*)(wsb + 32 * MB);
  unsigned short* qk_hi  = (unsigned short*)(wsb + 40 * MB);
  unsigned short* qk_lo  = (unsigned short*)(wsb + 48 * MB);
  float*          y      = (float*)(wsb + 40 * MB);
  unsigned short* vb     = (unsigned short*)(wsb + 56 * MB);
  unsigned short* attnb  = (unsigned short*)(wsb + 20 * MB);
  unsigned short* interb = (unsigned short*)(wsb + 32 * MB);

  float* outf  = (float*)d_out;        // out   [B,S,DM]  f32 (also t buffer)
  float* probs = outf + 4194304;       // probs [B,H,S,S] f32

  dim3 blk(256);
  // Merged preps: cvt_split + 4x tcvt + tcvt2 in one launch
  prep_kernel<<<6912, blk, 0, stream>>>(
      x, xh, xl, Wv, WvT, Wap, WapT, Wi, WiT, Wo, WoT, Wqk, WqkTh, WqkTl);

  // Merged qk projection (split 3-MFMA) + v projection (bf16 MFMA)
  qkv_kernel<<<1024, blk, 0, stream>>>(
      xh, xl, WqkTh, WqkTl, bqk, qk_hi, qk_lo, WvT, bv, vb);

  // V transpose -> [B,H,HD,S]  (xh dead now)
  vtrans_kernel<<<dim3(16, 64), blk, 0, stream>>>(vb, vbt);
  // scores + rel + mask + softmax -> probs f32 (XCD-swizzled)
  attn_kernel<<<dim3(32, 16, 4), dim3(512), 0, stream>>>(
      qk_hi, qk_lo, mask, rel, probs);
  // ctx = probs @ v (zero-LDS, reversed (b,h) for L3 reuse) -> bf16 [B,S,DM]
  pv_direct_kernel<<<dim3(8, 16, 4), blk, 0, stream>>>(probs, vbt, ctxb);
  // y = gelu(ctx @ Wap + bap) + x
  gemm_mfma_kernel<true, true, false, false><<<dim3(8, 64), blk, 0, stream>>>(
      ctxb, WapT, bap, x, y, 4096, 1024, 1024);
  // attnb = LN(y)*g1+b1 (bf16)
  ln_kernel<true><<<4096, blk, 0, stream>>>(y, g1, b1, attnb);
  // inter = gelu(attn @ Wi + bi) (bf16)
  gemm_mfma_kernel<true, false, false, true><<<dim3(32, 64), blk, 0, stream>>>(
      attnb, WiT, bi, nullptr, interb, 4096, 4096, 1024);
  // outf = gelu(inter @ Wo + bo) + attn   (t lives in d_out)
  gemm_mfma_kernel<true, true, true, false><<<dim3(8, 64), blk, 0, stream>>>(
      interb, WoT, bo, attnb, outf, 4096, 1024, 4096);
  // out = LN(t)*g2+b2 (f32, in place)
  ln_kernel<false><<<4096, blk, 0, stream>>>(outf, g2, b2, outf);
}

// Round 21
// 504.980 us; speedup vs baseline: 1.1793x; 1.0077x over previous
//
#include <hip/hip_runtime.h>
#include <hip/hip_bf16.h>

// Sizes (fixed for this problem)
#define B_  4
#define S_  1024
#define DM_ 1024
#define H_  16
#define HD_ 64
#define I_  4096

typedef __attribute__((ext_vector_type(8))) short bf16x8;
typedef __attribute__((ext_vector_type(4))) float f32x4;

__device__ __forceinline__ float gelu_f(float x) {
  float x3 = x * x * x;
  return 0.5f * x * (1.0f + tanhf(0.7978845608028654f * (x + 0.044715f * x3)));
}

__device__ __forceinline__ unsigned short f32_to_bf16(float f) {
  unsigned int u = __float_as_uint(f);
  unsigned int rounding = 0x7FFFu + ((u >> 16) & 1u);
  u += rounding;
  return (unsigned short)(u >> 16);
}

__device__ __forceinline__ float bf16_to_f32(unsigned short u) {
  return __uint_as_float(((unsigned int)u) << 16);
}

__device__ __forceinline__ void split_bf16(float v, unsigned short& h, unsigned short& l) {
  h = f32_to_bf16(v);
  l = f32_to_bf16(v - bf16_to_f32(h));
}

// Direct global->LDS DMA, 16 B per lane.
__device__ __forceinline__ void gload16(const void* g, void* l) {
  __builtin_amdgcn_global_load_lds(
      (const __attribute__((address_space(1))) void*)g,
      (__attribute__((address_space(3))) void*)l, 16, 0, 0);
}

// ---------------------------------------------------------------------------
// Merged prep kernel: one launch replaces cvt_split + 4x tcvt + tcvt2.
// ---------------------------------------------------------------------------
__device__ __forceinline__ void tcvt_body(
    const float* __restrict__ W, unsigned short* __restrict__ WT,
    int K, int N, int bx, int by, float (*tile)[65], int tid)
{
  const int k0 = by * 64, n0 = bx * 64;
#pragma unroll
  for (int i = 0; i < 4; ++i) {
    int u = tid + i * 256;
    int kr = u >> 4, nc = (u & 15) * 4;
    float4 v = *reinterpret_cast<const float4*>(&W[(size_t)(k0 + kr) * N + n0 + nc]);
    tile[kr][nc + 0] = v.x; tile[kr][nc + 1] = v.y;
    tile[kr][nc + 2] = v.z; tile[kr][nc + 3] = v.w;
  }
  __syncthreads();
  int n = tid >> 2, ks = (tid & 3) * 16;
  unsigned short* dst = &WT[(size_t)(n0 + n) * K + k0 + ks];
#pragma unroll
  for (int j = 0; j < 4; ++j) {
    ushort4 o;
    o.x = f32_to_bf16(tile[ks + j * 4 + 0][n]);
    o.y = f32_to_bf16(tile[ks + j * 4 + 1][n]);
    o.z = f32_to_bf16(tile[ks + j * 4 + 2][n]);
    o.w = f32_to_bf16(tile[ks + j * 4 + 3][n]);
    *reinterpret_cast<ushort4*>(&dst[j * 4]) = o;
  }
}

__device__ __forceinline__ void tcvt2_body(
    const float* __restrict__ W, unsigned short* __restrict__ WTh,
    unsigned short* __restrict__ WTl, int K, int N, int bx, int by,
    float (*tile)[65], int tid)
{
  const int k0 = by * 64, n0 = bx * 64;
#pragma unroll
  for (int i = 0; i < 4; ++i) {
    int u = tid + i * 256;
    int kr = u >> 4, nc = (u & 15) * 4;
    float4 v = *reinterpret_cast<const float4*>(&W[(size_t)(k0 + kr) * N + n0 + nc]);
    tile[kr][nc + 0] = v.x; tile[kr][nc + 1] = v.y;
    tile[kr][nc + 2] = v.z; tile[kr][nc + 3] = v.w;
  }
  __syncthreads();
  int n = tid >> 2, ks = (tid & 3) * 16;
#pragma unroll
  for (int j = 0; j < 4; ++j) {
    ushort4 h4, l4;
    split_bf16(tile[ks + j * 4 + 0][n], h4.x, l4.x);
    split_bf16(tile[ks + j * 4 + 1][n], h4.y, l4.y);
    split_bf16(tile[ks + j * 4 + 2][n], h4.z, l4.z);
    split_bf16(tile[ks + j * 4 + 3][n], h4.w, l4.w);
    *reinterpret_cast<ushort4*>(&WTh[(size_t)(n0 + n) * K + k0 + ks + j * 4]) = h4;
    *reinterpret_cast<ushort4*>(&WTl[(size_t)(n0 + n) * K + k0 + ks + j * 4]) = l4;
  }
}

__global__ __launch_bounds__(256) void prep_kernel(
    const float* __restrict__ x, unsigned short* __restrict__ xh,
    unsigned short* __restrict__ xl,
    const float* __restrict__ Wv,  unsigned short* __restrict__ WvT,
    const float* __restrict__ Wap, unsigned short* __restrict__ WapT,
    const float* __restrict__ Wi,  unsigned short* __restrict__ WiT,
    const float* __restrict__ Wo,  unsigned short* __restrict__ WoT,
    const float* __restrict__ Wqk, unsigned short* __restrict__ WqkTh,
    unsigned short* __restrict__ WqkTl)
{
  __shared__ float tile[64][65];
  const int blk = blockIdx.x;
  const int tid = threadIdx.x;

  if (blk < 4096) {
    int i = blk * 256 + tid;
    float4 v = *reinterpret_cast<const float4*>(&x[(size_t)i * 4]);
    ushort4 h4, l4;
    split_bf16(v.x, h4.x, l4.x); split_bf16(v.y, h4.y, l4.y);
    split_bf16(v.z, h4.z, l4.z); split_bf16(v.w, h4.w, l4.w);
    *reinterpret_cast<ushort4*>(&xh[(size_t)i * 4]) = h4;
    *reinterpret_cast<ushort4*>(&xl[(size_t)i * 4]) = l4;
  } else if (blk < 4352) {
    int b = blk - 4096;
    tcvt_body(Wv, WvT, 1024, 1024, b & 15, b >> 4, tile, tid);
  } else if (blk < 4608) {
    int b = blk - 4352;
    tcvt_body(Wap, WapT, 1024, 1024, b & 15, b >> 4, tile, tid);
  } else if (blk < 5632) {
    int b = blk - 4608;
    tcvt_body(Wi, WiT, 1024, 4096, b & 63, b >> 6, tile, tid);
  } else if (blk < 6656) {
    int b = blk - 5632;
    tcvt_body(Wo, WoT, 4096, 1024, b & 15, b >> 4, tile, tid);
  } else {
    int b = blk - 6656;
    tcvt2_body(Wqk, WqkTh, WqkTl, 1024, 1024, b & 15, b >> 4, tile, tid);
  }
}

// ---------------------------------------------------------------------------
// Merged QK-proj + V-proj kernel with XCD swizzle per 512-block section.
// V-proj epilogue writes vbt [BH][HD][S] DIRECTLY (transposed) via packed
// ushort4 (4 consecutive s per thread) — vtrans kernel eliminated.
// ---------------------------------------------------------------------------
__global__ __launch_bounds__(256) void qkv_kernel(
    const unsigned short* __restrict__ xh_g, const unsigned short* __restrict__ xl_g,
    const unsigned short* __restrict__ Bh_g, const unsigned short* __restrict__ Bl_g,
    const float* __restrict__ bqk, unsigned short* __restrict__ Ch,
    unsigned short* __restrict__ Cl,
    const unsigned short* __restrict__ WvT, const float* __restrict__ bv,
    unsigned short* __restrict__ vbt)
{
  __shared__ __align__(16) unsigned short smem[12288];   // 24 KB union
  const int tid = threadIdx.x;
  const int wid = tid >> 6;
  const int lane = tid & 63;
  const int l15 = lane & 15;
  const int hi4 = lane >> 4;
  const int kb = hi4 * 8;
  const int srow = lane >> 2;
  const int sseg = (lane & 3) * 8;
  const int K = 1024;

  if (blockIdx.x < 512) {
    // ---- qk projection (pre-split 3-MFMA) ----
    unsigned short (*Ah)[32] = (unsigned short (*)[32])smem;
    unsigned short (*Al)[32] = (unsigned short (*)[32])(smem + 2048);
    unsigned short (*Bh)[32] = (unsigned short (*)[32])(smem + 4096);
    unsigned short (*Bl)[32] = (unsigned short (*)[32])(smem + 8192);
    const int local = blockIdx.x;
    const int swz = (local & 7) * 64 + (local >> 3);   // XCD chunk swizzle
    const int bm = (swz >> 3) * 64;
    const int bn = (swz & 7) * 128;

    f32x4 acc[8];
#pragma unroll
    for (int ni = 0; ni < 8; ++ni) acc[ni] = (f32x4){0.f, 0.f, 0.f, 0.f};

    for (int k0 = 0; k0 < K; k0 += 32) {
      {
        size_t ga = (size_t)(bm + wid * 16 + srow) * K + k0 + sseg;
        gload16(&xh_g[ga], &Ah[wid * 16][0]);
        gload16(&xl_g[ga], &Al[wid * 16][0]);
      }
#pragma unroll
      for (int i = 0; i < 2; ++i) {
        int base_row = i * 64 + wid * 16;
        size_t gb = (size_t)(bn + base_row + srow) * K + k0 + sseg;
        gload16(&Bh_g[gb], &Bh[base_row][0]);
        gload16(&Bl_g[gb], &Bl[base_row][0]);
      }
      __syncthreads();

      bf16x8 ahf = *reinterpret_cast<const bf16x8*>(&Ah[wid * 16 + l15][kb]);
      bf16x8 alf = *reinterpret_cast<const bf16x8*>(&Al[wid * 16 + l15][kb]);
#pragma unroll
      for (int ni = 0; ni < 8; ++ni) {
        bf16x8 bh = *reinterpret_cast<const bf16x8*>(&Bh[ni * 16 + l15][kb]);
        bf16x8 bl = *reinterpret_cast<const bf16x8*>(&Bl[ni * 16 + l15][kb]);
        acc[ni] = __builtin_amdgcn_mfma_f32_16x16x32_bf16(ahf, bh, acc[ni], 0, 0, 0);
        acc[ni] = __builtin_amdgcn_mfma_f32_16x16x32_bf16(alf, bh, acc[ni], 0, 0, 0);
        acc[ni] = __builtin_amdgcn_mfma_f32_16x16x32_bf16(ahf, bl, acc[ni], 0, 0, 0);
      }
      __syncthreads();
    }

#pragma unroll
    for (int ni = 0; ni < 8; ++ni) {
      int gcol = bn + ni * 16 + l15;
      float bsv = bqk[gcol];
#pragma unroll
      for (int r = 0; r < 4; ++r) {
        int grow = bm + wid * 16 + hi4 * 4 + r;
        float val = acc[ni][r] + bsv;
        int bb = grow >> 10, ss = grow & 1023, hh = gcol >> 6, dd = gcol & 63;
        size_t adr = ((size_t)(bb * H_ + hh) * S_ + ss) * HD_ + dd;
        unsigned short hh2, ll2;
        split_bf16(val, hh2, ll2);
        Ch[adr] = hh2;
        Cl[adr] = ll2;
      }
    }
  } else {
    // ---- V projection (bf16 MFMA) -> vbt [BH][HD][S] direct transposed ----
    unsigned short (*As)[32] = (unsigned short (*)[32])smem;
    unsigned short (*Bs)[32] = (unsigned short (*)[32])(smem + 2048);
    const int local = blockIdx.x - 512;
    const int swz = (local & 7) * 64 + (local >> 3);
    const int bm = (swz >> 3) * 64;
    const int bn = (swz & 7) * 128;

    f32x4 acc[8];
#pragma unroll
    for (int ni = 0; ni < 8; ++ni) acc[ni] = (f32x4){0.f, 0.f, 0.f, 0.f};

    for (int k0 = 0; k0 < K; k0 += 32) {
      gload16(&xh_g[(size_t)(bm + wid * 16 + srow) * K + k0 + sseg], &As[wid * 16][0]);
#pragma unroll
      for (int i = 0; i < 2; ++i) {
        int base_row = i * 64 + wid * 16;
        gload16(&WvT[(size_t)(bn + base_row + srow) * K + k0 + sseg], &Bs[base_row][0]);
      }
      __syncthreads();

      bf16x8 af = *reinterpret_cast<const bf16x8*>(&As[wid * 16 + l15][kb]);
#pragma unroll
      for (int ni = 0; ni < 8; ++ni) {
        bf16x8 bfr = *reinterpret_cast<const bf16x8*>(&Bs[ni * 16 + l15][kb]);
        acc[ni] = __builtin_amdgcn_mfma_f32_16x16x32_bf16(af, bfr, acc[ni], 0, 0, 0);
      }
      __syncthreads();
    }

#pragma unroll
    for (int ni = 0; ni < 8; ++ni) {
      int gcol = bn + ni * 16 + l15;
      float bsv = bv[gcol];
      int hh = gcol >> 6, dd = gcol & 63;
      int grow0 = bm + wid * 16 + hi4 * 4;     // 4 consecutive s, same bb
      int bb = grow0 >> 10, ss0 = grow0 & 1023;
      ushort4 o;
      o.x = f32_to_bf16(acc[ni][0] + bsv);
      o.y = f32_to_bf16(acc[ni][1] + bsv);
      o.z = f32_to_bf16(acc[ni][2] + bsv);
      o.w = f32_to_bf16(acc[ni][3] + bsv);
      *reinterpret_cast<ushort4*>(
          &vbt[((size_t)(bb * H_ + hh) * HD_ + dd) * S_ + ss0]) = o;
    }
  }
}

// ---------------------------------------------------------------------------
// bf16 MFMA GEMM, 64x128 tile, BK=32, 4 waves, gload16 staging, XCD swizzle.
// ---------------------------------------------------------------------------
template<bool GELU, bool RES, bool RESBF16, bool OBF16>
__global__ __launch_bounds__(256) void gemm_mfma_kernel(
    const unsigned short* __restrict__ A, const unsigned short* __restrict__ BT,
    const float* __restrict__ bias, const void* __restrict__ res,
    void* __restrict__ C, int M, int N, int K)
{
  __shared__ unsigned short As[64][32];
  __shared__ unsigned short Bs[128][32];
  const int tid = threadIdx.x;
  const int wid = tid >> 6;
  const int lane = tid & 63;
  const int flat = blockIdx.y * gridDim.x + blockIdx.x;
  const int cpx = (gridDim.x * gridDim.y) >> 3;
  const int swz = (flat & 7) * cpx + (flat >> 3);
  const int bm = (swz / gridDim.x) * 64;
  const int bn = (swz % gridDim.x) * 128;
  const int l15 = lane & 15;
  const int hi4 = lane >> 4;
  const int kb = hi4 * 8;
  const int srow = lane >> 2;
  const int sseg = (lane & 3) * 8;

  f32x4 acc[8];
#pragma unroll
  for (int ni = 0; ni < 8; ++ni) acc[ni] = (f32x4){0.f, 0.f, 0.f, 0.f};

  for (int k0 = 0; k0 < K; k0 += 32) {
    gload16(&A[(size_t)(bm + wid * 16 + srow) * K + k0 + sseg], &As[wid * 16][0]);
#pragma unroll
    for (int i = 0; i < 2; ++i) {
      int base_row = i * 64 + wid * 16;
      gload16(&BT[(size_t)(bn + base_row + srow) * K + k0 + sseg], &Bs[base_row][0]);
    }
    __syncthreads();

    bf16x8 af = *reinterpret_cast<const bf16x8*>(&As[wid * 16 + l15][kb]);
#pragma unroll
    for (int ni = 0; ni < 8; ++ni) {
      bf16x8 bfr = *reinterpret_cast<const bf16x8*>(&Bs[ni * 16 + l15][kb]);
      acc[ni] = __builtin_amdgcn_mfma_f32_16x16x32_bf16(af, bfr, acc[ni], 0, 0, 0);
    }
    __syncthreads();
  }

#pragma unroll
  for (int ni = 0; ni < 8; ++ni) {
    int gcol = bn + ni * 16 + l15;
    float bsv = bias[gcol];
#pragma unroll
    for (int r = 0; r < 4; ++r) {
      int grow = bm + wid * 16 + hi4 * 4 + r;
      float val = acc[ni][r] + bsv;
      if (GELU) val = gelu_f(val);
      if (RES) {
        if (RESBF16) val += bf16_to_f32(((const unsigned short*)res)[(size_t)grow * N + gcol]);
        else         val += ((const float*)res)[(size_t)grow * N + gcol];
      }
      if (OBF16) {
        ((unsigned short*)C)[(size_t)grow * N + gcol] = f32_to_bf16(val);
      } else {
        ((float*)C)[(size_t)grow * N + gcol] = val;
      }
    }
  }
}

// ---------------------------------------------------------------------------
// Attention scores + rel + mask + softmax -> probs f32.
// 512 threads = 8 waves: 2 q-groups x 4 k-strip waves. XCD swizzle clusters
// each (b,h)'s 32 qt-blocks onto one XCD.
// ---------------------------------------------------------------------------
__global__ __launch_bounds__(512) void attn_kernel(
    const unsigned short* __restrict__ qkh, const unsigned short* __restrict__ qkl,
    const int* __restrict__ mask, const float* __restrict__ rel_emb,
    float* __restrict__ probs)
{
  __shared__ unsigned short Qh[32][72], Ql[32][72];
  __shared__ unsigned short Kh[128][72], Kl[128][72];
  __shared__ float relp[32][24];
  __shared__ float red1[8][16], red2[8][16];
  __shared__ int msk[1024];

  const int tid = threadIdx.x;
  const int flat = (blockIdx.z * gridDim.y + blockIdx.y) * gridDim.x + blockIdx.x;
  const int swz = (flat & 7) * 256 + (flat >> 3);
  const int qt = swz & 31;
  const int h = (swz >> 5) & 15;
  const int b = swz >> 9;
  const size_t bhoff = (size_t)(b * H_ + h) * S_ * HD_;
  const unsigned short* qh = qkh + bhoff;
  const unsigned short* ql = qkl + bhoff;
  const int q0 = qt * 32;

  for (int i = tid; i < 1024; i += 512) msk[i] = mask[b * S_ + i];

  if (tid < 256) {
    int row = tid >> 3, seg = (tid & 7) * 8;
    *reinterpret_cast<int4*>(&Qh[row][seg]) =
        *reinterpret_cast<const int4*>(&qh[(size_t)(q0 + row) * HD_ + seg]);
    *reinterpret_cast<int4*>(&Ql[row][seg]) =
        *reinterpret_cast<const int4*>(&ql[(size_t)(q0 + row) * HD_ + seg]);
  }
  __syncthreads();

  for (int idx = tid; idx < 32 * 21; idx += 512) {
    int q = idx / 21, r = idx - q * 21;
    float s = 0.f;
#pragma unroll 8
    for (int d = 0; d < 64; ++d) {
      float qf = bf16_to_f32(Qh[q][d]) + bf16_to_f32(Ql[q][d]);
      s += qf * rel_emb[r * 64 + d];
    }
    relp[q][r] = s;
  }

  const int qg = tid >> 8;
  const int wv = (tid >> 6) & 3;
  const int lane = tid & 63;
  const int l15 = lane & 15;
  const int hi4 = lane >> 4;
  const int kb = hi4 * 8;

  bf16x8 ah[2], al[2];
#pragma unroll
  for (int ks = 0; ks < 2; ++ks) {
    ah[ks] = *reinterpret_cast<const bf16x8*>(&Qh[qg * 16 + l15][ks * 32 + kb]);
    al[ks] = *reinterpret_cast<const bf16x8*>(&Ql[qg * 16 + l15][ks * 32 + kb]);
  }

  f32x4 acc[8][2];
#pragma unroll
  for (int t = 0; t < 8; ++t)
#pragma unroll
    for (int f = 0; f < 2; ++f) acc[t][f] = (f32x4){0.f, 0.f, 0.f, 0.f};

#pragma unroll
  for (int kt = 0; kt < 8; ++kt) {
    __syncthreads();
#pragma unroll
    for (int i = 0; i < 2; ++i) {
      int u = tid + i * 512;
      int row = u >> 3, seg = (u & 7) * 8;
      *reinterpret_cast<int4*>(&Kh[row][seg]) =
          *reinterpret_cast<const int4*>(&qh[(size_t)(kt * 128 + row) * HD_ + seg]);
      *reinterpret_cast<int4*>(&Kl[row][seg]) =
          *reinterpret_cast<const int4*>(&ql[(size_t)(kt * 128 + row) * HD_ + seg]);
    }
    __syncthreads();

#pragma unroll
    for (int f = 0; f < 2; ++f) {
      int cb = wv * 32 + f * 16;
#pragma unroll
      for (int ks = 0; ks < 2; ++ks) {
        bf16x8 bh = *reinterpret_cast<const bf16x8*>(&Kh[cb + l15][ks * 32 + kb]);
        bf16x8 bl = *reinterpret_cast<const bf16x8*>(&Kl[cb + l15][ks * 32 + kb]);
        acc[kt][f] = __builtin_amdgcn_mfma_f32_16x16x32_bf16(ah[ks], bh, acc[kt][f], 0, 0, 0);
        acc[kt][f] = __builtin_amdgcn_mfma_f32_16x16x32_bf16(al[ks], bh, acc[kt][f], 0, 0, 0);
        acc[kt][f] = __builtin_amdgcn_mfma_f32_16x16x32_bf16(ah[ks], bl, acc[kt][f], 0, 0, 0);
      }
    }
  }
  __syncthreads();

  float mx[4] = {-3.0e38f, -3.0e38f, -3.0e38f, -3.0e38f};
#pragma unroll
  for (int t = 0; t < 8; ++t)
#pragma unroll
    for (int f = 0; f < 2; ++f)
#pragma unroll
      for (int r = 0; r < 4; ++r) {
        int qlc = qg * 16 + hi4 * 4 + r;
        int q = q0 + qlc;
        int k = t * 128 + wv * 32 + f * 16 + l15;
        int d = k - q;
        int ridx = (d < -10 ? -10 : (d > 10 ? 10 : d)) + 10;
        float s = acc[t][f][r] + relp[qlc][ridx];
        if (k == q || msk[k] == 0) s -= 10000.0f;
        acc[t][f][r] = s;
        mx[r] = fmaxf(mx[r], s);
      }
#pragma unroll
  for (int r = 0; r < 4; ++r) {
    mx[r] = fmaxf(mx[r], __shfl_xor(mx[r], 1));
    mx[r] = fmaxf(mx[r], __shfl_xor(mx[r], 2));
    mx[r] = fmaxf(mx[r], __shfl_xor(mx[r], 4));
    mx[r] = fmaxf(mx[r], __shfl_xor(mx[r], 8));
  }
  {
    int wrow = qg * 4 + wv;
    if (l15 == 0) {
#pragma unroll
      for (int r = 0; r < 4; ++r) red1[wrow][hi4 * 4 + r] = mx[r];
    }
  }
  __syncthreads();
  float mxq[4];
#pragma unroll
  for (int r = 0; r < 4; ++r) {
    int ql16 = hi4 * 4 + r;
    mxq[r] = fmaxf(fmaxf(red1[qg * 4 + 0][ql16], red1[qg * 4 + 1][ql16]),
                   fmaxf(red1[qg * 4 + 2][ql16], red1[qg * 4 + 3][ql16]));
  }

  float sm[4] = {0.f, 0.f, 0.f, 0.f};
#pragma unroll
  for (int t = 0; t < 8; ++t)
#pragma unroll
    for (int f = 0; f < 2; ++f)
#pragma unroll
      for (int r = 0; r < 4; ++r) {
        float e = __expf(acc[t][f][r] - mxq[r]);
        acc[t][f][r] = e;
        sm[r] += e;
      }
#pragma unroll
  for (int r = 0; r < 4; ++r) {
    sm[r] += __shfl_xor(sm[r], 1);
    sm[r] += __shfl_xor(sm[r], 2);
    sm[r] += __shfl_xor(sm[r], 4);
    sm[r] += __shfl_xor(sm[r], 8);
  }
  {
    int wrow = qg * 4 + wv;
    if (l15 == 0) {
#pragma unroll
      for (int r = 0; r < 4; ++r) red2[wrow][hi4 * 4 + r] = sm[r];
    }
  }
  __syncthreads();
  float rinv[4];
#pragma unroll
  for (int r = 0; r < 4; ++r) {
    int ql16 = hi4 * 4 + r;
    rinv[r] = 1.0f / (red2[qg * 4 + 0][ql16] + red2[qg * 4 + 1][ql16] +
                      red2[qg * 4 + 2][ql16] + red2[qg * 4 + 3][ql16]);
  }

  float* pb = probs + (size_t)(b * H_ + h) * S_ * S_;
#pragma unroll
  for (int t = 0; t < 8; ++t)
#pragma unroll
    for (int f = 0; f < 2; ++f)
#pragma unroll
      for (int r = 0; r < 4; ++r) {
        int qlc = qg * 16 + hi4 * 4 + r;
        int kg = wv * 32 + f * 16 + l15;
        pb[(size_t)(q0 + qlc) * S_ + t * 128 + kg] = acc[t][f][r] * rinv[r];
      }
}

// ---------------------------------------------------------------------------
// PV, zero-LDS, reversed (b,h) for L3 recency (unchanged from r19).
// ---------------------------------------------------------------------------
__global__ __launch_bounds__(256) void pv_direct_kernel(
    const float* __restrict__ probs, const unsigned short* __restrict__ vbt,
    unsigned short* __restrict__ ctxb)
{
  const int tid = threadIdx.x;
  const int wv = tid >> 6;
  const int lane = tid & 63;
  const int l15 = lane & 15;
  const int hi4 = lane >> 4;
  const int b = (B_ - 1) - blockIdx.z;
  const int h = (H_ - 1) - blockIdx.y;
  const int qt = blockIdx.x;
  const float* pr = probs + (size_t)(b * H_ + h) * S_ * S_
                          + (size_t)(qt * 128 + wv * 32) * S_;
  const unsigned short* vtb = vbt + (size_t)(b * H_ + h) * HD_ * S_;

  f32x4 acc[2][4];
#pragma unroll
  for (int mi = 0; mi < 2; ++mi)
#pragma unroll
    for (int ni = 0; ni < 4; ++ni) acc[mi][ni] = (f32x4){0.f, 0.f, 0.f, 0.f};

  for (int k0 = 0; k0 < S_; k0 += 32) {
    bf16x8 af[2];
#pragma unroll
    for (int mi = 0; mi < 2; ++mi) {
      const float* prow = pr + (size_t)(mi * 16 + l15) * S_ + k0 + hi4 * 8;
      float4 p0 = *reinterpret_cast<const float4*>(prow);
      float4 p1 = *reinterpret_cast<const float4*>(prow + 4);
      bf16x8 a;
      a[0] = (short)f32_to_bf16(p0.x); a[1] = (short)f32_to_bf16(p0.y);
      a[2] = (short)f32_to_bf16(p0.z); a[3] = (short)f32_to_bf16(p0.w);
      a[4] = (short)f32_to_bf16(p1.x); a[5] = (short)f32_to_bf16(p1.y);
      a[6] = (short)f32_to_bf16(p1.z); a[7] = (short)f32_to_bf16(p1.w);
      af[mi] = a;
    }
#pragma unroll
    for (int ni = 0; ni < 4; ++ni) {
      bf16x8 vf = *reinterpret_cast<const bf16x8*>(
          &vtb[(size_t)(ni * 16 + l15) * S_ + k0 + hi4 * 8]);
      acc[0][ni] = __builtin_amdgcn_mfma_f32_16x16x32_bf16(af[0], vf, acc[0][ni], 0, 0, 0);
      acc[1][ni] = __builtin_amdgcn_mfma_f32_16x16x32_bf16(af[1], vf, acc[1][ni], 0, 0, 0);
    }
  }

#pragma unroll
  for (int mi = 0; mi < 2; ++mi)
#pragma unroll
    for (int ni = 0; ni < 4; ++ni) {
      int dd = ni * 16 + l15;
#pragma unroll
      for (int r = 0; r < 4; ++r) {
        int q = qt * 128 + wv * 32 + mi * 16 + hi4 * 4 + r;
        ctxb[((size_t)b * S_ + q) * DM_ + h * HD_ + dd] = f32_to_bf16(acc[mi][ni][r]);
      }
    }
}

// ---------------------------------------------------------------------------
// Row LayerNorm (1024 cols), f32 in, f32 or bf16 out (safe in-place for f32)
// ---------------------------------------------------------------------------
template<bool OUTB16>
__global__ __launch_bounds__(256) void ln_kernel(
    const float* __restrict__ in, const float* __restrict__ g,
    const float* __restrict__ be, void* __restrict__ out)
{
  __shared__ float red[4];
  const int row = blockIdx.x, tid = threadIdx.x;
  const float* r = in + (size_t)row * DM_;
  float4 x = *reinterpret_cast<const float4*>(&r[tid * 4]);

  float s = x.x + x.y + x.z + x.w;
#pragma unroll
  for (int m = 1; m < 64; m <<= 1) s += __shfl_xor(s, m);
  if ((tid & 63) == 0) red[tid >> 6] = s;
  __syncthreads();
  float mean = (red[0] + red[1] + red[2] + red[3]) * (1.0f / 1024.0f);
  __syncthreads();

  float d0 = x.x - mean, d1 = x.y - mean, d2 = x.z - mean, d3 = x.w - mean;
  float sq = d0 * d0 + d1 * d1 + d2 * d2 + d3 * d3;
#pragma unroll
  for (int m = 1; m < 64; m <<= 1) sq += __shfl_xor(sq, m);
  if ((tid & 63) == 0) red[tid >> 6] = sq;
  __syncthreads();
  float var = (red[0] + red[1] + red[2] + red[3]) * (1.0f / 1024.0f);
  float rstd = rsqrtf(var + 1e-3f);

  int c = tid * 4;
  float4 gv = *reinterpret_cast<const float4*>(&g[c]);
  float4 bv = *reinterpret_cast<const float4*>(&be[c]);
  float y0 = d0 * rstd * gv.x + bv.x;
  float y1 = d1 * rstd * gv.y + bv.y;
  float y2 = d2 * rstd * gv.z + bv.z;
  float y3 = d3 * rstd * gv.w + bv.w;
  if (OUTB16) {
    ushort4 o;
    o.x = f32_to_bf16(y0); o.y = f32_to_bf16(y1);
    o.z = f32_to_bf16(y2); o.w = f32_to_bf16(y3);
    *reinterpret_cast<ushort4*>(&((unsigned short*)out)[(size_t)row * DM_ + c]) = o;
  } else {
    *reinterpret_cast<float4*>(&((float*)out)[(size_t)row * DM_ + c]) =
        make_float4(y0, y1, y2, y3);
  }
}

// ---------------------------------------------------------------------------
// Workspace plan (64 MB, offsets in MB; overlays lifetime-checked):
//   0-8   WoT bf16       (prep -> Wo)
//   8-16  WiT bf16       (prep -> Wi)
//   16-18 WvT bf16       (prep -> qkv)
//   18-20 WapT bf16      (prep -> Wap)
//   20-22 WqkTh, 22-24 WqkTl  (prep -> qkv)
//   24-32 xh bf16        (prep -> qkv)
//   32-40 xl bf16        (prep -> qkv), then ctxb bf16 (pv -> Wap)
//   40-48 qk_hi bf16     (qkv -> attn)
//   48-56 qk_lo bf16     (qkv -> attn)
//   40-56 y f32          (Wap -> ln1)   [qk_hi/lo dead]
//   56-64 vbt bf16       (qkv -> pv)    [direct transposed V]
//   20-28 attnb bf16     (ln1 -> Wo)    [WqkT + xh dead]
//   32-64 interb bf16    (Wi -> Wo)     [ctxb/y/vbt dead]
//   t = outf (d_out); ln2 in place.
// ---------------------------------------------------------------------------
extern "C" void kernel_launch(void* const* d_in, const int* in_sizes, int n_in,
                              void* d_out, int out_size, void* d_ws, size_t ws_size,
                              hipStream_t stream) {
  const float* x    = (const float*)d_in[0];
  const int*   mask = (const int*)d_in[1];
  const float* Wqk  = (const float*)d_in[2];
  const float* bqk  = (const float*)d_in[3];
  const float* Wv   = (const float*)d_in[4];
  const float* bv   = (const float*)d_in[5];
  const float* rel  = (const float*)d_in[6];
  const float* Wap  = (const float*)d_in[7];
  const float* bap  = (const float*)d_in[8];
  const float* g1   = (const float*)d_in[9];
  const float* b1   = (const float*)d_in[10];
  const float* Wi   = (const float*)d_in[11];
  const float* bi   = (const float*)d_in[12];
  const float* Wo   = (const float*)d_in[13];
  const float* bo   = (const float*)d_in[14];
  const float* g2   = (const float*)d_in[15];
  const float* b2   = (const float*)d_in[16];

  char* wsb = (char*)d_ws;
  const size_t MB = 1048576;
  unsigned short* WoT    = (unsigned short*)(wsb + 0 * MB);
  unsigned short* WiT    = (unsigned short*)(wsb + 8 * MB);
  unsigned short* WvT    = (unsigned short*)(wsb + 16 * MB);
  unsigned short* WapT   = (unsigned short*)(wsb + 18 * MB);
  unsigned short* WqkTh  = (unsigned short*)(wsb + 20 * MB);
  unsigned short* WqkTl  = (unsigned short*)(wsb + 22 * MB);
  unsigned short* xh     = (unsigned short*)(wsb + 24 * MB);
  unsigned short* xl     = (unsigned short*)(wsb + 32 * MB);
  unsigned short* ctxb   = (unsigned short*)(wsb + 32 * MB);
  unsigned short* qk_hi  = (unsigned short*)(wsb + 40 * MB);
  unsigned short* qk_lo  = (unsigned short*)(wsb + 48 * MB);
  float*          y      = (float*)(wsb + 40 * MB);
  unsigned short* vbt    = (unsigned short*)(wsb + 56 * MB);
  unsigned short* attnb  = (unsigned short*)(wsb + 20 * MB);
  unsigned short* interb = (unsigned short*)(wsb + 32 * MB);

  float* outf  = (float*)d_out;        // out   [B,S,DM]  f32 (also t buffer)
  float* probs = outf + 4194304;       // probs [B,H,S,S] f32

  dim3 blk(256);
  // Merged preps: cvt_split + 4x tcvt + tcvt2 in one launch
  prep_kernel<<<6912, blk, 0, stream>>>(
      x, xh, xl, Wv, WvT, Wap, WapT, Wi, WiT, Wo, WoT, Wqk, WqkTh, WqkTl);

  // Merged qk projection (split 3-MFMA) + v projection (direct-transposed out)
  qkv_kernel<<<1024, blk, 0, stream>>>(
      xh, xl, WqkTh, WqkTl, bqk, qk_hi, qk_lo, WvT, bv, vbt);

  // scores + rel + mask + softmax -> probs f32 (XCD-swizzled)
  attn_kernel<<<dim3(32, 16, 4), dim3(512), 0, stream>>>(
      qk_hi, qk_lo, mask, rel, probs);
  // ctx = probs @ v (zero-LDS, reversed (b,h) for L3 reuse) -> bf16 [B,S,DM]
  pv_direct_kernel<<<dim3(8, 16, 4), blk, 0, stream>>>(probs, vbt, ctxb);
  // y = gelu(ctx @ Wap + bap) + x
  gemm_mfma_kernel<true, true, false, false><<<dim3(8, 64), blk, 0, stream>>>(
      ctxb, WapT, bap, x, y, 4096, 1024, 1024);
  // attnb = LN(y)*g1+b1 (bf16)
  ln_kernel<true><<<4096, blk, 0, stream>>>(y, g1, b1, attnb);
  // inter = gelu(attn @ Wi + bi) (bf16)
  gemm_mfma_kernel<true, false, false, true><<<dim3(32, 64), blk, 0, stream>>>(
      attnb, WiT, bi, nullptr, interb, 4096, 4096, 1024);
  // outf = gelu(inter @ Wo + bo) + attn   (t lives in d_out)
  gemm_mfma_kernel<true, true, true, false><<<dim3(8, 64), blk, 0, stream>>>(
      interb, WoT, bo, attnb, outf, 4096, 1024, 4096);
  // out = LN(t)*g2+b2 (f32, in place)
  ln_kernel<false><<<4096, blk, 0, stream>>>(outf, g2, b2, outf);
}